// Round 8
// baseline (113.438 us; speedup 1.0000x reference)
//
#include <hip/hip_runtime.h>
#include <hip/hip_bf16.h>
#include <cstddef>

// Problem constants (N, D, S, H, QP, VP) = (512, 256, 32, 4, 8, 8)
#define N_NODES 512
#define DIM     256
#define H_HEADS 4
#define PAIR_CN 56    // S + 3*VP
#define P3_N    96    // H*QP*3
#define FD_N    112   // P3 + 16
#define HPC     224   // H * PAIR_C

__device__ __forceinline__ bool mask_true(const void* m, int idx) {
    if (((const unsigned char*)m)[idx] != 0) return true;
    return ((const int*)m)[idx] != 0;
}
__device__ __forceinline__ float bflo(unsigned u) { return __uint_as_float(u << 16); }
__device__ __forceinline__ float bfhi(unsigned u) { return __uint_as_float(u & 0xffff0000u); }
__device__ __forceinline__ unsigned short bf16bits(float v) {
    __hip_bfloat16 b = __float2bfloat16(v);
    unsigned short s; __builtin_memcpy(&s, &b, 2); return s;
}
__device__ __forceinline__ unsigned packh2(float a, float b) {
    _Float16 ha = (_Float16)a, hb = (_Float16)b;
    unsigned short ua, ub;
    __builtin_memcpy(&ua, &ha, 2); __builtin_memcpy(&ub, &hb, 2);
    return (unsigned)ua | ((unsigned)ub << 16);
}
__device__ __forceinline__ float2 unpackh2(unsigned u) {
    unsigned short ua = (unsigned short)(u & 0xffff), ub = (unsigned short)(u >> 16);
    _Float16 ha, hb;
    __builtin_memcpy(&ha, &ua, 2); __builtin_memcpy(&hb, &ub, 2);
    return make_float2((float)ha, (float)hb);
}
#define WRED(x) { x += __shfl_xor(x,1); x += __shfl_xor(x,2); x += __shfl_xor(x,4); \
                  x += __shfl_xor(x,8); x += __shfl_xor(x,16); x += __shfl_xor(x,32); }

// ---------------------------------------------------------------------------
// Phase 1: projections + LayerNorm + separable terms. 2 rows/block, grid 256.
// Writes qn f32, knb bf16 (row-major), qpo f32, kpob bf16 (row-major),
// valT bf16 [224][512] (transposed), kpT bf16 [96][512] (transposed),
// jinfo, iinfo.
// ---------------------------------------------------------------------------
__global__ __launch_bounds__(512) void proj_kernel(
    const float* __restrict__ local, const float* __restrict__ pos,
    const float* __restrict__ qls, const float* __restrict__ qlo,
    const float* __restrict__ kls, const float* __restrict__ klo,
    const float* __restrict__ w_q, const float* __restrict__ b_q,
    const float* __restrict__ w_k, const float* __restrict__ b_k,
    const float* __restrict__ w_v, const float* __restrict__ b_v,
    const float* __restrict__ w_qp, const float* __restrict__ b_qp,
    const float* __restrict__ w_kp, const float* __restrict__ b_kp,
    const float* __restrict__ w_vp, const float* __restrict__ b_vp,
    const float* __restrict__ w_bias, const float* __restrict__ b_bias,
    const float* __restrict__ gamma,
    float* __restrict__ qn, __hip_bfloat16* __restrict__ knb,
    float* __restrict__ qpo, __hip_bfloat16* __restrict__ kpob,
    __hip_bfloat16* __restrict__ valT, __hip_bfloat16* __restrict__ kpT,
    float* __restrict__ jinfo, float* __restrict__ iinfo)
{
    const int i0 = blockIdx.x * 2;
    const int tid = threadIdx.x;

    __shared__ float xL[2][DIM];
    __shared__ float qraw[2][128];
    __shared__ float kraw[2][128];
    __shared__ float stat[2][16];
    __shared__ float qpL[2][P3_N];
    __shared__ float kpbL[2][P3_N];
    __shared__ float wbS[384];

    {
        const int r = tid >> 8, d = tid & 255;
        xL[r][d] = local[(size_t)(i0 + r) * DIM + d];
    }
    if (tid < 384) wbS[tid] = w_bias[tid];
    __syncthreads();

    char* valTB = (char*)valT;
    char* kpTB  = (char*)kpT;

    if (tid < 336) {
        const int colg = tid >> 1, dh = tid & 1;
        const int col = colg * 4;
        const float* w; int width, c, seg;
        if      (col < 128) { w = w_q;  c = col;       width = 128; seg = 0; }
        else if (col < 256) { w = w_k;  c = col - 128; width = 128; seg = 1; }
        else if (col < 384) { w = w_v;  c = col - 256; width = 128; seg = 2; }
        else if (col < 480) { w = w_qp; c = col - 384; width = 96;  seg = 3; }
        else if (col < 576) { w = w_kp; c = col - 480; width = 96;  seg = 4; }
        else                { w = w_vp; c = col - 576; width = 96;  seg = 5; }

        float acc[2][4] = {{0.f,0.f,0.f,0.f},{0.f,0.f,0.f,0.f}};
#pragma unroll 4
        for (int dd = 0; dd < 128; ++dd) {
            const int d = dh*128 + dd;
            float4 wv = *(const float4*)(w + (size_t)d * width + c);
#pragma unroll
            for (int r = 0; r < 2; ++r) {
                float x = xL[r][d];
                acc[r][0] += x * wv.x; acc[r][1] += x * wv.y;
                acc[r][2] += x * wv.z; acc[r][3] += x * wv.w;
            }
        }
#pragma unroll
        for (int r = 0; r < 2; ++r)
#pragma unroll
            for (int e = 0; e < 4; ++e)
                acc[r][e] += __shfl_xor(acc[r][e], 1);

        if (dh == 0) {
            const float cax0 = pos[i0*15+3],     cay0 = pos[i0*15+4],     caz0 = pos[i0*15+5];
            const float cax1 = pos[(i0+1)*15+3], cay1 = pos[(i0+1)*15+4], caz1 = pos[(i0+1)*15+5];
#pragma unroll
            for (int e = 0; e < 4; ++e) {
                const int cc = c + e;
                const float v0 = acc[0][e], v1 = acc[1][e];
                if (seg == 0) {
                    qraw[0][cc] = v0 + b_q[cc];
                    qraw[1][cc] = v1 + b_q[cc];
                } else if (seg == 1) {
                    kraw[0][cc] = v0 + b_k[cc];
                    kraw[1][cc] = v1 + b_k[cc];
                } else if (seg == 2) {
                    const int h = cc >> 5, sc = cc & 31;
                    const int row = h*PAIR_CN + sc;
                    const float a0 = v0 + b_v[cc], a1 = v1 + b_v[cc];
                    unsigned u = (unsigned)bf16bits(a0) | ((unsigned)bf16bits(a1) << 16);
                    *(unsigned*)(valTB + (size_t)row*1024 + i0*2) = u;
                } else if (seg == 3) {
                    const int x = cc % 3;
                    const float cav0 = (x==0)?cax0:((x==1)?cay0:caz0);
                    const float cav1 = (x==0)?cax1:((x==1)?cay1:caz1);
                    const float r0 = v0 + b_qp[cc] + cav0;
                    const float r1 = v1 + b_qp[cc] + cav1;
                    qpo[(size_t)i0*P3_N + cc] = r0;
                    qpo[(size_t)(i0+1)*P3_N + cc] = r1;
                    qpL[0][cc] = r0; qpL[1][cc] = r1;
                } else if (seg == 4) {
                    const int x = cc % 3;
                    const float cav0 = (x==0)?cax0:((x==1)?cay0:caz0);
                    const float cav1 = (x==0)?cax1:((x==1)?cay1:caz1);
                    const float r0 = v0 + b_kp[cc] + cav0;
                    const float r1 = v1 + b_kp[cc] + cav1;
                    const unsigned short s0 = bf16bits(r0), s1 = bf16bits(r1);
                    kpob[(size_t)i0*P3_N + cc]     = *(const __hip_bfloat16*)&s0;
                    kpob[(size_t)(i0+1)*P3_N + cc] = *(const __hip_bfloat16*)&s1;
                    *(unsigned*)(kpTB + (size_t)cc*1024 + i0*2) =
                        (unsigned)s0 | ((unsigned)s1 << 16);
                    kpbL[0][cc] = bflo((unsigned)s0 << 0) * 0.f + __uint_as_float(((unsigned)s0)<<16);
                    kpbL[1][cc] = __uint_as_float(((unsigned)s1)<<16);
                } else {
                    const int h = cc / 24, rr = cc % 24, x = cc % 3;
                    const float cav0 = (x==0)?cax0:((x==1)?cay0:caz0);
                    const float cav1 = (x==0)?cax1:((x==1)?cay1:caz1);
                    const int row = h*PAIR_CN + 32 + rr;
                    const float a0 = v0 + b_vp[cc] + cav0, a1 = v1 + b_vp[cc] + cav1;
                    unsigned u = (unsigned)bf16bits(a0) | ((unsigned)bf16bits(a1) << 16);
                    *(unsigned*)(valTB + (size_t)row*1024 + i0*2) = u;
                }
            }
        }
    }
    __syncthreads();

    if (tid < 16) {
        const int r = tid >> 3, t = tid & 7;
        const float* src = (t < 4) ? qraw[r] : kraw[r];
        const int h = t & 3, base = (t < 4) ? 0 : 8;
        float mu = 0.f;
        for (int c = 0; c < 32; ++c) mu += src[h*32 + c];
        mu *= (1.f/32.f);
        float var = 0.f;
        for (int c = 0; c < 32; ++c) { float d = src[h*32 + c] - mu; var += d*d; }
        var *= (1.f/32.f);
        stat[r][base + h*2 + 0] = mu;
        stat[r][base + h*2 + 1] = var;
    }
    __syncthreads();

    {
        const int r = tid >> 8, u = tid & 255;
        const int i = i0 + r;
        if (u < 128) {
            const int h = u >> 5, sidx = u & 31;
            const float mu = stat[r][h*2], var = stat[r][h*2+1];
            float v = (qraw[r][u] - mu) * rsqrtf(var + 1e-5f) * qls[sidx] + qlo[sidx];
            qn[(size_t)i*128 + u] = v * 0.17677669529663687f;  // * sqrt(1/S)
        } else {
            const int u2 = u - 128, h = u2 >> 5, sidx = u2 & 31;
            const float mu = stat[r][8 + h*2], var = stat[r][9 + h*2];
            float v = (kraw[r][u2] - mu) * rsqrtf(var + 1e-5f) * kls[sidx] + klo[sidx];
            knb[(size_t)i*128 + u2] = __float2bfloat16(v);
        }
    }

    // ---- separable terms, 64 threads = 2 r x 4 h x 8 ks ----
    if (tid < 64) {
        const int r = tid >> 5, h = (tid >> 3) & 3, ks = tid & 7;
        float uacc = 0.f, tacc = 0.f;
#pragma unroll
        for (int f = ks; f < P3_N; f += 8) {
            float wb = wbS[f*4 + h];
            uacc += qpL[r][f] * wb;
            tacc += kpbL[r][f] * wb;
        }
        float nq = 0.f, nk = 0.f;
#pragma unroll
        for (int f = h*24 + ks*3; f < h*24 + ks*3 + 3; ++f) {
            nq += qpL[r][f]*qpL[r][f];
            nk += kpbL[r][f]*kpbL[r][f];
        }
        uacc += __shfl_xor(uacc,1); uacc += __shfl_xor(uacc,2); uacc += __shfl_xor(uacc,4);
        tacc += __shfl_xor(tacc,1); tacc += __shfl_xor(tacc,2); tacc += __shfl_xor(tacc,4);
        nq   += __shfl_xor(nq,1);   nq   += __shfl_xor(nq,2);   nq   += __shfl_xor(nq,4);
        nk   += __shfl_xor(nk,1);   nk   += __shfl_xor(nk,2);   nk   += __shfl_xor(nk,4);
        if (ks == 0) {
            const int n = i0 + r;
            const float ps = log1pf(expf(gamma[h])) * (1.0f/12.0f);
            iinfo[n*4 + h] = -ps*nq + uacc + b_bias[h];
            jinfo[n*8 + h] = -ps*nk - tacc;
            if (h == 0) {
                jinfo[n*8 + 4] = 10.f * pos[n*15 + 3];
                jinfo[n*8 + 5] = 10.f * pos[n*15 + 4];
                jinfo[n*8 + 6] = 10.f * pos[n*15 + 5];
                jinfo[n*8 + 7] = 0.f;
            }
        }
    }
}

// ---------------------------------------------------------------------------
// Phase 2: one block per query row. 512 threads, grid 512.
// No staging: direct coalesced global reads; wave-owner reductions in Pass B.
// ---------------------------------------------------------------------------
__global__ __launch_bounds__(512, 4) void attn_kernel(
    const float* __restrict__ qn, const __hip_bfloat16* __restrict__ knb,
    const float* __restrict__ qpo, const __hip_bfloat16* __restrict__ kpob,
    const __hip_bfloat16* __restrict__ valT, const __hip_bfloat16* __restrict__ kpT,
    const float* __restrict__ jinfo, const float* __restrict__ iinfo,
    const int* __restrict__ resi, const int* __restrict__ chain,
    const int* __restrict__ batch, const void* __restrict__ maskp,
    const float* __restrict__ remb, const float* __restrict__ w_pair,
    const float* __restrict__ w_bias, const float* __restrict__ gamma,
    const float* __restrict__ w_out,
    float* __restrict__ out)
{
    const int i    = blockIdx.x;
    const int tid  = threadIdx.x;
    const int lane = tid & 63;
    const int wv   = tid >> 6;

    __shared__ float    logitsF[H_HEADS][516];
    __shared__ unsigned attnH[H_HEADS][260];    // packed f16 prob pairs
    __shared__ float    distL[N_NODES];
    __shared__ float    qpiL[P3_N];
    __shared__ float    GLf[H_HEADS][FD_N];
    __shared__ float    resL[HPC];
    __shared__ float    abkt[H_HEADS][66];
    __shared__ float    mxP[2][H_HEADS], smP[2][H_HEADS];
    __shared__ unsigned char rdL[N_NODES], pmL[N_NODES];

    // ---- init ----
    if (tid < 96) qpiL[tid] = qpo[(size_t)i*P3_N + tid];
    if (tid >= 128 && tid < 128 + H_HEADS*66) {
        const int v = tid - 128;
        abkt[v/66][v%66] = 0.f;
    }
    const int  r_i = resi[i], ch_i = chain[i], ba_i = batch[i];
    const bool m_i = mask_true(maskp, i);
    const float dix = jinfo[(size_t)i*8+4], diy = jinfo[(size_t)i*8+5], diz = jinfo[(size_t)i*8+6];

    const float inv3  = 0.57735026918962576f;
    const float rstep = 0.72727272727272727f;   // 1/1.375

    // ================= Pass A: direct global, (jl, h, ks) split =============
    {
        const int jlA = tid >> 4, hA = (tid >> 2) & 3, ksA = tid & 3;
        const char* knB = (const char*)knb;
        const char* kpB = (const char*)kpob;

        float qv[8];
        {
            const float4 a = *(const float4*)(qn + (size_t)i*128 + hA*32 + ksA*8);
            const float4 b = *(const float4*)(qn + (size_t)i*128 + hA*32 + ksA*8 + 4);
            qv[0]=a.x; qv[1]=a.y; qv[2]=a.z; qv[3]=a.w;
            qv[4]=b.x; qv[5]=b.y; qv[6]=b.z; qv[7]=b.w;
        }
        float qs[8] = {0.f,0.f,0.f,0.f,0.f,0.f,0.f,0.f};
        if (ksA < 3) {
            const float ps2 = 2.f * log1pf(expf(gamma[hA])) * (1.0f/12.0f);
            const float4 a = *(const float4*)(qpo + (size_t)i*P3_N + hA*24 + ksA*8);
            const float4 b = *(const float4*)(qpo + (size_t)i*P3_N + hA*24 + ksA*8 + 4);
            qs[0]=ps2*a.x; qs[1]=ps2*a.y; qs[2]=ps2*a.z; qs[3]=ps2*a.w;
            qs[4]=ps2*b.x; qs[5]=ps2*b.y; qs[6]=ps2*b.z; qs[7]=ps2*b.w;
        }
        float wb4[4], cb4[4];
#pragma unroll
        for (int bb = 0; bb < 4; ++bb) {
            const int b = ksA*4 + bb;
            wb4[bb] = w_bias[(P3_N + b)*H_HEADS + hA];
            cb4[bb] = 1.375f*(float)b + 0.6875f;
        }
        const float ci = iinfo[i*4 + hA];
        const bool wrRD = (hA == 3 && ksA == 3);
        const bool wrLg = (ksA == 0);

#pragma unroll 2
        for (int jj = 0; jj < 16; ++jj) {
            const int j = jj*32 + jlA;
            float l = 0.f;
            {
                const uint4 kk = *(const uint4*)(knB + (size_t)j*256 + hA*64 + ksA*16);
                const unsigned uu[4] = {kk.x, kk.y, kk.z, kk.w};
#pragma unroll
                for (int e = 0; e < 4; ++e)
                    l += qv[2*e]*bflo(uu[e]) + qv[2*e+1]*bfhi(uu[e]);
            }
            if (ksA < 3) {
                const uint4 kk = *(const uint4*)(kpB + (size_t)j*192 + hA*48 + ksA*16);
                const unsigned uu[4] = {kk.x, kk.y, kk.z, kk.w};
#pragma unroll
                for (int e = 0; e < 4; ++e)
                    l += qs[2*e]*bflo(uu[e]) + qs[2*e+1]*bfhi(uu[e]);
            }
            const float4 dj = *(const float4*)(jinfo + (size_t)j*8 + 4);
            const float vq = jinfo[(size_t)j*8 + hA];
            const float dd0 = dix - dj.x, dd1 = diy - dj.y, dd2 = diz - dj.z;
            const float dist = sqrtf(dd0*dd0 + dd1*dd1 + dd2*dd2 + 1e-6f);
#pragma unroll
            for (int bb = 0; bb < 4; ++bb) {
                const float u = (dist - cb4[bb]) * rstep;
                l += __expf(-u*u) * wb4[bb];
            }
            l += __shfl_xor(l, 1);
            l += __shfl_xor(l, 2);
            if (wrLg) logitsF[hA][j] = (l + ci + vq) * inv3;
            if (wrRD) {
                const int rj = resi[j], cj = chain[j], bj = batch[j];
                const bool pm = m_i && mask_true(maskp, j) && (ba_i == bj);
                rdL[j] = (unsigned char)((ch_i != cj) ? 65 : (min(max(r_i - rj, -32), 32) + 32));
                pmL[j] = pm ? 1 : 0;
                distL[j] = dist;
            }
        }
    }
    __syncthreads();

    // ================= Softmax (wave = (h, half)) + buckets + pack ==========
    {
        const int h = wv >> 1, half = wv & 1;
        float lv[4];
        float mx = -1e30f;
#pragma unroll
        for (int k = 0; k < 4; ++k) {
            const int j = half*256 + lane + 64*k;
            const float v = pmL[j] ? logitsF[h][j] : -1e9f;
            lv[k] = v;
            mx = fmaxf(mx, v);
        }
#pragma unroll
        for (int off = 32; off; off >>= 1) mx = fmaxf(mx, __shfl_xor(mx, off));
        if (lane == 0) mxP[half][h] = mx;
        __syncthreads();
        mx = fmaxf(mxP[0][h], mxP[1][h]);
        float sm = 0.f;
#pragma unroll
        for (int k = 0; k < 4; ++k) sm += __expf(lv[k] - mx);
#pragma unroll
        for (int off = 32; off; off >>= 1) sm += __shfl_xor(sm, off);
        if (lane == 0) smP[half][h] = sm;
        __syncthreads();
        const float rden = 1.f / fmaxf(smP[0][h] + smP[1][h], 1e-37f);
        float p[4];
#pragma unroll
        for (int k = 0; k < 4; ++k) {
            const int j = half*256 + lane + 64*k;
            float a = __expf(lv[k] - mx) * rden;
            a = pmL[j] ? a : 0.f;
            p[k] = a;
            atomicAdd(&abkt[h][rdL[j]], a);
        }
#pragma unroll
        for (int k = 0; k < 4; ++k) {
            const float po = __shfl_xor(p[k], 1);
            if (!(lane & 1)) {
                const int j = half*256 + lane + 64*k;
                attnH[h][j >> 1] = packh2(p[k], po);
            }
        }
    }
    __syncthreads();

    // ================= Pass B (wave = (h, half)): coalesced row reductions ===
    {
        const int h = wv >> 1, half = wv & 1;
        // hoist probs for h: j = 2*(lane+64k), 2*(lane+64k)+1
        float pj[8];
#pragma unroll
        for (int k = 0; k < 4; ++k) {
            const float2 f2 = unpackh2(attnH[h][lane + 64*k]);
            pj[2*k] = f2.x; pj[2*k+1] = f2.y;
        }
        // asum[h] from buckets
        float asum = abkt[h][lane] + ((lane < 2) ? abkt[h][64 + lane] : 0.f);
        WRED(asum);

        const char* valB = (const char*)valT;
        const char* kpTB = (const char*)kpT;

        // ---- B1: R-val, 28 output rows per wave ----
#pragma unroll 2
        for (int ii = 0; ii < 28; ++ii) {
            const int s = h*56 + half*28 + ii;
            const char* vrow = valB + (size_t)s*1024;
            float acc = 0.f;
#pragma unroll
            for (int k = 0; k < 4; ++k) {
                const unsigned u = *(const unsigned*)(vrow + (lane + 64*k)*4);
                acc += pj[2*k]*bflo(u) + pj[2*k+1]*bfhi(u);
            }
            WRED(acc);
            if (lane == 0) resL[s] = acc;
        }
        // ---- Gk: 48 f-rows per wave ----
#pragma unroll 2
        for (int ii = 0; ii < 48; ++ii) {
            const int f = half*48 + ii;
            const char* krow = kpTB + (size_t)f*1024;
            float acc = 0.f;
#pragma unroll
            for (int k = 0; k < 4; ++k) {
                const unsigned u = *(const unsigned*)(krow + (lane + 64*k)*4);
                acc += pj[2*k]*bflo(u) + pj[2*k+1]*bfhi(u);
            }
            WRED(acc);
            if (lane == 0) GLf[h][f] = qpiL[f]*asum - acc;
        }
        // ---- rbf-G: 8 b per wave ----
        for (int ii = 0; ii < 8; ++ii) {
            const int b = half*8 + ii;
            const float cb = 1.375f*(float)b + 0.6875f;
            float acc = 0.f;
#pragma unroll
            for (int k = 0; k < 4; ++k) {
                const float2 d2 = *(const float2*)&distL[2*(lane + 64*k)];
                const float u0 = (d2.x - cb)*rstep;
                const float u1 = (d2.y - cb)*rstep;
                acc += pj[2*k]*__expf(-u0*u0) + pj[2*k+1]*__expf(-u1*u1);
            }
            WRED(acc);
            if (lane == 0) GLf[h][96 + b] = acc;
        }
    }
    __syncthreads();

    // ================= Epilogue: res = R + emb-buckets + G @ w_pair =========
    if (tid < HPC) {
        const int h = tid / PAIR_CN, c = tid - h*PAIR_CN;
        float r = resL[tid];
#pragma unroll 4
        for (int rr = 0; rr < 66; ++rr) r += abkt[h][rr] * remb[rr*PAIR_CN + c];
        const float* gl = GLf[h];
        const float* wp = w_pair + c;
#pragma unroll 8
        for (int f = 0; f < FD_N; ++f) r += gl[f] * wp[f*PAIR_CN];
        resL[tid] = r;
    }
    __syncthreads();

    // ================= out = res @ w_out (t-split 2-way) ====================
    {
        const int col = tid >> 1, ph = tid & 1;
        float o = 0.f;
#pragma unroll 8
        for (int t = ph*112; t < ph*112 + 112; ++t)
            o += resL[t] * w_out[(size_t)t*DIM + col];
        o += __shfl_xor(o, 1);
        if (ph == 0) out[(size_t)i*DIM + col] = o;
    }
}

// ---------------------------------------------------------------------------
extern "C" void kernel_launch(void* const* d_in, const int* in_sizes, int n_in,
                              void* d_out, int out_size, void* d_ws, size_t ws_size,
                              hipStream_t stream) {
    (void)in_sizes; (void)n_in; (void)out_size; (void)ws_size;
    const float* local = (const float*)d_in[0];
    const float* pos   = (const float*)d_in[1];
    const int*   resi  = (const int*)d_in[2];
    const int*   chain = (const int*)d_in[3];
    const int*   batch = (const int*)d_in[4];
    const void*  maskp = d_in[5];
    const float* qls   = (const float*)d_in[6];
    const float* qlo   = (const float*)d_in[7];
    const float* kls   = (const float*)d_in[8];
    const float* klo   = (const float*)d_in[9];
    const float* w_q   = (const float*)d_in[10];
    const float* b_q   = (const float*)d_in[11];
    const float* w_k   = (const float*)d_in[12];
    const float* b_k   = (const float*)d_in[13];
    const float* w_v   = (const float*)d_in[14];
    const float* b_v   = (const float*)d_in[15];
    const float* w_qp  = (const float*)d_in[16];
    const float* b_qp  = (const float*)d_in[17];
    const float* w_kp  = (const float*)d_in[18];
    const float* b_kp  = (const float*)d_in[19];
    const float* w_vp  = (const float*)d_in[20];
    const float* b_vp  = (const float*)d_in[21];
    const float* remb  = (const float*)d_in[22];
    const float* w_pair= (const float*)d_in[23];
    const float* w_bias= (const float*)d_in[24];
    const float* b_bias= (const float*)d_in[25];
    const float* gamma = (const float*)d_in[26];
    const float* w_out = (const float*)d_in[27];

    char* ws = (char*)d_ws;
    float*           qn    = (float*)(ws);                       // 262144 B
    __hip_bfloat16*  knb   = (__hip_bfloat16*)(ws + 262144);     // 131072 B
    float*           qpo   = (float*)(ws + 393216);              // 196608 B
    __hip_bfloat16*  kpob  = (__hip_bfloat16*)(ws + 589824);     //  98304 B
    __hip_bfloat16*  valT  = (__hip_bfloat16*)(ws + 688128);     // 229376 B [224][512]
    __hip_bfloat16*  kpT   = (__hip_bfloat16*)(ws + 917504);     //  98304 B [96][512]
    float*           jinf  = (float*)(ws + 1015808);             //  16384 B
    float*           iinf  = (float*)(ws + 1032192);             //   8192 B

    proj_kernel<<<N_NODES / 2, 512, 0, stream>>>(
        local, pos, qls, qlo, kls, klo,
        w_q, b_q, w_k, b_k, w_v, b_v,
        w_qp, b_qp, w_kp, b_kp, w_vp, b_vp,
        w_bias, b_bias, gamma,
        qn, knb, qpo, kpob, valT, kpT, jinf, iinf);

    attn_kernel<<<N_NODES, 512, 0, stream>>>(
        qn, knb, qpo, kpob, valT, kpT, jinf, iinf,
        resi, chain, batch, maskp,
        remb, w_pair, w_bias, gamma, w_out,
        (float*)d_out);
}

// Round 9
// 79.055 us; speedup vs baseline: 1.4349x; 1.4349x over previous
//
#include <hip/hip_runtime.h>
#include <hip/hip_bf16.h>
#include <cstddef>

// Problem constants (N, D, S, H, QP, VP) = (512, 256, 32, 4, 8, 8)
#define N_NODES 512
#define DIM     256
#define H_HEADS 4
#define PAIR_CN 56    // S + 3*VP
#define P3_N    96    // H*QP*3
#define FD_N    112   // P3 + 16
#define HPC     224   // H * PAIR_C

typedef _Float16 h2v __attribute__((ext_vector_type(2)));

__device__ __forceinline__ bool mask_true(const void* m, int idx) {
    if (((const unsigned char*)m)[idx] != 0) return true;
    return ((const int*)m)[idx] != 0;
}
__device__ __forceinline__ unsigned packh2(float a, float b) {
    _Float16 ha = (_Float16)a, hb = (_Float16)b;
    unsigned short ua, ub;
    __builtin_memcpy(&ua, &ha, 2); __builtin_memcpy(&ub, &hb, 2);
    return (unsigned)ua | ((unsigned)ub << 16);
}
__device__ __forceinline__ float dot2u(unsigned a, unsigned b, float c) {
#if __has_builtin(__builtin_amdgcn_fdot2)
    h2v ha, hb;
    __builtin_memcpy(&ha, &a, 4);
    __builtin_memcpy(&hb, &b, 4);
    return __builtin_amdgcn_fdot2(ha, hb, c, false);
#else
    _Float16 a0, a1, b0, b1;
    unsigned short t;
    t = (unsigned short)(a & 0xffff); __builtin_memcpy(&a0, &t, 2);
    t = (unsigned short)(a >> 16);    __builtin_memcpy(&a1, &t, 2);
    t = (unsigned short)(b & 0xffff); __builtin_memcpy(&b0, &t, 2);
    t = (unsigned short)(b >> 16);    __builtin_memcpy(&b1, &t, 2);
    return c + (float)a0*(float)b0 + (float)a1*(float)b1;
#endif
}

// ---------------------------------------------------------------------------
// Phase 1: projections + LayerNorm + separable terms. 2 rows/block, grid 256.
// Tables stored f16: knb [512][128], kpob [512][96] (row-major),
// valT [224][512], kpT [96][512] (transposed). qn/qpo stay f32.
// ---------------------------------------------------------------------------
__global__ __launch_bounds__(512) void proj_kernel(
    const float* __restrict__ local, const float* __restrict__ pos,
    const float* __restrict__ qls, const float* __restrict__ qlo,
    const float* __restrict__ kls, const float* __restrict__ klo,
    const float* __restrict__ w_q, const float* __restrict__ b_q,
    const float* __restrict__ w_k, const float* __restrict__ b_k,
    const float* __restrict__ w_v, const float* __restrict__ b_v,
    const float* __restrict__ w_qp, const float* __restrict__ b_qp,
    const float* __restrict__ w_kp, const float* __restrict__ b_kp,
    const float* __restrict__ w_vp, const float* __restrict__ b_vp,
    const float* __restrict__ w_bias, const float* __restrict__ b_bias,
    const float* __restrict__ gamma,
    float* __restrict__ qn, _Float16* __restrict__ knb,
    float* __restrict__ qpo, _Float16* __restrict__ kpob,
    _Float16* __restrict__ valT, _Float16* __restrict__ kpT,
    float* __restrict__ jinfo, float* __restrict__ iinfo)
{
    const int i0 = blockIdx.x * 2;
    const int tid = threadIdx.x;

    __shared__ float xL[2][DIM];
    __shared__ float qraw[2][128];
    __shared__ float kraw[2][128];
    __shared__ float stat[2][16];
    __shared__ float qpL[2][P3_N];
    __shared__ float kpbL[2][P3_N];
    __shared__ float wbS[384];

    {
        const int r = tid >> 8, d = tid & 255;
        xL[r][d] = local[(size_t)(i0 + r) * DIM + d];
    }
    if (tid < 384) wbS[tid] = w_bias[tid];
    __syncthreads();

    char* valTB = (char*)valT;
    char* kpTB  = (char*)kpT;

    if (tid < 336) {
        const int colg = tid >> 1, dh = tid & 1;
        const int col = colg * 4;
        const float* w; int width, c, seg;
        if      (col < 128) { w = w_q;  c = col;       width = 128; seg = 0; }
        else if (col < 256) { w = w_k;  c = col - 128; width = 128; seg = 1; }
        else if (col < 384) { w = w_v;  c = col - 256; width = 128; seg = 2; }
        else if (col < 480) { w = w_qp; c = col - 384; width = 96;  seg = 3; }
        else if (col < 576) { w = w_kp; c = col - 480; width = 96;  seg = 4; }
        else                { w = w_vp; c = col - 576; width = 96;  seg = 5; }

        float acc[2][4] = {{0.f,0.f,0.f,0.f},{0.f,0.f,0.f,0.f}};
#pragma unroll 4
        for (int dd = 0; dd < 128; ++dd) {
            const int d = dh*128 + dd;
            float4 wv = *(const float4*)(w + (size_t)d * width + c);
#pragma unroll
            for (int r = 0; r < 2; ++r) {
                float x = xL[r][d];
                acc[r][0] += x * wv.x; acc[r][1] += x * wv.y;
                acc[r][2] += x * wv.z; acc[r][3] += x * wv.w;
            }
        }
#pragma unroll
        for (int r = 0; r < 2; ++r)
#pragma unroll
            for (int e = 0; e < 4; ++e)
                acc[r][e] += __shfl_xor(acc[r][e], 1);

        if (dh == 0) {
            const float cax0 = pos[i0*15+3],     cay0 = pos[i0*15+4],     caz0 = pos[i0*15+5];
            const float cax1 = pos[(i0+1)*15+3], cay1 = pos[(i0+1)*15+4], caz1 = pos[(i0+1)*15+5];
#pragma unroll
            for (int e = 0; e < 4; ++e) {
                const int cc = c + e;
                const float v0 = acc[0][e], v1 = acc[1][e];
                if (seg == 0) {
                    qraw[0][cc] = v0 + b_q[cc];
                    qraw[1][cc] = v1 + b_q[cc];
                } else if (seg == 1) {
                    kraw[0][cc] = v0 + b_k[cc];
                    kraw[1][cc] = v1 + b_k[cc];
                } else if (seg == 2) {
                    const int h = cc >> 5, sc = cc & 31;
                    const int row = h*PAIR_CN + sc;
                    *(unsigned*)(valTB + (size_t)row*1024 + i0*2) =
                        packh2(v0 + b_v[cc], v1 + b_v[cc]);
                } else if (seg == 3) {
                    const int x = cc % 3;
                    const float cav0 = (x==0)?cax0:((x==1)?cay0:caz0);
                    const float cav1 = (x==0)?cax1:((x==1)?cay1:caz1);
                    const float r0 = v0 + b_qp[cc] + cav0;
                    const float r1 = v1 + b_qp[cc] + cav1;
                    qpo[(size_t)i0*P3_N + cc] = r0;
                    qpo[(size_t)(i0+1)*P3_N + cc] = r1;
                    qpL[0][cc] = r0; qpL[1][cc] = r1;
                } else if (seg == 4) {
                    const int x = cc % 3;
                    const float cav0 = (x==0)?cax0:((x==1)?cay0:caz0);
                    const float cav1 = (x==0)?cax1:((x==1)?cay1:caz1);
                    const float r0 = v0 + b_kp[cc] + cav0;
                    const float r1 = v1 + b_kp[cc] + cav1;
                    const _Float16 h0 = (_Float16)r0, h1 = (_Float16)r1;
                    kpob[(size_t)i0*P3_N + cc]     = h0;
                    kpob[(size_t)(i0+1)*P3_N + cc] = h1;
                    *(unsigned*)(kpTB + (size_t)cc*1024 + i0*2) = packh2(r0, r1);
                    kpbL[0][cc] = (float)h0;
                    kpbL[1][cc] = (float)h1;
                } else {
                    const int h = cc / 24, rr = cc % 24, x = cc % 3;
                    const float cav0 = (x==0)?cax0:((x==1)?cay0:caz0);
                    const float cav1 = (x==0)?cax1:((x==1)?cay1:caz1);
                    const int row = h*PAIR_CN + 32 + rr;
                    *(unsigned*)(valTB + (size_t)row*1024 + i0*2) =
                        packh2(v0 + b_vp[cc] + cav0, v1 + b_vp[cc] + cav1);
                }
            }
        }
    }
    __syncthreads();

    if (tid < 16) {
        const int r = tid >> 3, t = tid & 7;
        const float* src = (t < 4) ? qraw[r] : kraw[r];
        const int h = t & 3, base = (t < 4) ? 0 : 8;
        float mu = 0.f;
        for (int c = 0; c < 32; ++c) mu += src[h*32 + c];
        mu *= (1.f/32.f);
        float var = 0.f;
        for (int c = 0; c < 32; ++c) { float d = src[h*32 + c] - mu; var += d*d; }
        var *= (1.f/32.f);
        stat[r][base + h*2 + 0] = mu;
        stat[r][base + h*2 + 1] = var;
    }
    __syncthreads();

    {
        const int r = tid >> 8, u = tid & 255;
        const int i = i0 + r;
        if (u < 128) {
            const int h = u >> 5, sidx = u & 31;
            const float mu = stat[r][h*2], var = stat[r][h*2+1];
            float v = (qraw[r][u] - mu) * rsqrtf(var + 1e-5f) * qls[sidx] + qlo[sidx];
            qn[(size_t)i*128 + u] = v * 0.17677669529663687f;  // * sqrt(1/S)
        } else {
            const int u2 = u - 128, h = u2 >> 5, sidx = u2 & 31;
            const float mu = stat[r][8 + h*2], var = stat[r][9 + h*2];
            float v = (kraw[r][u2] - mu) * rsqrtf(var + 1e-5f) * kls[sidx] + klo[sidx];
            knb[(size_t)i*128 + u2] = (_Float16)v;
        }
    }

    // ---- separable terms, 64 threads = 2 r x 4 h x 8 ks ----
    if (tid < 64) {
        const int r = tid >> 5, h = (tid >> 3) & 3, ks = tid & 7;
        float uacc = 0.f, tacc = 0.f;
#pragma unroll
        for (int f = ks; f < P3_N; f += 8) {
            float wb = wbS[f*4 + h];
            uacc += qpL[r][f] * wb;
            tacc += kpbL[r][f] * wb;
        }
        float nq = 0.f, nk = 0.f;
#pragma unroll
        for (int f = h*24 + ks*3; f < h*24 + ks*3 + 3; ++f) {
            nq += qpL[r][f]*qpL[r][f];
            nk += kpbL[r][f]*kpbL[r][f];
        }
        uacc += __shfl_xor(uacc,1); uacc += __shfl_xor(uacc,2); uacc += __shfl_xor(uacc,4);
        tacc += __shfl_xor(tacc,1); tacc += __shfl_xor(tacc,2); tacc += __shfl_xor(tacc,4);
        nq   += __shfl_xor(nq,1);   nq   += __shfl_xor(nq,2);   nq   += __shfl_xor(nq,4);
        nk   += __shfl_xor(nk,1);   nk   += __shfl_xor(nk,2);   nk   += __shfl_xor(nk,4);
        if (ks == 0) {
            const int n = i0 + r;
            const float ps = log1pf(expf(gamma[h])) * (1.0f/12.0f);
            iinfo[n*4 + h] = -ps*nq + uacc + b_bias[h];
            jinfo[n*8 + h] = -ps*nk - tacc;
            if (h == 0) {
                jinfo[n*8 + 4] = 10.f * pos[n*15 + 3];
                jinfo[n*8 + 5] = 10.f * pos[n*15 + 4];
                jinfo[n*8 + 6] = 10.f * pos[n*15 + 5];
                jinfo[n*8 + 7] = 0.f;
            }
        }
    }
}

// ---------------------------------------------------------------------------
// Phase 2: one block per query row. 512 threads, grid 512.
// f16 dot2 everywhere; 3-shfl partial reductions + combine pass.
// ---------------------------------------------------------------------------
__global__ __launch_bounds__(512, 4) void attn_kernel(
    const float* __restrict__ qn, const _Float16* __restrict__ knb,
    const float* __restrict__ qpo, const _Float16* __restrict__ kpob,
    const _Float16* __restrict__ valT, const _Float16* __restrict__ kpT,
    const float* __restrict__ jinfo, const float* __restrict__ iinfo,
    const int* __restrict__ resi, const int* __restrict__ chain,
    const int* __restrict__ batch, const void* __restrict__ maskp,
    const float* __restrict__ remb, const float* __restrict__ w_pair,
    const float* __restrict__ w_bias, const float* __restrict__ gamma,
    const float* __restrict__ w_out,
    float* __restrict__ out)
{
    const int i    = blockIdx.x;
    const int tid  = threadIdx.x;
    const int lane = tid & 63;
    const int wv   = tid >> 6;

    __shared__ float    logitsF[H_HEADS][516];
    __shared__ unsigned attnH[H_HEADS][260];    // packed f16 prob pairs
    __shared__ float    distL[N_NODES];
    __shared__ float    vqL[N_NODES][4];
    __shared__ unsigned rbfP[N_NODES][10];      // 8 used (16 bins f16-packed)
    __shared__ float    part8[672][8];
    __shared__ float    qpiL[P3_N];
    __shared__ float    GLf[H_HEADS][FD_N];
    __shared__ float    resL[HPC];
    __shared__ float    abkt[H_HEADS][66];
    __shared__ float    mxP[2][H_HEADS], smP[2][H_HEADS], asP[2][H_HEADS];
    __shared__ unsigned char rdL[N_NODES], pmL[N_NODES];

    if (tid < 96) qpiL[tid] = qpo[(size_t)i*P3_N + tid];
    if (tid >= 128 && tid < 392) {
        const int v = tid - 128;
        abkt[v/66][v%66] = 0.f;
    }
    const int  r_i = resi[i], ch_i = chain[i], ba_i = batch[i];
    const bool m_i = mask_true(maskp, i);
    const float dix = jinfo[(size_t)i*8+4], diy = jinfo[(size_t)i*8+5], diz = jinfo[(size_t)i*8+6];

    const float inv3  = 0.57735026918962576f;
    const float rstep = 0.72727272727272727f;   // 1/1.375

    // ================= Prephase: per-j dist, rbf, mask, vq =================
    {
        const int j = tid;
        const float4 vq4 = *(const float4*)(jinfo + (size_t)j*8);
        const float4 dj4 = *(const float4*)(jinfo + (size_t)j*8 + 4);
        *(float4*)&vqL[j][0] = vq4;
        const float dd0 = dix - dj4.x, dd1 = diy - dj4.y, dd2 = diz - dj4.z;
        const float dist = sqrtf(dd0*dd0 + dd1*dd1 + dd2*dd2 + 1e-6f);
        distL[j] = dist;
#pragma unroll
        for (int p = 0; p < 8; ++p) {
            const float u0 = (dist - (1.375f*(float)(2*p)   + 0.6875f)) * rstep;
            const float u1 = (dist - (1.375f*(float)(2*p+1) + 0.6875f)) * rstep;
            rbfP[j][p] = packh2(__expf(-u0*u0), __expf(-u1*u1));
        }
        const int  rj = resi[j], cj = chain[j], bj = batch[j];
        const bool pm = m_i && mask_true(maskp, j) && (ba_i == bj);
        rdL[j] = (unsigned char)((ch_i != cj) ? 65 : (min(max(r_i - rj, -32), 32) + 32));
        pmL[j] = pm ? 1 : 0;
    }
    __syncthreads();

    // ================= Pass A: logits via dot2 =================
    {
        const int jl = tid >> 4, hA = (tid >> 2) & 3, ks = tid & 3;
        unsigned qvp[4];
        {
            const float4 a = *(const float4*)(qn + (size_t)i*128 + hA*32 + ks*8);
            const float4 b = *(const float4*)(qn + (size_t)i*128 + hA*32 + ks*8 + 4);
            qvp[0] = packh2(a.x, a.y); qvp[1] = packh2(a.z, a.w);
            qvp[2] = packh2(b.x, b.y); qvp[3] = packh2(b.z, b.w);
        }
        unsigned qsp[4] = {0u,0u,0u,0u};
        if (ks < 3) {
            const float ps2 = 2.f * log1pf(expf(gamma[hA])) * (1.0f/12.0f);
            const float4 a = *(const float4*)(qpo + (size_t)i*P3_N + hA*24 + ks*8);
            const float4 b = *(const float4*)(qpo + (size_t)i*P3_N + hA*24 + ks*8 + 4);
            qsp[0] = packh2(ps2*a.x, ps2*a.y); qsp[1] = packh2(ps2*a.z, ps2*a.w);
            qsp[2] = packh2(ps2*b.x, ps2*b.y); qsp[3] = packh2(ps2*b.z, ps2*b.w);
        }
        const unsigned wbp0 = packh2(w_bias[(P3_N + ks*4    )*H_HEADS + hA],
                                     w_bias[(P3_N + ks*4 + 1)*H_HEADS + hA]);
        const unsigned wbp1 = packh2(w_bias[(P3_N + ks*4 + 2)*H_HEADS + hA],
                                     w_bias[(P3_N + ks*4 + 3)*H_HEADS + hA]);
        const float ci = iinfo[i*4 + hA];
        const char* knB = (const char*)knb;
        const char* kpB = (const char*)kpob;

#pragma unroll 2
        for (int jj = 0; jj < 16; ++jj) {
            const int j = jj*32 + jl;
            float l = 0.f;
            {
                const uint4 kk = *(const uint4*)(knB + (size_t)j*256 + hA*64 + ks*16);
                l = dot2u(kk.x, qvp[0], l);
                l = dot2u(kk.y, qvp[1], l);
                l = dot2u(kk.z, qvp[2], l);
                l = dot2u(kk.w, qvp[3], l);
            }
            if (ks < 3) {
                const uint4 kk = *(const uint4*)(kpB + (size_t)j*192 + hA*48 + ks*16);
                l = dot2u(kk.x, qsp[0], l);
                l = dot2u(kk.y, qsp[1], l);
                l = dot2u(kk.z, qsp[2], l);
                l = dot2u(kk.w, qsp[3], l);
            }
            {
                const uint2 rr = *(const uint2*)&rbfP[j][ks*2];
                l = dot2u(rr.x, wbp0, l);
                l = dot2u(rr.y, wbp1, l);
            }
            l += __shfl_xor(l, 1);
            l += __shfl_xor(l, 2);
            if (ks == 0) logitsF[hA][j] = (l + ci + vqL[j][hA]) * inv3;
        }
    }
    __syncthreads();

    // ================= Softmax (wave = (h, half)) + buckets + pack ==========
    {
        const int h = wv >> 1, half = wv & 1;
        float lv[4];
        float mx = -1e30f;
#pragma unroll
        for (int k = 0; k < 4; ++k) {
            const int j = half*256 + lane + 64*k;
            const float v = pmL[j] ? logitsF[h][j] : -1e9f;
            lv[k] = v;
            mx = fmaxf(mx, v);
        }
#pragma unroll
        for (int off = 32; off; off >>= 1) mx = fmaxf(mx, __shfl_xor(mx, off));
        if (lane == 0) mxP[half][h] = mx;
        __syncthreads();
        mx = fmaxf(mxP[0][h], mxP[1][h]);
        float sm = 0.f;
#pragma unroll
        for (int k = 0; k < 4; ++k) sm += __expf(lv[k] - mx);
#pragma unroll
        for (int off = 32; off; off >>= 1) sm += __shfl_xor(sm, off);
        if (lane == 0) smP[half][h] = sm;
        __syncthreads();
        const float rden = 1.f / fmaxf(smP[0][h] + smP[1][h], 1e-37f);
        float p[4];
        float asu = 0.f;
#pragma unroll
        for (int k = 0; k < 4; ++k) {
            const int j = half*256 + lane + 64*k;
            float a = __expf(lv[k] - mx) * rden;
            a = pmL[j] ? a : 0.f;
            p[k] = a;
            asu += a;
            atomicAdd(&abkt[h][rdL[j]], a);
        }
#pragma unroll
        for (int off = 32; off; off >>= 1) asu += __shfl_xor(asu, off);
        if (lane == 0) asP[half][h] = asu;
#pragma unroll
        for (int k = 0; k < 4; ++k) {
            const float po = __shfl_xor(p[k], 1);
            if (!(lane & 1)) {
                const int j = half*256 + lane + 64*k;
                attnH[h][j >> 1] = packh2(p[k], po);
            }
        }
    }
    __syncthreads();

    // ================= Pass B: dot2 rows, 3-shfl partials ====================
    {
        unsigned pjp[4][4];
#pragma unroll
        for (int h = 0; h < 4; ++h)
#pragma unroll
            for (int k = 0; k < 4; ++k)
                pjp[h][k] = attnH[h][lane + 64*k];

        const char* valB = (const char*)valT;
        const char* kpTB = (const char*)kpT;
        const int h1 = wv >> 1;
        const bool wr = ((lane & 7) == 0);
        const int seg = lane >> 3;

        // ---- B1: 28 rows/wave, batch 2 ----
#pragma unroll 2
        for (int ii = 0; ii < 28; ii += 2) {
            const int s0 = wv*28 + ii, s1 = s0 + 1;
            const char* r0 = valB + (size_t)s0*1024;
            const char* r1 = valB + (size_t)s1*1024;
            float a0 = 0.f, a1 = 0.f;
#pragma unroll
            for (int k = 0; k < 4; ++k) {
                const unsigned u0 = *(const unsigned*)(r0 + (lane + 64*k)*4);
                const unsigned u1 = *(const unsigned*)(r1 + (lane + 64*k)*4);
                a0 = dot2u(u0, pjp[h1][k], a0);
                a1 = dot2u(u1, pjp[h1][k], a1);
            }
            a0 += __shfl_xor(a0,1); a0 += __shfl_xor(a0,2); a0 += __shfl_xor(a0,4);
            a1 += __shfl_xor(a1,1); a1 += __shfl_xor(a1,2); a1 += __shfl_xor(a1,4);
            if (wr) { part8[s0][seg] = a0; part8[s1][seg] = a1; }
        }

        // ---- Gk: 12 rows/wave, 4 head-accumulators per row ----
#pragma unroll 2
        for (int ii = 0; ii < 12; ++ii) {
            const int f = wv*12 + ii;
            const char* rw = kpTB + (size_t)f*1024;
            unsigned u[4];
#pragma unroll
            for (int k = 0; k < 4; ++k)
                u[k] = *(const unsigned*)(rw + (lane + 64*k)*4);
            float a[4] = {0.f,0.f,0.f,0.f};
#pragma unroll
            for (int k = 0; k < 4; ++k) {
                a[0] = dot2u(u[k], pjp[0][k], a[0]);
                a[1] = dot2u(u[k], pjp[1][k], a[1]);
                a[2] = dot2u(u[k], pjp[2][k], a[2]);
                a[3] = dot2u(u[k], pjp[3][k], a[3]);
            }
#pragma unroll
            for (int h = 0; h < 4; ++h) {
                a[h] += __shfl_xor(a[h],1); a[h] += __shfl_xor(a[h],2); a[h] += __shfl_xor(a[h],4);
                if (wr) part8[224 + h*P3_N + f][seg] = a[h];
            }
        }

        // ---- rbf-G: 2 bins/wave, 4 head-accumulators per bin ----
        for (int ii = 0; ii < 2; ++ii) {
            const int b = wv*2 + ii;
            const float cb = 1.375f*(float)b + 0.6875f;
            float a[4] = {0.f,0.f,0.f,0.f};
#pragma unroll
            for (int k = 0; k < 4; ++k) {
                const float2 d2 = *(const float2*)&distL[2*(lane + 64*k)];
                const float u0 = (d2.x - cb)*rstep;
                const float u1 = (d2.y - cb)*rstep;
                const unsigned ee = packh2(__expf(-u0*u0), __expf(-u1*u1));
                a[0] = dot2u(ee, pjp[0][k], a[0]);
                a[1] = dot2u(ee, pjp[1][k], a[1]);
                a[2] = dot2u(ee, pjp[2][k], a[2]);
                a[3] = dot2u(ee, pjp[3][k], a[3]);
            }
#pragma unroll
            for (int h = 0; h < 4; ++h) {
                a[h] += __shfl_xor(a[h],1); a[h] += __shfl_xor(a[h],2); a[h] += __shfl_xor(a[h],4);
                if (wr) part8[608 + h*16 + b][seg] = a[h];
            }
        }
    }
    __syncthreads();

    // ================= Combine partials ====================
    for (int t = tid; t < 672; t += 512) {
        const float4 pa = *(const float4*)&part8[t][0];
        const float4 pb = *(const float4*)&part8[t][4];
        const float s = ((pa.x + pa.y) + (pa.z + pa.w)) + ((pb.x + pb.y) + (pb.z + pb.w));
        if (t < 224) {
            resL[t] = s;
        } else if (t < 608) {
            const int v = t - 224, h = v / P3_N, f = v - h*P3_N;
            GLf[h][f] = qpiL[f] * (asP[0][h] + asP[1][h]) - s;
        } else {
            const int v = t - 608;
            GLf[v >> 4][96 + (v & 15)] = s;
        }
    }
    __syncthreads();

    // ================= Epilogue: res = R + emb-buckets + G @ w_pair =========
    if (tid < HPC) {
        const int h = tid / PAIR_CN, c = tid - h*PAIR_CN;
        float r = resL[tid];
#pragma unroll 4
        for (int rr = 0; rr < 66; ++rr) r += abkt[h][rr] * remb[rr*PAIR_CN + c];
        const float* gl = GLf[h];
        const float* wp = w_pair + c;
#pragma unroll 8
        for (int f = 0; f < FD_N; ++f) r += gl[f] * wp[f*PAIR_CN];
        resL[tid] = r;
    }
    __syncthreads();

    // ================= out = res @ w_out (t-split 2-way) ====================
    {
        const int col = tid >> 1, ph = tid & 1;
        float o = 0.f;
#pragma unroll 8
        for (int t = ph*112; t < ph*112 + 112; ++t)
            o += resL[t] * w_out[(size_t)t*DIM + col];
        o += __shfl_xor(o, 1);
        if (ph == 0) out[(size_t)i*DIM + col] = o;
    }
}

// ---------------------------------------------------------------------------
extern "C" void kernel_launch(void* const* d_in, const int* in_sizes, int n_in,
                              void* d_out, int out_size, void* d_ws, size_t ws_size,
                              hipStream_t stream) {
    (void)in_sizes; (void)n_in; (void)out_size; (void)ws_size;
    const float* local = (const float*)d_in[0];
    const float* pos   = (const float*)d_in[1];
    const int*   resi  = (const int*)d_in[2];
    const int*   chain = (const int*)d_in[3];
    const int*   batch = (const int*)d_in[4];
    const void*  maskp = d_in[5];
    const float* qls   = (const float*)d_in[6];
    const float* qlo   = (const float*)d_in[7];
    const float* kls   = (const float*)d_in[8];
    const float* klo   = (const float*)d_in[9];
    const float* w_q   = (const float*)d_in[10];
    const float* b_q   = (const float*)d_in[11];
    const float* w_k   = (const float*)d_in[12];
    const float* b_k   = (const float*)d_in[13];
    const float* w_v   = (const float*)d_in[14];
    const float* b_v   = (const float*)d_in[15];
    const float* w_qp  = (const float*)d_in[16];
    const float* b_qp  = (const float*)d_in[17];
    const float* w_kp  = (const float*)d_in[18];
    const float* b_kp  = (const float*)d_in[19];
    const float* w_vp  = (const float*)d_in[20];
    const float* b_vp  = (const float*)d_in[21];
    const float* remb  = (const float*)d_in[22];
    const float* w_pair= (const float*)d_in[23];
    const float* w_bias= (const float*)d_in[24];
    const float* b_bias= (const float*)d_in[25];
    const float* gamma = (const float*)d_in[26];
    const float* w_out = (const float*)d_in[27];

    char* ws = (char*)d_ws;
    float*     qn    = (float*)(ws);                 // 262144 B
    _Float16*  knb   = (_Float16*)(ws + 262144);     // 131072 B [512][128]
    float*     qpo   = (float*)(ws + 393216);        // 196608 B
    _Float16*  kpob  = (_Float16*)(ws + 589824);     //  98304 B [512][96]
    _Float16*  valT  = (_Float16*)(ws + 688128);     // 229376 B [224][512]
    _Float16*  kpT   = (_Float16*)(ws + 917504);     //  98304 B [96][512]
    float*     jinf  = (float*)(ws + 1015808);       //  16384 B
    float*     iinf  = (float*)(ws + 1032192);       //   8192 B

    proj_kernel<<<N_NODES / 2, 512, 0, stream>>>(
        local, pos, qls, qlo, kls, klo,
        w_q, b_q, w_k, b_k, w_v, b_v,
        w_qp, b_qp, w_kp, b_kp, w_vp, b_vp,
        w_bias, b_bias, gamma,
        qn, knb, qpo, kpob, valT, kpT, jinf, iinf);

    attn_kernel<<<N_NODES, 512, 0, stream>>>(
        qn, knb, qpo, kpob, valT, kpT, jinf, iinf,
        resi, chain, batch, maskp,
        remb, w_pair, w_bias, gamma, w_out,
        (float*)d_out);
}

// Round 10
// 70.732 us; speedup vs baseline: 1.6038x; 1.1177x over previous
//
#include <hip/hip_runtime.h>
#include <hip/hip_bf16.h>
#include <cstddef>

// Problem constants (N, D, S, H, QP, VP) = (512, 256, 32, 4, 8, 8)
#define N_NODES 512
#define DIM     256
#define H_HEADS 4
#define PAIR_CN 56    // S + 3*VP
#define P3_N    96    // H*QP*3
#define FD_N    112   // P3 + 16
#define HPC     224   // H * PAIR_C

typedef _Float16 h2v __attribute__((ext_vector_type(2)));

__device__ __forceinline__ bool mask_true(const void* m, int idx) {
    if (((const unsigned char*)m)[idx] != 0) return true;
    return ((const int*)m)[idx] != 0;
}
__device__ __forceinline__ unsigned packh2(float a, float b) {
    _Float16 ha = (_Float16)a, hb = (_Float16)b;
    unsigned short ua, ub;
    __builtin_memcpy(&ua, &ha, 2); __builtin_memcpy(&ub, &hb, 2);
    return (unsigned)ua | ((unsigned)ub << 16);
}
__device__ __forceinline__ float dot2u(unsigned a, unsigned b, float c) {
#if __has_builtin(__builtin_amdgcn_fdot2)
    h2v ha, hb;
    __builtin_memcpy(&ha, &a, 4);
    __builtin_memcpy(&hb, &b, 4);
    return __builtin_amdgcn_fdot2(ha, hb, c, false);
#else
    _Float16 a0, a1, b0, b1;
    unsigned short t;
    t = (unsigned short)(a & 0xffff); __builtin_memcpy(&a0, &t, 2);
    t = (unsigned short)(a >> 16);    __builtin_memcpy(&a1, &t, 2);
    t = (unsigned short)(b & 0xffff); __builtin_memcpy(&b0, &t, 2);
    t = (unsigned short)(b >> 16);    __builtin_memcpy(&b1, &t, 2);
    return c + (float)a0*(float)b0 + (float)a1*(float)b1;
#endif
}

// ---------------------------------------------------------------------------
// Phase 1: projections + LayerNorm + separable terms. 2 rows/block, grid 256.
// Tables: knb [512][128] f16, kpob [512][96] f16 (row-major, Pass A);
// valT2 [256][224] u32, kpT2 [256][96] u32 (j-pair-major packed f16, Pass B).
// ---------------------------------------------------------------------------
__global__ __launch_bounds__(512) void proj_kernel(
    const float* __restrict__ local, const float* __restrict__ pos,
    const float* __restrict__ qls, const float* __restrict__ qlo,
    const float* __restrict__ kls, const float* __restrict__ klo,
    const float* __restrict__ w_q, const float* __restrict__ b_q,
    const float* __restrict__ w_k, const float* __restrict__ b_k,
    const float* __restrict__ w_v, const float* __restrict__ b_v,
    const float* __restrict__ w_qp, const float* __restrict__ b_qp,
    const float* __restrict__ w_kp, const float* __restrict__ b_kp,
    const float* __restrict__ w_vp, const float* __restrict__ b_vp,
    const float* __restrict__ w_bias, const float* __restrict__ b_bias,
    const float* __restrict__ gamma,
    float* __restrict__ qn, _Float16* __restrict__ knb,
    float* __restrict__ qpo, _Float16* __restrict__ kpob,
    unsigned* __restrict__ valT2, unsigned* __restrict__ kpT2,
    float* __restrict__ jinfo, float* __restrict__ iinfo)
{
    const int i0 = blockIdx.x * 2;
    const int tid = threadIdx.x;

    __shared__ float xL[2][DIM];
    __shared__ float qraw[2][128];
    __shared__ float kraw[2][128];
    __shared__ float stat[2][16];
    __shared__ float qpL[2][P3_N];
    __shared__ float kpbL[2][P3_N];
    __shared__ float wbS[384];

    {
        const int r = tid >> 8, d = tid & 255;
        xL[r][d] = local[(size_t)(i0 + r) * DIM + d];
    }
    if (tid < 384) wbS[tid] = w_bias[tid];
    __syncthreads();

    char* valT2B = (char*)valT2;
    char* kpT2B  = (char*)kpT2;
    const size_t jp = (size_t)(i0 >> 1);

    if (tid < 336) {
        const int colg = tid >> 1, dh = tid & 1;
        const int col = colg * 4;
        const float* w; int width, c, seg;
        if      (col < 128) { w = w_q;  c = col;       width = 128; seg = 0; }
        else if (col < 256) { w = w_k;  c = col - 128; width = 128; seg = 1; }
        else if (col < 384) { w = w_v;  c = col - 256; width = 128; seg = 2; }
        else if (col < 480) { w = w_qp; c = col - 384; width = 96;  seg = 3; }
        else if (col < 576) { w = w_kp; c = col - 480; width = 96;  seg = 4; }
        else                { w = w_vp; c = col - 576; width = 96;  seg = 5; }

        float acc[2][4] = {{0.f,0.f,0.f,0.f},{0.f,0.f,0.f,0.f}};
#pragma unroll 4
        for (int dd = 0; dd < 128; ++dd) {
            const int d = dh*128 + dd;
            float4 wv = *(const float4*)(w + (size_t)d * width + c);
#pragma unroll
            for (int r = 0; r < 2; ++r) {
                float x = xL[r][d];
                acc[r][0] += x * wv.x; acc[r][1] += x * wv.y;
                acc[r][2] += x * wv.z; acc[r][3] += x * wv.w;
            }
        }
#pragma unroll
        for (int r = 0; r < 2; ++r)
#pragma unroll
            for (int e = 0; e < 4; ++e)
                acc[r][e] += __shfl_xor(acc[r][e], 1);

        if (dh == 0) {
            const float cax0 = pos[i0*15+3],     cay0 = pos[i0*15+4],     caz0 = pos[i0*15+5];
            const float cax1 = pos[(i0+1)*15+3], cay1 = pos[(i0+1)*15+4], caz1 = pos[(i0+1)*15+5];
#pragma unroll
            for (int e = 0; e < 4; ++e) {
                const int cc = c + e;
                const float v0 = acc[0][e], v1 = acc[1][e];
                if (seg == 0) {
                    qraw[0][cc] = v0 + b_q[cc];
                    qraw[1][cc] = v1 + b_q[cc];
                } else if (seg == 1) {
                    kraw[0][cc] = v0 + b_k[cc];
                    kraw[1][cc] = v1 + b_k[cc];
                } else if (seg == 2) {
                    const int h = cc >> 5, sc = cc & 31;
                    const int row = h*PAIR_CN + sc;
                    *(unsigned*)(valT2B + jp*896 + row*4) =
                        packh2(v0 + b_v[cc], v1 + b_v[cc]);
                } else if (seg == 3) {
                    const int x = cc % 3;
                    const float cav0 = (x==0)?cax0:((x==1)?cay0:caz0);
                    const float cav1 = (x==0)?cax1:((x==1)?cay1:caz1);
                    const float r0 = v0 + b_qp[cc] + cav0;
                    const float r1 = v1 + b_qp[cc] + cav1;
                    qpo[(size_t)i0*P3_N + cc] = r0;
                    qpo[(size_t)(i0+1)*P3_N + cc] = r1;
                    qpL[0][cc] = r0; qpL[1][cc] = r1;
                } else if (seg == 4) {
                    const int x = cc % 3;
                    const float cav0 = (x==0)?cax0:((x==1)?cay0:caz0);
                    const float cav1 = (x==0)?cax1:((x==1)?cay1:caz1);
                    const float r0 = v0 + b_kp[cc] + cav0;
                    const float r1 = v1 + b_kp[cc] + cav1;
                    const _Float16 h0 = (_Float16)r0, h1 = (_Float16)r1;
                    kpob[(size_t)i0*P3_N + cc]     = h0;
                    kpob[(size_t)(i0+1)*P3_N + cc] = h1;
                    *(unsigned*)(kpT2B + jp*384 + cc*4) = packh2(r0, r1);
                    kpbL[0][cc] = (float)h0;
                    kpbL[1][cc] = (float)h1;
                } else {
                    const int h = cc / 24, rr = cc % 24, x = cc % 3;
                    const float cav0 = (x==0)?cax0:((x==1)?cay0:caz0);
                    const float cav1 = (x==0)?cax1:((x==1)?cay1:caz1);
                    const int row = h*PAIR_CN + 32 + rr;
                    *(unsigned*)(valT2B + jp*896 + row*4) =
                        packh2(v0 + b_vp[cc] + cav0, v1 + b_vp[cc] + cav1);
                }
            }
        }
    }
    __syncthreads();

    if (tid < 16) {
        const int r = tid >> 3, t = tid & 7;
        const float* src = (t < 4) ? qraw[r] : kraw[r];
        const int h = t & 3, base = (t < 4) ? 0 : 8;
        float mu = 0.f;
        for (int c = 0; c < 32; ++c) mu += src[h*32 + c];
        mu *= (1.f/32.f);
        float var = 0.f;
        for (int c = 0; c < 32; ++c) { float d = src[h*32 + c] - mu; var += d*d; }
        var *= (1.f/32.f);
        stat[r][base + h*2 + 0] = mu;
        stat[r][base + h*2 + 1] = var;
    }
    __syncthreads();

    {
        const int r = tid >> 8, u = tid & 255;
        const int i = i0 + r;
        if (u < 128) {
            const int h = u >> 5, sidx = u & 31;
            const float mu = stat[r][h*2], var = stat[r][h*2+1];
            float v = (qraw[r][u] - mu) * rsqrtf(var + 1e-5f) * qls[sidx] + qlo[sidx];
            qn[(size_t)i*128 + u] = v * 0.17677669529663687f;  // * sqrt(1/S)
        } else {
            const int u2 = u - 128, h = u2 >> 5, sidx = u2 & 31;
            const float mu = stat[r][8 + h*2], var = stat[r][9 + h*2];
            float v = (kraw[r][u2] - mu) * rsqrtf(var + 1e-5f) * kls[sidx] + klo[sidx];
            knb[(size_t)i*128 + u2] = (_Float16)v;
        }
    }

    // ---- separable terms, 64 threads = 2 r x 4 h x 8 ks ----
    if (tid < 64) {
        const int r = tid >> 5, h = (tid >> 3) & 3, ks = tid & 7;
        float uacc = 0.f, tacc = 0.f;
#pragma unroll
        for (int f = ks; f < P3_N; f += 8) {
            float wb = wbS[f*4 + h];
            uacc += qpL[r][f] * wb;
            tacc += kpbL[r][f] * wb;
        }
        float nq = 0.f, nk = 0.f;
#pragma unroll
        for (int f = h*24 + ks*3; f < h*24 + ks*3 + 3; ++f) {
            nq += qpL[r][f]*qpL[r][f];
            nk += kpbL[r][f]*kpbL[r][f];
        }
        uacc += __shfl_xor(uacc,1); uacc += __shfl_xor(uacc,2); uacc += __shfl_xor(uacc,4);
        tacc += __shfl_xor(tacc,1); tacc += __shfl_xor(tacc,2); tacc += __shfl_xor(tacc,4);
        nq   += __shfl_xor(nq,1);   nq   += __shfl_xor(nq,2);   nq   += __shfl_xor(nq,4);
        nk   += __shfl_xor(nk,1);   nk   += __shfl_xor(nk,2);   nk   += __shfl_xor(nk,4);
        if (ks == 0) {
            const int n = i0 + r;
            const float ps = log1pf(expf(gamma[h])) * (1.0f/12.0f);
            iinfo[n*4 + h] = -ps*nq + uacc + b_bias[h];
            jinfo[n*8 + h] = -ps*nk - tacc;
            if (h == 0) {
                jinfo[n*8 + 4] = 10.f * pos[n*15 + 3];
                jinfo[n*8 + 5] = 10.f * pos[n*15 + 4];
                jinfo[n*8 + 6] = 10.f * pos[n*15 + 5];
                jinfo[n*8 + 7] = 0.f;
            }
        }
    }
}

// ---------------------------------------------------------------------------
// Phase 2: one block per query row. 512 threads, grid 512.
// Pass B: thread-owned outputs, coalesced j-major loads, no shuffles.
// ---------------------------------------------------------------------------
__global__ __launch_bounds__(512, 4) void attn_kernel(
    const float* __restrict__ qn, const _Float16* __restrict__ knb,
    const float* __restrict__ qpo, const _Float16* __restrict__ kpob,
    const unsigned* __restrict__ valT2, const unsigned* __restrict__ kpT2,
    const float* __restrict__ jinfo, const float* __restrict__ iinfo,
    const int* __restrict__ resi, const int* __restrict__ chain,
    const int* __restrict__ batch, const void* __restrict__ maskp,
    const float* __restrict__ remb, const float* __restrict__ w_pair,
    const float* __restrict__ w_bias, const float* __restrict__ gamma,
    const float* __restrict__ w_out,
    float* __restrict__ out)
{
    const int i    = blockIdx.x;
    const int tid  = threadIdx.x;
    const int lane = tid & 63;
    const int wv   = tid >> 6;

    __shared__ float    logitsF[H_HEADS][516];
    __shared__ unsigned attnH[H_HEADS][260];     // packed f16 prob pairs [jp]
    __shared__ float    vqL[N_NODES][4];
    __shared__ unsigned rbfP[N_NODES][10];       // bin-pair packs (Pass A)
    __shared__ _Float16 rbfT[16][520];           // [bin][j] (Pass B)
    __shared__ float    qpiL[P3_N];
    __shared__ float    GLf[H_HEADS][FD_N];
    __shared__ float    resL[HPC];
    __shared__ float    abkt2[2][H_HEADS][66];
    __shared__ float    mxP[2][H_HEADS], smP[2][H_HEADS], asP[2][H_HEADS];
    __shared__ unsigned char rdL[N_NODES], pmL[N_NODES];

    if (tid < 96) qpiL[tid] = qpo[(size_t)i*P3_N + tid];
    for (int t = tid; t < 2*H_HEADS*66; t += 512) ((float*)abkt2)[t] = 0.f;

    const int  r_i = resi[i], ch_i = chain[i], ba_i = batch[i];
    const bool m_i = mask_true(maskp, i);
    const float dix = jinfo[(size_t)i*8+4], diy = jinfo[(size_t)i*8+5], diz = jinfo[(size_t)i*8+6];

    const float inv3  = 0.57735026918962576f;
    const float rstep = 0.72727272727272727f;   // 1/1.375

    // ================= Prephase: per-j dist, rbf, mask, vq =================
    {
        const int j = tid;
        const float4 vq4 = *(const float4*)(jinfo + (size_t)j*8);
        const float4 dj4 = *(const float4*)(jinfo + (size_t)j*8 + 4);
        *(float4*)&vqL[j][0] = vq4;
        const float dd0 = dix - dj4.x, dd1 = diy - dj4.y, dd2 = diz - dj4.z;
        const float dist = sqrtf(dd0*dd0 + dd1*dd1 + dd2*dd2 + 1e-6f);
#pragma unroll
        for (int p = 0; p < 8; ++p) {
            const float u0 = (dist - (1.375f*(float)(2*p)   + 0.6875f)) * rstep;
            const float u1 = (dist - (1.375f*(float)(2*p+1) + 0.6875f)) * rstep;
            const float e0 = __expf(-u0*u0), e1 = __expf(-u1*u1);
            rbfP[j][p] = packh2(e0, e1);
            rbfT[2*p][j]   = (_Float16)e0;
            rbfT[2*p+1][j] = (_Float16)e1;
        }
        const int  rj = resi[j], cj = chain[j], bj = batch[j];
        const bool pm = m_i && mask_true(maskp, j) && (ba_i == bj);
        rdL[j] = (unsigned char)((ch_i != cj) ? 65 : (min(max(r_i - rj, -32), 32) + 32));
        pmL[j] = pm ? 1 : 0;
    }
    __syncthreads();

    // ================= Pass A: logits via dot2 =================
    {
        const int jl = tid >> 4, hA = (tid >> 2) & 3, ks = tid & 3;
        unsigned qvp[4];
        {
            const float4 a = *(const float4*)(qn + (size_t)i*128 + hA*32 + ks*8);
            const float4 b = *(const float4*)(qn + (size_t)i*128 + hA*32 + ks*8 + 4);
            qvp[0] = packh2(a.x, a.y); qvp[1] = packh2(a.z, a.w);
            qvp[2] = packh2(b.x, b.y); qvp[3] = packh2(b.z, b.w);
        }
        unsigned qsp[4] = {0u,0u,0u,0u};
        if (ks < 3) {
            const float ps2 = 2.f * log1pf(expf(gamma[hA])) * (1.0f/12.0f);
            const float4 a = *(const float4*)(qpo + (size_t)i*P3_N + hA*24 + ks*8);
            const float4 b = *(const float4*)(qpo + (size_t)i*P3_N + hA*24 + ks*8 + 4);
            qsp[0] = packh2(ps2*a.x, ps2*a.y); qsp[1] = packh2(ps2*a.z, ps2*a.w);
            qsp[2] = packh2(ps2*b.x, ps2*b.y); qsp[3] = packh2(ps2*b.z, ps2*b.w);
        }
        const unsigned wbp0 = packh2(w_bias[(P3_N + ks*4    )*H_HEADS + hA],
                                     w_bias[(P3_N + ks*4 + 1)*H_HEADS + hA]);
        const unsigned wbp1 = packh2(w_bias[(P3_N + ks*4 + 2)*H_HEADS + hA],
                                     w_bias[(P3_N + ks*4 + 3)*H_HEADS + hA]);
        const float ci = iinfo[i*4 + hA];
        const char* knB = (const char*)knb;
        const char* kpB = (const char*)kpob;

#pragma unroll 2
        for (int jj = 0; jj < 16; ++jj) {
            const int j = jj*32 + jl;
            float l = 0.f;
            {
                const uint4 kk = *(const uint4*)(knB + (size_t)j*256 + hA*64 + ks*16);
                l = dot2u(kk.x, qvp[0], l);
                l = dot2u(kk.y, qvp[1], l);
                l = dot2u(kk.z, qvp[2], l);
                l = dot2u(kk.w, qvp[3], l);
            }
            if (ks < 3) {
                const uint4 kk = *(const uint4*)(kpB + (size_t)j*192 + hA*48 + ks*16);
                l = dot2u(kk.x, qsp[0], l);
                l = dot2u(kk.y, qsp[1], l);
                l = dot2u(kk.z, qsp[2], l);
                l = dot2u(kk.w, qsp[3], l);
            }
            {
                const uint2 rr = *(const uint2*)&rbfP[j][ks*2];
                l = dot2u(rr.x, wbp0, l);
                l = dot2u(rr.y, wbp1, l);
            }
            l += __shfl_xor(l, 1);
            l += __shfl_xor(l, 2);
            if (ks == 0) logitsF[hA][j] = (l + ci + vqL[j][hA]) * inv3;
        }
    }
    __syncthreads();

    // ================= Softmax (wave = (h, half)) + buckets + pack ==========
    {
        const int h = wv >> 1, half = wv & 1;
        float lv[4];
        float mx = -1e30f;
#pragma unroll
        for (int k = 0; k < 4; ++k) {
            const int j = half*256 + lane + 64*k;
            const float v = pmL[j] ? logitsF[h][j] : -1e9f;
            lv[k] = v;
            mx = fmaxf(mx, v);
        }
#pragma unroll
        for (int off = 32; off; off >>= 1) mx = fmaxf(mx, __shfl_xor(mx, off));
        if (lane == 0) mxP[half][h] = mx;
        __syncthreads();
        mx = fmaxf(mxP[0][h], mxP[1][h]);
        float sm = 0.f;
#pragma unroll
        for (int k = 0; k < 4; ++k) sm += __expf(lv[k] - mx);
#pragma unroll
        for (int off = 32; off; off >>= 1) sm += __shfl_xor(sm, off);
        if (lane == 0) smP[half][h] = sm;
        __syncthreads();
        const float rden = 1.f / fmaxf(smP[0][h] + smP[1][h], 1e-37f);
        float p[4];
        float asu = 0.f;
#pragma unroll
        for (int k = 0; k < 4; ++k) {
            const int j = half*256 + lane + 64*k;
            float a = __expf(lv[k] - mx) * rden;
            a = pmL[j] ? a : 0.f;
            p[k] = a;
            asu += a;
            atomicAdd(&abkt2[half][h][rdL[j]], a);
        }
#pragma unroll
        for (int off = 32; off; off >>= 1) asu += __shfl_xor(asu, off);
        if (lane == 0) asP[half][h] = asu;
#pragma unroll
        for (int k = 0; k < 4; ++k) {
            const float po = __shfl_xor(p[k], 1);
            if (!(lane & 1)) {
                const int j = half*256 + lane + 64*k;
                attnH[h][j >> 1] = packh2(p[k], po);
            }
        }
    }
    __syncthreads();

    // ================= Pass B: thread-owned outputs, no shuffles ============
    if (tid < HPC) {
        // R: slot s = tid; coalesced along s, prob broadcast along jp.
        const int s = tid, h = s / PAIR_CN;
        const char* col = (const char*)valT2 + s*4;   // stride 896 B per jp
        float a0 = 0.f, a1 = 0.f;
#pragma unroll 4
        for (int jp = 0; jp < 256; jp += 2) {
            const unsigned u0 = *(const unsigned*)(col + (size_t)jp*896);
            const unsigned u1 = *(const unsigned*)(col + (size_t)(jp+1)*896);
            a0 = dot2u(u0, attnH[h][jp],   a0);
            a1 = dot2u(u1, attnH[h][jp+1], a1);
        }
        resL[s] = a0 + a1;
    } else if (tid >= 256 && tid < 448) {
        // Gk: f = (tid-256)>>1, half j-range per thread, 4 heads per load.
        const int v = tid - 256, f = v >> 1, half = v & 1;
        const char* col = (const char*)kpT2 + f*4;    // stride 384 B per jp
        float a[4] = {0.f,0.f,0.f,0.f};
#pragma unroll 4
        for (int jp = half*128; jp < half*128 + 128; ++jp) {
            const unsigned u = *(const unsigned*)(col + (size_t)jp*384);
            a[0] = dot2u(u, attnH[0][jp], a[0]);
            a[1] = dot2u(u, attnH[1][jp], a[1]);
            a[2] = dot2u(u, attnH[2][jp], a[2]);
            a[3] = dot2u(u, attnH[3][jp], a[3]);
        }
#pragma unroll
        for (int h = 0; h < 4; ++h) {
            a[h] += __shfl_xor(a[h], 1);
            if (half == 0) GLf[h][f] = qpiL[f] * (asP[0][h] + asP[1][h]) - a[h];
        }
    } else if (tid >= 480 && tid < 496) {
        // rbf-G: b = tid-480, from LDS rbfT, 4 heads per load.
        const int b = tid - 480;
        const char* rowB = (const char*)&rbfT[b][0];
        float a[4] = {0.f,0.f,0.f,0.f};
#pragma unroll 4
        for (int jp = 0; jp < 256; ++jp) {
            const unsigned u = *(const unsigned*)(rowB + jp*4);
            a[0] = dot2u(u, attnH[0][jp], a[0]);
            a[1] = dot2u(u, attnH[1][jp], a[1]);
            a[2] = dot2u(u, attnH[2][jp], a[2]);
            a[3] = dot2u(u, attnH[3][jp], a[3]);
        }
#pragma unroll
        for (int h = 0; h < 4; ++h) GLf[h][96 + b] = a[h];
    }
    __syncthreads();

    // ================= Epilogue: res = R + emb-buckets + G @ w_pair =========
    if (tid < HPC) {
        const int h = tid / PAIR_CN, c = tid - h*PAIR_CN;
        float r = resL[tid];
#pragma unroll 4
        for (int rr = 0; rr < 66; ++rr)
            r += (abkt2[0][h][rr] + abkt2[1][h][rr]) * remb[rr*PAIR_CN + c];
        const float* gl = GLf[h];
        const float* wp = w_pair + c;
#pragma unroll 8
        for (int f = 0; f < FD_N; ++f) r += gl[f] * wp[f*PAIR_CN];
        resL[tid] = r;
    }
    __syncthreads();

    // ================= out = res @ w_out (t-split 2-way) ====================
    {
        const int col = tid >> 1, ph = tid & 1;
        float o = 0.f;
#pragma unroll 8
        for (int t = ph*112; t < ph*112 + 112; ++t)
            o += resL[t] * w_out[(size_t)t*DIM + col];
        o += __shfl_xor(o, 1);
        if (ph == 0) out[(size_t)i*DIM + col] = o;
    }
}

// ---------------------------------------------------------------------------
extern "C" void kernel_launch(void* const* d_in, const int* in_sizes, int n_in,
                              void* d_out, int out_size, void* d_ws, size_t ws_size,
                              hipStream_t stream) {
    (void)in_sizes; (void)n_in; (void)out_size; (void)ws_size;
    const float* local = (const float*)d_in[0];
    const float* pos   = (const float*)d_in[1];
    const int*   resi  = (const int*)d_in[2];
    const int*   chain = (const int*)d_in[3];
    const int*   batch = (const int*)d_in[4];
    const void*  maskp = d_in[5];
    const float* qls   = (const float*)d_in[6];
    const float* qlo   = (const float*)d_in[7];
    const float* kls   = (const float*)d_in[8];
    const float* klo   = (const float*)d_in[9];
    const float* w_q   = (const float*)d_in[10];
    const float* b_q   = (const float*)d_in[11];
    const float* w_k   = (const float*)d_in[12];
    const float* b_k   = (const float*)d_in[13];
    const float* w_v   = (const float*)d_in[14];
    const float* b_v   = (const float*)d_in[15];
    const float* w_qp  = (const float*)d_in[16];
    const float* b_qp  = (const float*)d_in[17];
    const float* w_kp  = (const float*)d_in[18];
    const float* b_kp  = (const float*)d_in[19];
    const float* w_vp  = (const float*)d_in[20];
    const float* b_vp  = (const float*)d_in[21];
    const float* remb  = (const float*)d_in[22];
    const float* w_pair= (const float*)d_in[23];
    const float* w_bias= (const float*)d_in[24];
    const float* b_bias= (const float*)d_in[25];
    const float* gamma = (const float*)d_in[26];
    const float* w_out = (const float*)d_in[27];

    char* ws = (char*)d_ws;
    float*     qn    = (float*)(ws);                 // 262144 B
    _Float16*  knb   = (_Float16*)(ws + 262144);     // 131072 B [512][128]
    float*     qpo   = (float*)(ws + 393216);        // 196608 B
    _Float16*  kpob  = (_Float16*)(ws + 589824);     //  98304 B [512][96]
    unsigned*  valT2 = (unsigned*)(ws + 688128);     // 229376 B [256][224] u32
    unsigned*  kpT2  = (unsigned*)(ws + 917504);     //  98304 B [256][96] u32
    float*     jinf  = (float*)(ws + 1015808);       //  16384 B
    float*     iinf  = (float*)(ws + 1032192);       //   8192 B

    proj_kernel<<<N_NODES / 2, 512, 0, stream>>>(
        local, pos, qls, qlo, kls, klo,
        w_q, b_q, w_k, b_k, w_v, b_v,
        w_qp, b_qp, w_kp, b_kp, w_vp, b_vp,
        w_bias, b_bias, gamma,
        qn, knb, qpo, kpob, valT2, kpT2, jinf, iinf);

    attn_kernel<<<N_NODES, 512, 0, stream>>>(
        qn, knb, qpo, kpob, valT2, kpT2, jinf, iinf,
        resi, chain, batch, maskp,
        remb, w_pair, w_bias, gamma, w_out,
        (float*)d_out);
}

// Round 11
// 69.312 us; speedup vs baseline: 1.6366x; 1.0205x over previous
//
#include <hip/hip_runtime.h>
#include <hip/hip_bf16.h>
#include <cstddef>

// Problem constants (N, D, S, H, QP, VP) = (512, 256, 32, 4, 8, 8)
#define N_NODES 512
#define DIM     256
#define H_HEADS 4
#define PAIR_CN 56    // S + 3*VP
#define P3_N    96    // H*QP*3
#define FD_N    112   // P3 + 16
#define HPC     224   // H * PAIR_C

typedef _Float16 h2v __attribute__((ext_vector_type(2)));

__device__ __forceinline__ bool mask_true(const void* m, int idx) {
    if (((const unsigned char*)m)[idx] != 0) return true;
    return ((const int*)m)[idx] != 0;
}
__device__ __forceinline__ unsigned packh2(float a, float b) {
    _Float16 ha = (_Float16)a, hb = (_Float16)b;
    unsigned short ua, ub;
    __builtin_memcpy(&ua, &ha, 2); __builtin_memcpy(&ub, &hb, 2);
    return (unsigned)ua | ((unsigned)ub << 16);
}
__device__ __forceinline__ float h2lof(unsigned u) {
    unsigned short t = (unsigned short)(u & 0xffff);
    _Float16 h; __builtin_memcpy(&h, &t, 2); return (float)h;
}
__device__ __forceinline__ float h2hif(unsigned u) {
    unsigned short t = (unsigned short)(u >> 16);
    _Float16 h; __builtin_memcpy(&h, &t, 2); return (float)h;
}
__device__ __forceinline__ float dot2u(unsigned a, unsigned b, float c) {
#if __has_builtin(__builtin_amdgcn_fdot2)
    h2v ha, hb;
    __builtin_memcpy(&ha, &a, 4);
    __builtin_memcpy(&hb, &b, 4);
    return __builtin_amdgcn_fdot2(ha, hb, c, false);
#else
    return c + h2lof(a)*h2lof(b) + h2hif(a)*h2hif(b);
#endif
}

// ---------------------------------------------------------------------------
// Phase 1: projections + LayerNorm + separable terms. 2 rows/block, grid 256.
// Tables: knb [512][128] f16, kpob [512][96] f16 (row-major, Pass A);
// valT2 [256][224] u32, kpT2 [256][96] u32 (j-pair-major packed f16, Pass B).
// ---------------------------------------------------------------------------
__global__ __launch_bounds__(512) void proj_kernel(
    const float* __restrict__ local, const float* __restrict__ pos,
    const float* __restrict__ qls, const float* __restrict__ qlo,
    const float* __restrict__ kls, const float* __restrict__ klo,
    const float* __restrict__ w_q, const float* __restrict__ b_q,
    const float* __restrict__ w_k, const float* __restrict__ b_k,
    const float* __restrict__ w_v, const float* __restrict__ b_v,
    const float* __restrict__ w_qp, const float* __restrict__ b_qp,
    const float* __restrict__ w_kp, const float* __restrict__ b_kp,
    const float* __restrict__ w_vp, const float* __restrict__ b_vp,
    const float* __restrict__ w_bias, const float* __restrict__ b_bias,
    const float* __restrict__ gamma,
    float* __restrict__ qn, _Float16* __restrict__ knb,
    float* __restrict__ qpo, _Float16* __restrict__ kpob,
    unsigned* __restrict__ valT2, unsigned* __restrict__ kpT2,
    float* __restrict__ jinfo, float* __restrict__ iinfo)
{
    const int i0 = blockIdx.x * 2;
    const int tid = threadIdx.x;

    __shared__ float xL[2][DIM];
    __shared__ float qraw[2][128];
    __shared__ float kraw[2][128];
    __shared__ float stat[2][16];
    __shared__ float qpL[2][P3_N];
    __shared__ float kpbL[2][P3_N];
    __shared__ float wbS[384];

    {
        const int r = tid >> 8, d = tid & 255;
        xL[r][d] = local[(size_t)(i0 + r) * DIM + d];
    }
    if (tid < 384) wbS[tid] = w_bias[tid];
    __syncthreads();

    char* valT2B = (char*)valT2;
    char* kpT2B  = (char*)kpT2;
    const size_t jp = (size_t)(i0 >> 1);

    if (tid < 336) {
        const int colg = tid >> 1, dh = tid & 1;
        const int col = colg * 4;
        const float* w; int width, c, seg;
        if      (col < 128) { w = w_q;  c = col;       width = 128; seg = 0; }
        else if (col < 256) { w = w_k;  c = col - 128; width = 128; seg = 1; }
        else if (col < 384) { w = w_v;  c = col - 256; width = 128; seg = 2; }
        else if (col < 480) { w = w_qp; c = col - 384; width = 96;  seg = 3; }
        else if (col < 576) { w = w_kp; c = col - 480; width = 96;  seg = 4; }
        else                { w = w_vp; c = col - 576; width = 96;  seg = 5; }

        float acc[2][4] = {{0.f,0.f,0.f,0.f},{0.f,0.f,0.f,0.f}};
#pragma unroll 4
        for (int dd = 0; dd < 128; ++dd) {
            const int d = dh*128 + dd;
            float4 wv = *(const float4*)(w + (size_t)d * width + c);
#pragma unroll
            for (int r = 0; r < 2; ++r) {
                float x = xL[r][d];
                acc[r][0] += x * wv.x; acc[r][1] += x * wv.y;
                acc[r][2] += x * wv.z; acc[r][3] += x * wv.w;
            }
        }
#pragma unroll
        for (int r = 0; r < 2; ++r)
#pragma unroll
            for (int e = 0; e < 4; ++e)
                acc[r][e] += __shfl_xor(acc[r][e], 1);

        if (dh == 0) {
            const float cax0 = pos[i0*15+3],     cay0 = pos[i0*15+4],     caz0 = pos[i0*15+5];
            const float cax1 = pos[(i0+1)*15+3], cay1 = pos[(i0+1)*15+4], caz1 = pos[(i0+1)*15+5];
#pragma unroll
            for (int e = 0; e < 4; ++e) {
                const int cc = c + e;
                const float v0 = acc[0][e], v1 = acc[1][e];
                if (seg == 0) {
                    qraw[0][cc] = v0 + b_q[cc];
                    qraw[1][cc] = v1 + b_q[cc];
                } else if (seg == 1) {
                    kraw[0][cc] = v0 + b_k[cc];
                    kraw[1][cc] = v1 + b_k[cc];
                } else if (seg == 2) {
                    const int h = cc >> 5, sc = cc & 31;
                    const int row = h*PAIR_CN + sc;
                    *(unsigned*)(valT2B + jp*896 + row*4) =
                        packh2(v0 + b_v[cc], v1 + b_v[cc]);
                } else if (seg == 3) {
                    const int x = cc % 3;
                    const float cav0 = (x==0)?cax0:((x==1)?cay0:caz0);
                    const float cav1 = (x==0)?cax1:((x==1)?cay1:caz1);
                    const float r0 = v0 + b_qp[cc] + cav0;
                    const float r1 = v1 + b_qp[cc] + cav1;
                    qpo[(size_t)i0*P3_N + cc] = r0;
                    qpo[(size_t)(i0+1)*P3_N + cc] = r1;
                    qpL[0][cc] = r0; qpL[1][cc] = r1;
                } else if (seg == 4) {
                    const int x = cc % 3;
                    const float cav0 = (x==0)?cax0:((x==1)?cay0:caz0);
                    const float cav1 = (x==0)?cax1:((x==1)?cay1:caz1);
                    const float r0 = v0 + b_kp[cc] + cav0;
                    const float r1 = v1 + b_kp[cc] + cav1;
                    const _Float16 h0 = (_Float16)r0, h1 = (_Float16)r1;
                    kpob[(size_t)i0*P3_N + cc]     = h0;
                    kpob[(size_t)(i0+1)*P3_N + cc] = h1;
                    *(unsigned*)(kpT2B + jp*384 + cc*4) = packh2(r0, r1);
                    kpbL[0][cc] = (float)h0;
                    kpbL[1][cc] = (float)h1;
                } else {
                    const int h = cc / 24, rr = cc % 24, x = cc % 3;
                    const float cav0 = (x==0)?cax0:((x==1)?cay0:caz0);
                    const float cav1 = (x==0)?cax1:((x==1)?cay1:caz1);
                    const int row = h*PAIR_CN + 32 + rr;
                    *(unsigned*)(valT2B + jp*896 + row*4) =
                        packh2(v0 + b_vp[cc] + cav0, v1 + b_vp[cc] + cav1);
                }
            }
        }
    }
    __syncthreads();

    if (tid < 16) {
        const int r = tid >> 3, t = tid & 7;
        const float* src = (t < 4) ? qraw[r] : kraw[r];
        const int h = t & 3, base = (t < 4) ? 0 : 8;
        float mu = 0.f;
        for (int c = 0; c < 32; ++c) mu += src[h*32 + c];
        mu *= (1.f/32.f);
        float var = 0.f;
        for (int c = 0; c < 32; ++c) { float d = src[h*32 + c] - mu; var += d*d; }
        var *= (1.f/32.f);
        stat[r][base + h*2 + 0] = mu;
        stat[r][base + h*2 + 1] = var;
    }
    __syncthreads();

    {
        const int r = tid >> 8, u = tid & 255;
        const int i = i0 + r;
        if (u < 128) {
            const int h = u >> 5, sidx = u & 31;
            const float mu = stat[r][h*2], var = stat[r][h*2+1];
            float v = (qraw[r][u] - mu) * rsqrtf(var + 1e-5f) * qls[sidx] + qlo[sidx];
            qn[(size_t)i*128 + u] = v * 0.17677669529663687f;  // * sqrt(1/S)
        } else {
            const int u2 = u - 128, h = u2 >> 5, sidx = u2 & 31;
            const float mu = stat[r][8 + h*2], var = stat[r][9 + h*2];
            float v = (kraw[r][u2] - mu) * rsqrtf(var + 1e-5f) * kls[sidx] + klo[sidx];
            knb[(size_t)i*128 + u2] = (_Float16)v;
        }
    }

    // ---- separable terms, 64 threads = 2 r x 4 h x 8 ks ----
    if (tid < 64) {
        const int r = tid >> 5, h = (tid >> 3) & 3, ks = tid & 7;
        float uacc = 0.f, tacc = 0.f;
#pragma unroll
        for (int f = ks; f < P3_N; f += 8) {
            float wb = wbS[f*4 + h];
            uacc += qpL[r][f] * wb;
            tacc += kpbL[r][f] * wb;
        }
        float nq = 0.f, nk = 0.f;
#pragma unroll
        for (int f = h*24 + ks*3; f < h*24 + ks*3 + 3; ++f) {
            nq += qpL[r][f]*qpL[r][f];
            nk += kpbL[r][f]*kpbL[r][f];
        }
        uacc += __shfl_xor(uacc,1); uacc += __shfl_xor(uacc,2); uacc += __shfl_xor(uacc,4);
        tacc += __shfl_xor(tacc,1); tacc += __shfl_xor(tacc,2); tacc += __shfl_xor(tacc,4);
        nq   += __shfl_xor(nq,1);   nq   += __shfl_xor(nq,2);   nq   += __shfl_xor(nq,4);
        nk   += __shfl_xor(nk,1);   nk   += __shfl_xor(nk,2);   nk   += __shfl_xor(nk,4);
        if (ks == 0) {
            const int n = i0 + r;
            const float ps = log1pf(expf(gamma[h])) * (1.0f/12.0f);
            iinfo[n*4 + h] = -ps*nq + uacc + b_bias[h];
            jinfo[n*8 + h] = -ps*nk - tacc;
            if (h == 0) {
                jinfo[n*8 + 4] = 10.f * pos[n*15 + 3];
                jinfo[n*8 + 5] = 10.f * pos[n*15 + 4];
                jinfo[n*8 + 6] = 10.f * pos[n*15 + 5];
                jinfo[n*8 + 7] = 0.f;
            }
        }
    }
}

// ---------------------------------------------------------------------------
// Phase 2: one block per query row. 512 threads, grid 512.
// Deep-unrolled Pass B for MLP; lean LDS (~37 KB).
// ---------------------------------------------------------------------------
__global__ __launch_bounds__(512, 4) void attn_kernel(
    const float* __restrict__ qn, const _Float16* __restrict__ knb,
    const float* __restrict__ qpo, const _Float16* __restrict__ kpob,
    const unsigned* __restrict__ valT2, const unsigned* __restrict__ kpT2,
    const float* __restrict__ jinfo, const float* __restrict__ iinfo,
    const int* __restrict__ resi, const int* __restrict__ chain,
    const int* __restrict__ batch, const void* __restrict__ maskp,
    const float* __restrict__ remb, const float* __restrict__ w_pair,
    const float* __restrict__ w_bias, const float* __restrict__ gamma,
    const float* __restrict__ w_out,
    float* __restrict__ out)
{
    const int i    = blockIdx.x;
    const int tid  = threadIdx.x;
    const int lane = tid & 63;
    const int wv   = tid >> 6;

    __shared__ float    logitsF[H_HEADS][516];
    __shared__ unsigned attnH[H_HEADS][260];     // packed f16 prob pairs [jp]
    __shared__ unsigned rbfP[N_NODES][9];        // 8 bin-pair packs, stride 9
    __shared__ float    qpiL[P3_N];
    __shared__ float    GLf[H_HEADS][FD_N];
    __shared__ float    resL[HPC];
    __shared__ float    abkt2[2][H_HEADS][66];
    __shared__ float    mxP[2][H_HEADS], smP[2][H_HEADS], asP[2][H_HEADS];
    __shared__ unsigned char rdL[N_NODES], pmL[N_NODES];

    if (tid < 96) qpiL[tid] = qpo[(size_t)i*P3_N + tid];
    for (int t = tid; t < 2*H_HEADS*66; t += 512) ((float*)abkt2)[t] = 0.f;

    const int  r_i = resi[i], ch_i = chain[i], ba_i = batch[i];
    const bool m_i = mask_true(maskp, i);
    const float dix = jinfo[(size_t)i*8+4], diy = jinfo[(size_t)i*8+5], diz = jinfo[(size_t)i*8+6];

    const float inv3  = 0.57735026918962576f;
    const float rstep = 0.72727272727272727f;   // 1/1.375

    // ================= Prephase: per-j dist, rbf, mask =================
    {
        const int j = tid;
        const float4 dj4 = *(const float4*)(jinfo + (size_t)j*8 + 4);
        const float dd0 = dix - dj4.x, dd1 = diy - dj4.y, dd2 = diz - dj4.z;
        const float dist = sqrtf(dd0*dd0 + dd1*dd1 + dd2*dd2 + 1e-6f);
#pragma unroll
        for (int p = 0; p < 8; ++p) {
            const float u0 = (dist - (1.375f*(float)(2*p)   + 0.6875f)) * rstep;
            const float u1 = (dist - (1.375f*(float)(2*p+1) + 0.6875f)) * rstep;
            rbfP[j][p] = packh2(__expf(-u0*u0), __expf(-u1*u1));
        }
        const int  rj = resi[j], cj = chain[j], bj = batch[j];
        const bool pm = m_i && mask_true(maskp, j) && (ba_i == bj);
        rdL[j] = (unsigned char)((ch_i != cj) ? 65 : (min(max(r_i - rj, -32), 32) + 32));
        pmL[j] = pm ? 1 : 0;
    }
    __syncthreads();

    // ================= Pass A: logits via dot2 =================
    {
        const int jl = tid >> 4, hA = (tid >> 2) & 3, ks = tid & 3;
        unsigned qvp[4];
        {
            const float4 a = *(const float4*)(qn + (size_t)i*128 + hA*32 + ks*8);
            const float4 b = *(const float4*)(qn + (size_t)i*128 + hA*32 + ks*8 + 4);
            qvp[0] = packh2(a.x, a.y); qvp[1] = packh2(a.z, a.w);
            qvp[2] = packh2(b.x, b.y); qvp[3] = packh2(b.z, b.w);
        }
        unsigned qsp[4] = {0u,0u,0u,0u};
        if (ks < 3) {
            const float ps2 = 2.f * log1pf(expf(gamma[hA])) * (1.0f/12.0f);
            const float4 a = *(const float4*)(qpo + (size_t)i*P3_N + hA*24 + ks*8);
            const float4 b = *(const float4*)(qpo + (size_t)i*P3_N + hA*24 + ks*8 + 4);
            qsp[0] = packh2(ps2*a.x, ps2*a.y); qsp[1] = packh2(ps2*a.z, ps2*a.w);
            qsp[2] = packh2(ps2*b.x, ps2*b.y); qsp[3] = packh2(ps2*b.z, ps2*b.w);
        }
        const unsigned wbp0 = packh2(w_bias[(P3_N + ks*4    )*H_HEADS + hA],
                                     w_bias[(P3_N + ks*4 + 1)*H_HEADS + hA]);
        const unsigned wbp1 = packh2(w_bias[(P3_N + ks*4 + 2)*H_HEADS + hA],
                                     w_bias[(P3_N + ks*4 + 3)*H_HEADS + hA]);
        const float ci = iinfo[i*4 + hA];
        const char* knB = (const char*)knb;
        const char* kpB = (const char*)kpob;

#pragma unroll 4
        for (int jj = 0; jj < 16; ++jj) {
            const int j = jj*32 + jl;
            float l = 0.f;
            {
                const uint4 kk = *(const uint4*)(knB + (size_t)j*256 + hA*64 + ks*16);
                l = dot2u(kk.x, qvp[0], l);
                l = dot2u(kk.y, qvp[1], l);
                l = dot2u(kk.z, qvp[2], l);
                l = dot2u(kk.w, qvp[3], l);
            }
            if (ks < 3) {
                const uint4 kk = *(const uint4*)(kpB + (size_t)j*192 + hA*48 + ks*16);
                l = dot2u(kk.x, qsp[0], l);
                l = dot2u(kk.y, qsp[1], l);
                l = dot2u(kk.z, qsp[2], l);
                l = dot2u(kk.w, qsp[3], l);
            }
            {
                const unsigned r0 = rbfP[j][ks*2], r1 = rbfP[j][ks*2 + 1];
                l = dot2u(r0, wbp0, l);
                l = dot2u(r1, wbp1, l);
            }
            l += __shfl_xor(l, 1);
            l += __shfl_xor(l, 2);
            if (ks == 0) logitsF[hA][j] = (l + ci + jinfo[(size_t)j*8 + hA]) * inv3;
        }
    }
    __syncthreads();

    // ================= Softmax (wave = (h, half)) + buckets + pack ==========
    {
        const int h = wv >> 1, half = wv & 1;
        float lv[4];
        float mx = -1e30f;
#pragma unroll
        for (int k = 0; k < 4; ++k) {
            const int j = half*256 + lane + 64*k;
            const float v = pmL[j] ? logitsF[h][j] : -1e9f;
            lv[k] = v;
            mx = fmaxf(mx, v);
        }
#pragma unroll
        for (int off = 32; off; off >>= 1) mx = fmaxf(mx, __shfl_xor(mx, off));
        if (lane == 0) mxP[half][h] = mx;
        __syncthreads();
        mx = fmaxf(mxP[0][h], mxP[1][h]);
        float sm = 0.f;
#pragma unroll
        for (int k = 0; k < 4; ++k) sm += __expf(lv[k] - mx);
#pragma unroll
        for (int off = 32; off; off >>= 1) sm += __shfl_xor(sm, off);
        if (lane == 0) smP[half][h] = sm;
        __syncthreads();
        const float rden = 1.f / fmaxf(smP[0][h] + smP[1][h], 1e-37f);
        float p[4];
        float asu = 0.f;
#pragma unroll
        for (int k = 0; k < 4; ++k) {
            const int j = half*256 + lane + 64*k;
            float a = __expf(lv[k] - mx) * rden;
            a = pmL[j] ? a : 0.f;
            p[k] = a;
            asu += a;
            atomicAdd(&abkt2[half][h][rdL[j]], a);
        }
#pragma unroll
        for (int off = 32; off; off >>= 1) asu += __shfl_xor(asu, off);
        if (lane == 0) asP[half][h] = asu;
#pragma unroll
        for (int k = 0; k < 4; ++k) {
            const float po = __shfl_xor(p[k], 1);
            if (!(lane & 1)) {
                const int j = half*256 + lane + 64*k;
                attnH[h][j >> 1] = packh2(p[k], po);
            }
        }
    }
    __syncthreads();

    // ================= Pass B: thread-owned outputs, deep MLP ==============
    if (tid < HPC) {
        // R: slot s = tid; 4 independent chains, 32 loads in flight.
        const int s = tid, h = s / PAIR_CN;
        const char* col = (const char*)valT2 + s*4;   // stride 896 B per jp
        float a0 = 0.f, a1 = 0.f, a2 = 0.f, a3 = 0.f;
#pragma unroll 8
        for (int jp = 0; jp < 256; jp += 4) {
            const unsigned u0 = *(const unsigned*)(col + (size_t)jp*896);
            const unsigned u1 = *(const unsigned*)(col + (size_t)(jp+1)*896);
            const unsigned u2 = *(const unsigned*)(col + (size_t)(jp+2)*896);
            const unsigned u3 = *(const unsigned*)(col + (size_t)(jp+3)*896);
            a0 = dot2u(u0, attnH[h][jp],   a0);
            a1 = dot2u(u1, attnH[h][jp+1], a1);
            a2 = dot2u(u2, attnH[h][jp+2], a2);
            a3 = dot2u(u3, attnH[h][jp+3], a3);
        }
        resL[s] = (a0 + a1) + (a2 + a3);
    } else if (tid >= 256 && tid < 448) {
        // Gk: f = (tid-256)>>1, half j-range; 4 heads per load, unroll 8.
        const int v = tid - 256, f = v >> 1, half = v & 1;
        const char* col = (const char*)kpT2 + f*4;    // stride 384 B per jp
        float a[4] = {0.f,0.f,0.f,0.f};
#pragma unroll 8
        for (int jp = half*128; jp < half*128 + 128; ++jp) {
            const unsigned u = *(const unsigned*)(col + (size_t)jp*384);
            a[0] = dot2u(u, attnH[0][jp], a[0]);
            a[1] = dot2u(u, attnH[1][jp], a[1]);
            a[2] = dot2u(u, attnH[2][jp], a[2]);
            a[3] = dot2u(u, attnH[3][jp], a[3]);
        }
#pragma unroll
        for (int h = 0; h < 4; ++h) {
            a[h] += __shfl_xor(a[h], 1);
            if (half == 0) GLf[h][f] = qpiL[f] * (asP[0][h] + asP[1][h]) - a[h];
        }
    } else if (tid >= 448 && tid < 512) {
        // rbf-G: 64 threads = (b, quarter); 64 jp each, 2-shfl combine.
        const int idx = tid - 448, b = idx >> 2, q = idx & 3;
        const int w = b >> 1;
        const bool hi = (b & 1);
        float a[4] = {0.f,0.f,0.f,0.f};
#pragma unroll 4
        for (int jp = q*64; jp < q*64 + 64; ++jp) {
            const unsigned r0 = rbfP[2*jp][w];
            const unsigned r1 = rbfP[2*jp + 1][w];
            const float e0 = hi ? h2hif(r0) : h2lof(r0);
            const float e1 = hi ? h2hif(r1) : h2lof(r1);
            const unsigned ee = packh2(e0, e1);
            a[0] = dot2u(ee, attnH[0][jp], a[0]);
            a[1] = dot2u(ee, attnH[1][jp], a[1]);
            a[2] = dot2u(ee, attnH[2][jp], a[2]);
            a[3] = dot2u(ee, attnH[3][jp], a[3]);
        }
#pragma unroll
        for (int h = 0; h < 4; ++h) {
            a[h] += __shfl_xor(a[h], 1);
            a[h] += __shfl_xor(a[h], 2);
            if (q == 0) GLf[h][96 + b] = a[h];
        }
    }
    __syncthreads();

    // ================= Epilogue: res = R + emb-buckets + G @ w_pair =========
    if (tid < HPC) {
        const int h = tid / PAIR_CN, c = tid - h*PAIR_CN;
        float r = resL[tid];
#pragma unroll 8
        for (int rr = 0; rr < 66; ++rr)
            r += (abkt2[0][h][rr] + abkt2[1][h][rr]) * remb[rr*PAIR_CN + c];
        const float* gl = GLf[h];
        const float* wp = w_pair + c;
#pragma unroll 8
        for (int f = 0; f < FD_N; ++f) r += gl[f] * wp[f*PAIR_CN];
        resL[tid] = r;
    }
    __syncthreads();

    // ================= out = res @ w_out (t-split 2-way) ====================
    {
        const int col = tid >> 1, ph = tid & 1;
        float o = 0.f;
#pragma unroll 8
        for (int t = ph*112; t < ph*112 + 112; ++t)
            o += resL[t] * w_out[(size_t)t*DIM + col];
        o += __shfl_xor(o, 1);
        if (ph == 0) out[(size_t)i*DIM + col] = o;
    }
}

// ---------------------------------------------------------------------------
extern "C" void kernel_launch(void* const* d_in, const int* in_sizes, int n_in,
                              void* d_out, int out_size, void* d_ws, size_t ws_size,
                              hipStream_t stream) {
    (void)in_sizes; (void)n_in; (void)out_size; (void)ws_size;
    const float* local = (const float*)d_in[0];
    const float* pos   = (const float*)d_in[1];
    const int*   resi  = (const int*)d_in[2];
    const int*   chain = (const int*)d_in[3];
    const int*   batch = (const int*)d_in[4];
    const void*  maskp = d_in[5];
    const float* qls   = (const float*)d_in[6];
    const float* qlo   = (const float*)d_in[7];
    const float* kls   = (const float*)d_in[8];
    const float* klo   = (const float*)d_in[9];
    const float* w_q   = (const float*)d_in[10];
    const float* b_q   = (const float*)d_in[11];
    const float* w_k   = (const float*)d_in[12];
    const float* b_k   = (const float*)d_in[13];
    const float* w_v   = (const float*)d_in[14];
    const float* b_v   = (const float*)d_in[15];
    const float* w_qp  = (const float*)d_in[16];
    const float* b_qp  = (const float*)d_in[17];
    const float* w_kp  = (const float*)d_in[18];
    const float* b_kp  = (const float*)d_in[19];
    const float* w_vp  = (const float*)d_in[20];
    const float* b_vp  = (const float*)d_in[21];
    const float* remb  = (const float*)d_in[22];
    const float* w_pair= (const float*)d_in[23];
    const float* w_bias= (const float*)d_in[24];
    const float* b_bias= (const float*)d_in[25];
    const float* gamma = (const float*)d_in[26];
    const float* w_out = (const float*)d_in[27];

    char* ws = (char*)d_ws;
    float*     qn    = (float*)(ws);                 // 262144 B
    _Float16*  knb   = (_Float16*)(ws + 262144);     // 131072 B [512][128]
    float*     qpo   = (float*)(ws + 393216);        // 196608 B
    _Float16*  kpob  = (_Float16*)(ws + 589824);     //  98304 B [512][96]
    unsigned*  valT2 = (unsigned*)(ws + 688128);     // 229376 B [256][224] u32
    unsigned*  kpT2  = (unsigned*)(ws + 917504);     //  98304 B [256][96] u32
    float*     jinf  = (float*)(ws + 1015808);       //  16384 B
    float*     iinf  = (float*)(ws + 1032192);       //   8192 B

    proj_kernel<<<N_NODES / 2, 512, 0, stream>>>(
        local, pos, qls, qlo, kls, klo,
        w_q, b_q, w_k, b_k, w_v, b_v,
        w_qp, b_qp, w_kp, b_kp, w_vp, b_vp,
        w_bias, b_bias, gamma,
        qn, knb, qpo, kpob, valT2, kpT2, jinf, iinf);

    attn_kernel<<<N_NODES, 512, 0, stream>>>(
        qn, knb, qpo, kpob, valT2, kpT2, jinf, iinf,
        resi, chain, batch, maskp,
        remb, w_pair, w_bias, gamma, w_out,
        (float*)d_out);
}

// Round 12
// 62.445 us; speedup vs baseline: 1.8166x; 1.1100x over previous
//
#include <hip/hip_runtime.h>
#include <hip/hip_bf16.h>
#include <cstddef>

// Problem constants (N, D, S, H, QP, VP) = (512, 256, 32, 4, 8, 8)
#define N_NODES 512
#define DIM     256
#define H_HEADS 4
#define PAIR_CN 56    // S + 3*VP
#define P3_N    96    // H*QP*3
#define FD_N    112   // P3 + 16
#define HPC     224   // H * PAIR_C

typedef _Float16 h2v __attribute__((ext_vector_type(2)));

__device__ __forceinline__ bool mask_true(const void* m, int idx) {
    if (((const unsigned char*)m)[idx] != 0) return true;
    return ((const int*)m)[idx] != 0;
}
__device__ __forceinline__ unsigned packh2(float a, float b) {
    _Float16 ha = (_Float16)a, hb = (_Float16)b;
    unsigned short ua, ub;
    __builtin_memcpy(&ua, &ha, 2); __builtin_memcpy(&ub, &hb, 2);
    return (unsigned)ua | ((unsigned)ub << 16);
}
__device__ __forceinline__ float dot2u(unsigned a, unsigned b, float c) {
#if __has_builtin(__builtin_amdgcn_fdot2)
    h2v ha, hb;
    __builtin_memcpy(&ha, &a, 4);
    __builtin_memcpy(&hb, &b, 4);
    return __builtin_amdgcn_fdot2(ha, hb, c, false);
#else
    unsigned short t;
    _Float16 a0, a1, b0, b1;
    t = (unsigned short)(a & 0xffff); __builtin_memcpy(&a0, &t, 2);
    t = (unsigned short)(a >> 16);    __builtin_memcpy(&a1, &t, 2);
    t = (unsigned short)(b & 0xffff); __builtin_memcpy(&b0, &t, 2);
    t = (unsigned short)(b >> 16);    __builtin_memcpy(&b1, &t, 2);
    return c + (float)a0*(float)b0 + (float)a1*(float)b1;
#endif
}

// ---------------------------------------------------------------------------
// Phase 1: projections + LayerNorm + separable terms. 2 rows/block, grid 256.
// Tables:
//   knT2  [64 d2][512 j]  u32 (f16 pair over dims d=2*d2,2*d2+1)   - Pass A
//   kpT2f [48 f2][512 j]  u32 (f16 pair over f=2*f2,2*f2+1)        - Pass A
//   valT2 [256 jp][224 s] u32 (f16 pair over j=2*jp,2*jp+1)        - Pass B
//   kpT2  [256 jp][96 f]  u32 (f16 pair over j)                    - Pass B
// ---------------------------------------------------------------------------
__global__ __launch_bounds__(512) void proj_kernel(
    const float* __restrict__ local, const float* __restrict__ pos,
    const float* __restrict__ qls, const float* __restrict__ qlo,
    const float* __restrict__ kls, const float* __restrict__ klo,
    const float* __restrict__ w_q, const float* __restrict__ b_q,
    const float* __restrict__ w_k, const float* __restrict__ b_k,
    const float* __restrict__ w_v, const float* __restrict__ b_v,
    const float* __restrict__ w_qp, const float* __restrict__ b_qp,
    const float* __restrict__ w_kp, const float* __restrict__ b_kp,
    const float* __restrict__ w_vp, const float* __restrict__ b_vp,
    const float* __restrict__ w_bias, const float* __restrict__ b_bias,
    const float* __restrict__ gamma,
    float* __restrict__ qn, unsigned* __restrict__ knT2,
    float* __restrict__ qpo, unsigned* __restrict__ kpT2f,
    unsigned* __restrict__ valT2, unsigned* __restrict__ kpT2,
    float* __restrict__ jinfo, float* __restrict__ iinfo)
{
    const int i0 = blockIdx.x * 2;
    const int tid = threadIdx.x;

    __shared__ float xL[2][DIM];
    __shared__ float qraw[2][128];
    __shared__ float kraw[2][128];
    __shared__ float stat[2][16];
    __shared__ float qpL[2][P3_N];
    __shared__ float kpbL[2][P3_N];
    __shared__ float wbS[384];

    {
        const int r = tid >> 8, d = tid & 255;
        xL[r][d] = local[(size_t)(i0 + r) * DIM + d];
    }
    if (tid < 384) wbS[tid] = w_bias[tid];
    __syncthreads();

    char* valT2B = (char*)valT2;
    char* kpT2B  = (char*)kpT2;
    const size_t jp = (size_t)(i0 >> 1);

    if (tid < 336) {
        const int colg = tid >> 1, dh = tid & 1;
        const int col = colg * 4;
        const float* w; int width, c, seg;
        if      (col < 128) { w = w_q;  c = col;       width = 128; seg = 0; }
        else if (col < 256) { w = w_k;  c = col - 128; width = 128; seg = 1; }
        else if (col < 384) { w = w_v;  c = col - 256; width = 128; seg = 2; }
        else if (col < 480) { w = w_qp; c = col - 384; width = 96;  seg = 3; }
        else if (col < 576) { w = w_kp; c = col - 480; width = 96;  seg = 4; }
        else                { w = w_vp; c = col - 576; width = 96;  seg = 5; }

        float acc[2][4] = {{0.f,0.f,0.f,0.f},{0.f,0.f,0.f,0.f}};
#pragma unroll 4
        for (int dd = 0; dd < 128; ++dd) {
            const int d = dh*128 + dd;
            float4 wv = *(const float4*)(w + (size_t)d * width + c);
#pragma unroll
            for (int r = 0; r < 2; ++r) {
                float x = xL[r][d];
                acc[r][0] += x * wv.x; acc[r][1] += x * wv.y;
                acc[r][2] += x * wv.z; acc[r][3] += x * wv.w;
            }
        }
#pragma unroll
        for (int r = 0; r < 2; ++r)
#pragma unroll
            for (int e = 0; e < 4; ++e)
                acc[r][e] += __shfl_xor(acc[r][e], 1);

        if (dh == 0) {
            const float cax0 = pos[i0*15+3],     cay0 = pos[i0*15+4],     caz0 = pos[i0*15+5];
            const float cax1 = pos[(i0+1)*15+3], cay1 = pos[(i0+1)*15+4], caz1 = pos[(i0+1)*15+5];
            float fr0[4], fr1[4];
            bool isKp = (seg == 4);
#pragma unroll
            for (int e = 0; e < 4; ++e) {
                const int cc = c + e;
                const float v0 = acc[0][e], v1 = acc[1][e];
                if (seg == 0) {
                    qraw[0][cc] = v0 + b_q[cc];
                    qraw[1][cc] = v1 + b_q[cc];
                } else if (seg == 1) {
                    kraw[0][cc] = v0 + b_k[cc];
                    kraw[1][cc] = v1 + b_k[cc];
                } else if (seg == 2) {
                    const int h = cc >> 5, sc = cc & 31;
                    const int row = h*PAIR_CN + sc;
                    *(unsigned*)(valT2B + jp*896 + row*4) =
                        packh2(v0 + b_v[cc], v1 + b_v[cc]);
                } else if (seg == 3) {
                    const int x = cc % 3;
                    const float cav0 = (x==0)?cax0:((x==1)?cay0:caz0);
                    const float cav1 = (x==0)?cax1:((x==1)?cay1:caz1);
                    const float r0 = v0 + b_qp[cc] + cav0;
                    const float r1 = v1 + b_qp[cc] + cav1;
                    qpo[(size_t)i0*P3_N + cc] = r0;
                    qpo[(size_t)(i0+1)*P3_N + cc] = r1;
                    qpL[0][cc] = r0; qpL[1][cc] = r1;
                } else if (seg == 4) {
                    const int x = cc % 3;
                    const float cav0 = (x==0)?cax0:((x==1)?cay0:caz0);
                    const float cav1 = (x==0)?cax1:((x==1)?cay1:caz1);
                    const float r0 = v0 + b_kp[cc] + cav0;
                    const float r1 = v1 + b_kp[cc] + cav1;
                    fr0[e] = r0; fr1[e] = r1;
                    *(unsigned*)(kpT2B + jp*384 + cc*4) = packh2(r0, r1);
                    kpbL[0][cc] = (float)(_Float16)r0;
                    kpbL[1][cc] = (float)(_Float16)r1;
                } else {
                    const int h = cc / 24, rr = cc % 24, x = cc % 3;
                    const float cav0 = (x==0)?cax0:((x==1)?cay0:caz0);
                    const float cav1 = (x==0)?cax1:((x==1)?cay1:caz1);
                    const int row = h*PAIR_CN + 32 + rr;
                    *(unsigned*)(valT2B + jp*896 + row*4) =
                        packh2(v0 + b_vp[cc] + cav0, v1 + b_vp[cc] + cav1);
                }
            }
            if (isKp) {
                const int f2 = c >> 1;   // c multiple of 4
                kpT2f[(size_t)(f2    )*N_NODES + i0    ] = packh2(fr0[0], fr0[1]);
                kpT2f[(size_t)(f2 + 1)*N_NODES + i0    ] = packh2(fr0[2], fr0[3]);
                kpT2f[(size_t)(f2    )*N_NODES + i0 + 1] = packh2(fr1[0], fr1[1]);
                kpT2f[(size_t)(f2 + 1)*N_NODES + i0 + 1] = packh2(fr1[2], fr1[3]);
            }
        }
    }
    __syncthreads();

    if (tid < 16) {
        const int r = tid >> 3, t = tid & 7;
        const float* src = (t < 4) ? qraw[r] : kraw[r];
        const int h = t & 3, base = (t < 4) ? 0 : 8;
        float mu = 0.f;
        for (int c = 0; c < 32; ++c) mu += src[h*32 + c];
        mu *= (1.f/32.f);
        float var = 0.f;
        for (int c = 0; c < 32; ++c) { float d = src[h*32 + c] - mu; var += d*d; }
        var *= (1.f/32.f);
        stat[r][base + h*2 + 0] = mu;
        stat[r][base + h*2 + 1] = var;
    }
    __syncthreads();

    {
        const int r = tid >> 8, u = tid & 255;
        const int i = i0 + r;
        if (u < 128) {
            const int h = u >> 5, sidx = u & 31;
            const float mu = stat[r][h*2], var = stat[r][h*2+1];
            float v = (qraw[r][u] - mu) * rsqrtf(var + 1e-5f) * qls[sidx] + qlo[sidx];
            qn[(size_t)i*128 + u] = v * 0.17677669529663687f;  // * sqrt(1/S)
        } else {
            const int u2 = u - 128, h = u2 >> 5, sidx = u2 & 31;
            const float mu = stat[r][8 + h*2], var = stat[r][9 + h*2];
            float v = (kraw[r][u2] - mu) * rsqrtf(var + 1e-5f) * kls[sidx] + klo[sidx];
            const float vo = __shfl_xor(v, 1);
            if (!(u2 & 1))
                knT2[(size_t)(u2 >> 1)*N_NODES + i] = packh2(v, vo);
        }
    }

    // ---- separable terms, 64 threads = 2 r x 4 h x 8 ks ----
    if (tid < 64) {
        const int r = tid >> 5, h = (tid >> 3) & 3, ks = tid & 7;
        float uacc = 0.f, tacc = 0.f;
#pragma unroll
        for (int f = ks; f < P3_N; f += 8) {
            float wb = wbS[f*4 + h];
            uacc += qpL[r][f] * wb;
            tacc += kpbL[r][f] * wb;
        }
        float nq = 0.f, nk = 0.f;
#pragma unroll
        for (int f = h*24 + ks*3; f < h*24 + ks*3 + 3; ++f) {
            nq += qpL[r][f]*qpL[r][f];
            nk += kpbL[r][f]*kpbL[r][f];
        }
        uacc += __shfl_xor(uacc,1); uacc += __shfl_xor(uacc,2); uacc += __shfl_xor(uacc,4);
        tacc += __shfl_xor(tacc,1); tacc += __shfl_xor(tacc,2); tacc += __shfl_xor(tacc,4);
        nq   += __shfl_xor(nq,1);   nq   += __shfl_xor(nq,2);   nq   += __shfl_xor(nq,4);
        nk   += __shfl_xor(nk,1);   nk   += __shfl_xor(nk,2);   nk   += __shfl_xor(nk,4);
        if (ks == 0) {
            const int n = i0 + r;
            const float ps = log1pf(expf(gamma[h])) * (1.0f/12.0f);
            iinfo[n*4 + h] = -ps*nq + uacc + b_bias[h];
            jinfo[n*8 + h] = -ps*nk - tacc;
            if (h == 0) {
                jinfo[n*8 + 4] = 10.f * pos[n*15 + 3];
                jinfo[n*8 + 5] = 10.f * pos[n*15 + 4];
                jinfo[n*8 + 6] = 10.f * pos[n*15 + 5];
                jinfo[n*8 + 7] = 0.f;
            }
        }
    }
}

// ---------------------------------------------------------------------------
// Phase 2: one block per query row. 512 threads, grid 512.
// Pass A: thread = j, d-major coalesced streams, logits in registers.
// ---------------------------------------------------------------------------
__global__ __launch_bounds__(512, 4) void attn_kernel(
    const float* __restrict__ qn, const unsigned* __restrict__ knT2,
    const float* __restrict__ qpo, const unsigned* __restrict__ kpT2f,
    const unsigned* __restrict__ valT2, const unsigned* __restrict__ kpT2,
    const float* __restrict__ jinfo, const float* __restrict__ iinfo,
    const int* __restrict__ resi, const int* __restrict__ chain,
    const int* __restrict__ batch, const void* __restrict__ maskp,
    const float* __restrict__ remb, const float* __restrict__ w_pair,
    const float* __restrict__ w_bias, const float* __restrict__ gamma,
    const float* __restrict__ w_out,
    float* __restrict__ out)
{
    const int i    = blockIdx.x;
    const int tid  = threadIdx.x;
    const int lane = tid & 63;
    const int wv   = tid >> 6;

    __shared__ unsigned qpkL[64];        // packed q (kn dims)
    __shared__ unsigned qspkL[48];       // packed 2ps*qp
    __shared__ unsigned wbPk[H_HEADS][8];
    __shared__ unsigned rbfP[N_NODES][9];
    __shared__ unsigned attnH[H_HEADS][260];
    __shared__ float    mxW[8][H_HEADS];
    __shared__ float    smW[8][H_HEADS];
    __shared__ float    qpiL[P3_N];
    __shared__ float    GLf[H_HEADS][FD_N];
    __shared__ float    resL[HPC];
    __shared__ float    abkt2[2][H_HEADS][66];
    __shared__ unsigned char rdL[N_NODES], pmL[N_NODES];

    // ---- uniform-constant init ----
    if (tid < 64) {
        const float2 qq = *(const float2*)(qn + (size_t)i*128 + 2*tid);
        qpkL[tid] = packh2(qq.x, qq.y);
    } else if (tid < 112) {
        const int f2 = tid - 64;
        const int h = f2 / 12;
        const float ps2 = 2.f * log1pf(expf(gamma[h])) * (1.0f/12.0f);
        const float2 qq = *(const float2*)(qpo + (size_t)i*P3_N + 2*f2);
        qspkL[f2] = packh2(ps2*qq.x, ps2*qq.y);
    } else if (tid < 144) {
        const int v = tid - 112, h = v >> 3, e = v & 7;
        wbPk[h][e] = packh2(w_bias[(P3_N + 2*e)*H_HEADS + h],
                            w_bias[(P3_N + 2*e + 1)*H_HEADS + h]);
    } else if (tid < 240) {
        qpiL[tid - 144] = qpo[(size_t)i*P3_N + (tid - 144)];
    }
    for (int t = tid; t < 2*H_HEADS*66; t += 512) ((float*)abkt2)[t] = 0.f;

    const int  r_i = resi[i], ch_i = chain[i], ba_i = batch[i];
    const bool m_i = mask_true(maskp, i);
    const float dix = jinfo[(size_t)i*8+4], diy = jinfo[(size_t)i*8+5], diz = jinfo[(size_t)i*8+6];

    const float inv3  = 0.57735026918962576f;
    const float rstep = 0.72727272727272727f;   // 1/1.375

    // ---- per-thread j prework (regs) ----
    const int j = tid;
    const float4 vq4 = *(const float4*)(jinfo + (size_t)j*8);
    const float4 dj4 = *(const float4*)(jinfo + (size_t)j*8 + 4);
    const float4 ci4 = *(const float4*)(iinfo + (size_t)i*4);
    const float vqa[4] = {vq4.x, vq4.y, vq4.z, vq4.w};
    const float cia[4] = {ci4.x, ci4.y, ci4.z, ci4.w};
    const float dd0 = dix - dj4.x, dd1 = diy - dj4.y, dd2 = diz - dj4.z;
    const float dist = sqrtf(dd0*dd0 + dd1*dd1 + dd2*dd2 + 1e-6f);
    unsigned rr[8];
#pragma unroll
    for (int p = 0; p < 8; ++p) {
        const float u0 = (dist - (1.375f*(float)(2*p)   + 0.6875f)) * rstep;
        const float u1 = (dist - (1.375f*(float)(2*p+1) + 0.6875f)) * rstep;
        rr[p] = packh2(__expf(-u0*u0), __expf(-u1*u1));
        rbfP[j][p] = rr[p];
    }
    const int  rj = resi[j], cj = chain[j], bj = batch[j];
    const bool pm = m_i && mask_true(maskp, j) && (ba_i == bj);
    rdL[j] = (unsigned char)((ch_i != cj) ? 65 : (min(max(r_i - rj, -32), 32) + 32));
    pmL[j] = pm ? 1 : 0;
    __syncthreads();

    // ================= Pass A: thread=j streaming dots =================
    float lv[4];
    {
        const unsigned* kcol = knT2 + j;
        const unsigned* pcol = kpT2f + j;
#pragma unroll
        for (int h = 0; h < 4; ++h) {
            float acc = 0.f;
#pragma unroll
            for (int g = 0; g < 4; ++g) {
                const uint4 qq = *(const uint4*)&qpkL[h*16 + g*4];
                const unsigned k0 = kcol[(size_t)(h*16 + g*4    )*N_NODES];
                const unsigned k1 = kcol[(size_t)(h*16 + g*4 + 1)*N_NODES];
                const unsigned k2 = kcol[(size_t)(h*16 + g*4 + 2)*N_NODES];
                const unsigned k3 = kcol[(size_t)(h*16 + g*4 + 3)*N_NODES];
                acc = dot2u(k0, qq.x, acc);
                acc = dot2u(k1, qq.y, acc);
                acc = dot2u(k2, qq.z, acc);
                acc = dot2u(k3, qq.w, acc);
            }
#pragma unroll
            for (int g = 0; g < 3; ++g) {
                const uint4 qq = *(const uint4*)&qspkL[h*12 + g*4];
                const unsigned k0 = pcol[(size_t)(h*12 + g*4    )*N_NODES];
                const unsigned k1 = pcol[(size_t)(h*12 + g*4 + 1)*N_NODES];
                const unsigned k2 = pcol[(size_t)(h*12 + g*4 + 2)*N_NODES];
                const unsigned k3 = pcol[(size_t)(h*12 + g*4 + 3)*N_NODES];
                acc = dot2u(k0, qq.x, acc);
                acc = dot2u(k1, qq.y, acc);
                acc = dot2u(k2, qq.z, acc);
                acc = dot2u(k3, qq.w, acc);
            }
            const uint4 w0 = *(const uint4*)&wbPk[h][0];
            const uint4 w1 = *(const uint4*)&wbPk[h][4];
            acc = dot2u(rr[0], w0.x, acc);
            acc = dot2u(rr[1], w0.y, acc);
            acc = dot2u(rr[2], w0.z, acc);
            acc = dot2u(rr[3], w0.w, acc);
            acc = dot2u(rr[4], w1.x, acc);
            acc = dot2u(rr[5], w1.y, acc);
            acc = dot2u(rr[6], w1.z, acc);
            acc = dot2u(rr[7], w1.w, acc);
            lv[h] = pm ? (acc + cia[h] + vqa[h]) * inv3 : -1e9f;
        }
    }

    // ================= Softmax: 2 reduce rounds =================
    float p[4];
    float asum[4];
    {
        float mx[4] = {lv[0], lv[1], lv[2], lv[3]};
#pragma unroll
        for (int off = 1; off < 64; off <<= 1) {
#pragma unroll
            for (int h = 0; h < 4; ++h) mx[h] = fmaxf(mx[h], __shfl_xor(mx[h], off));
        }
        if (lane == 0) *(float4*)&mxW[wv][0] = make_float4(mx[0], mx[1], mx[2], mx[3]);
        __syncthreads();
        float mxg[4] = {-1e30f, -1e30f, -1e30f, -1e30f};
#pragma unroll
        for (int w = 0; w < 8; ++w) {
            const float4 m = *(const float4*)&mxW[w][0];
            mxg[0] = fmaxf(mxg[0], m.x); mxg[1] = fmaxf(mxg[1], m.y);
            mxg[2] = fmaxf(mxg[2], m.z); mxg[3] = fmaxf(mxg[3], m.w);
        }
        float e[4], sm[4];
#pragma unroll
        for (int h = 0; h < 4; ++h) {
            e[h] = pm ? __expf(lv[h] - mxg[h]) : 0.f;
            sm[h] = e[h];
        }
#pragma unroll
        for (int off = 1; off < 64; off <<= 1) {
#pragma unroll
            for (int h = 0; h < 4; ++h) sm[h] += __shfl_xor(sm[h], off);
        }
        if (lane == 0) *(float4*)&smW[wv][0] = make_float4(sm[0], sm[1], sm[2], sm[3]);
        __syncthreads();
        float smt[4] = {0.f, 0.f, 0.f, 0.f};
#pragma unroll
        for (int w = 0; w < 8; ++w) {
            const float4 m = *(const float4*)&smW[w][0];
            smt[0] += m.x; smt[1] += m.y; smt[2] += m.z; smt[3] += m.w;
        }
        const int half = j >> 8;
#pragma unroll
        for (int h = 0; h < 4; ++h) {
            const float rden = 1.f / fmaxf(smt[h], 1e-37f);
            asum[h] = smt[h] * rden;
            p[h] = e[h] * rden;
            atomicAdd(&abkt2[half][h][rdL[j]], p[h]);
        }
#pragma unroll
        for (int h = 0; h < 4; ++h) {
            const float po = __shfl_xor(p[h], 1);
            if (!(j & 1)) attnH[h][j >> 1] = packh2(p[h], po);
        }
    }
    __syncthreads();

    // ================= Pass B: thread-owned outputs, batched loads ==========
    if (tid < HPC) {
        const int s = tid, h = s / PAIR_CN;
        const char* col = (const char*)valT2 + s*4;   // stride 896 B per jp
        float a[4] = {0.f, 0.f, 0.f, 0.f};
        for (int jp0 = 0; jp0 < 256; jp0 += 16) {
            unsigned u[16];
#pragma unroll
            for (int k = 0; k < 16; ++k)
                u[k] = *(const unsigned*)(col + (size_t)(jp0 + k)*896);
#pragma unroll
            for (int k = 0; k < 16; ++k)
                a[k & 3] = dot2u(u[k], attnH[h][jp0 + k], a[k & 3]);
        }
        resL[s] = (a[0] + a[1]) + (a[2] + a[3]);
    } else if (tid >= 256 && tid < 448) {
        const int v = tid - 256, f = v >> 1, half = v & 1;
        const char* col = (const char*)kpT2 + f*4;    // stride 384 B per jp
        float a[4] = {0.f, 0.f, 0.f, 0.f};
        for (int jp0 = half*128; jp0 < half*128 + 128; jp0 += 8) {
            unsigned u[8];
#pragma unroll
            for (int k = 0; k < 8; ++k)
                u[k] = *(const unsigned*)(col + (size_t)(jp0 + k)*384);
#pragma unroll
            for (int k = 0; k < 8; ++k) {
                a[0] = dot2u(u[k], attnH[0][jp0 + k], a[0]);
                a[1] = dot2u(u[k], attnH[1][jp0 + k], a[1]);
                a[2] = dot2u(u[k], attnH[2][jp0 + k], a[2]);
                a[3] = dot2u(u[k], attnH[3][jp0 + k], a[3]);
            }
        }
#pragma unroll
        for (int h = 0; h < 4; ++h) {
            a[h] += __shfl_xor(a[h], 1);
            if (half == 0) GLf[h][f] = qpiL[f] * asum[h] - a[h];
        }
    } else if (tid >= 448 && tid < 512) {
        const int idx = tid - 448, b = idx >> 2, q = idx & 3;
        const int w = b >> 1;
        const bool hi = (b & 1);
        float a[4] = {0.f, 0.f, 0.f, 0.f};
#pragma unroll 4
        for (int jpp = q*64; jpp < q*64 + 64; ++jpp) {
            const unsigned r0 = rbfP[2*jpp][w];
            const unsigned r1 = rbfP[2*jpp + 1][w];
            const unsigned ee = hi ? ((r0 >> 16) | (r1 & 0xffff0000u))
                                   : ((r0 & 0xffffu) | (r1 << 16));
            a[0] = dot2u(ee, attnH[0][jpp], a[0]);
            a[1] = dot2u(ee, attnH[1][jpp], a[1]);
            a[2] = dot2u(ee, attnH[2][jpp], a[2]);
            a[3] = dot2u(ee, attnH[3][jpp], a[3]);
        }
#pragma unroll
        for (int h = 0; h < 4; ++h) {
            a[h] += __shfl_xor(a[h], 1);
            a[h] += __shfl_xor(a[h], 2);
            if (q == 0) GLf[h][96 + b] = a[h];
        }
    }
    __syncthreads();

    // ================= Epilogue: res = R + emb-buckets + G @ w_pair =========
    if (tid < HPC) {
        const int h = tid / PAIR_CN, c = tid - h*PAIR_CN;
        float r = resL[tid];
#pragma unroll 8
        for (int rrr = 0; rrr < 66; ++rrr)
            r += (abkt2[0][h][rrr] + abkt2[1][h][rrr]) * remb[rrr*PAIR_CN + c];
        const float* gl = GLf[h];
        const float* wp = w_pair + c;
#pragma unroll 8
        for (int f = 0; f < FD_N; ++f) r += gl[f] * wp[f*PAIR_CN];
        resL[tid] = r;
    }
    __syncthreads();

    // ================= out = res @ w_out (t-split 2-way) ====================
    {
        const int col = tid >> 1, ph = tid & 1;
        float o = 0.f;
#pragma unroll 8
        for (int t = ph*112; t < ph*112 + 112; ++t)
            o += resL[t] * w_out[(size_t)t*DIM + col];
        o += __shfl_xor(o, 1);
        if (ph == 0) out[(size_t)i*DIM + col] = o;
    }
}

// ---------------------------------------------------------------------------
extern "C" void kernel_launch(void* const* d_in, const int* in_sizes, int n_in,
                              void* d_out, int out_size, void* d_ws, size_t ws_size,
                              hipStream_t stream) {
    (void)in_sizes; (void)n_in; (void)out_size; (void)ws_size;
    const float* local = (const float*)d_in[0];
    const float* pos   = (const float*)d_in[1];
    const int*   resi  = (const int*)d_in[2];
    const int*   chain = (const int*)d_in[3];
    const int*   batch = (const int*)d_in[4];
    const void*  maskp = d_in[5];
    const float* qls   = (const float*)d_in[6];
    const float* qlo   = (const float*)d_in[7];
    const float* kls   = (const float*)d_in[8];
    const float* klo   = (const float*)d_in[9];
    const float* w_q   = (const float*)d_in[10];
    const float* b_q   = (const float*)d_in[11];
    const float* w_k   = (const float*)d_in[12];
    const float* b_k   = (const float*)d_in[13];
    const float* w_v   = (const float*)d_in[14];
    const float* b_v   = (const float*)d_in[15];
    const float* w_qp  = (const float*)d_in[16];
    const float* b_qp  = (const float*)d_in[17];
    const float* w_kp  = (const float*)d_in[18];
    const float* b_kp  = (const float*)d_in[19];
    const float* w_vp  = (const float*)d_in[20];
    const float* b_vp  = (const float*)d_in[21];
    const float* remb  = (const float*)d_in[22];
    const float* w_pair= (const float*)d_in[23];
    const float* w_bias= (const float*)d_in[24];
    const float* b_bias= (const float*)d_in[25];
    const float* gamma = (const float*)d_in[26];
    const float* w_out = (const float*)d_in[27];

    char* ws = (char*)d_ws;
    float*     qn    = (float*)(ws);                 // 262144 B
    float*     qpo   = (float*)(ws + 262144);        // 196608 B
    unsigned*  knT2  = (unsigned*)(ws + 458752);     // 131072 B [64][512]
    unsigned*  kpT2f = (unsigned*)(ws + 589824);     //  98304 B [48][512]
    unsigned*  valT2 = (unsigned*)(ws + 688128);     // 229376 B [256][224]
    unsigned*  kpT2  = (unsigned*)(ws + 917504);     //  98304 B [256][96]
    float*     jinf  = (float*)(ws + 1015808);       //  16384 B
    float*     iinf  = (float*)(ws + 1032192);       //   8192 B

    proj_kernel<<<N_NODES / 2, 512, 0, stream>>>(
        local, pos, qls, qlo, kls, klo,
        w_q, b_q, w_k, b_k, w_v, b_v,
        w_qp, b_qp, w_kp, b_kp, w_vp, b_vp,
        w_bias, b_bias, gamma,
        qn, knT2, qpo, kpT2f, valT2, kpT2, jinf, iinf);

    attn_kernel<<<N_NODES, 512, 0, stream>>>(
        qn, knT2, qpo, kpT2f, valT2, kpT2, jinf, iinf,
        resi, chain, batch, maskp,
        remb, w_pair, w_bias, gamma, w_out,
        (float*)d_out);
}

// Round 13
// 57.411 us; speedup vs baseline: 1.9759x; 1.0877x over previous
//
#include <hip/hip_runtime.h>
#include <hip/hip_bf16.h>
#include <cstddef>

// Problem constants (N, D, S, H, QP, VP) = (512, 256, 32, 4, 8, 8)
#define N_NODES 512
#define DIM     256
#define H_HEADS 4
#define PAIR_CN 56    // S + 3*VP
#define P3_N    96    // H*QP*3
#define FD_N    112   // P3 + 16
#define HPC     224   // H * PAIR_C

typedef _Float16 h2v __attribute__((ext_vector_type(2)));

__device__ __forceinline__ bool mask_true(const void* m, int idx) {
    if (((const unsigned char*)m)[idx] != 0) return true;
    return ((const int*)m)[idx] != 0;
}
__device__ __forceinline__ unsigned packh2(float a, float b) {
    _Float16 ha = (_Float16)a, hb = (_Float16)b;
    unsigned short ua, ub;
    __builtin_memcpy(&ua, &ha, 2); __builtin_memcpy(&ub, &hb, 2);
    return (unsigned)ua | ((unsigned)ub << 16);
}
__device__ __forceinline__ float h2lof(unsigned u) {
    unsigned short t = (unsigned short)(u & 0xffff);
    _Float16 h; __builtin_memcpy(&h, &t, 2); return (float)h;
}
__device__ __forceinline__ float h2hif(unsigned u) {
    unsigned short t = (unsigned short)(u >> 16);
    _Float16 h; __builtin_memcpy(&h, &t, 2); return (float)h;
}
__device__ __forceinline__ float dot2u(unsigned a, unsigned b, float c) {
#if __has_builtin(__builtin_amdgcn_fdot2)
    h2v ha, hb;
    __builtin_memcpy(&ha, &a, 4);
    __builtin_memcpy(&hb, &b, 4);
    return __builtin_amdgcn_fdot2(ha, hb, c, false);
#else
    return c + h2lof(a)*h2lof(b) + h2hif(a)*h2hif(b);
#endif
}

// ---------------------------------------------------------------------------
// Phase 1: projections + LayerNorm + separable terms + weight packing.
// Tables (all u32 = f16 pair):
//   qnP   [512][64]          q pairs (pre-scaled)
//   qpP   [512][48]          qp pairs (raw)
//   knT4  [16 dq][512 j][4]  kn, 4 dim-pairs per uint4
//   kpT4  [12 fq][512 j][4]  kp, 4 f-pairs per uint4
//   valT2 [256 jp][224 s]    value pairs over j
//   kpT2  [256 jp][96 f]     kp pairs over j
//   woPk  [112 t2][256 col]  w_out pairs over t      (blocks 0..15 pack)
//   wp2   [56 f2][56 c]      w_pair pairs over f
//   remb2 [33 r2][56 c]      resi_emb pairs over row
// ---------------------------------------------------------------------------
__global__ __launch_bounds__(512) void proj_kernel(
    const float* __restrict__ local, const float* __restrict__ pos,
    const float* __restrict__ qls, const float* __restrict__ qlo,
    const float* __restrict__ kls, const float* __restrict__ klo,
    const float* __restrict__ w_q, const float* __restrict__ b_q,
    const float* __restrict__ w_k, const float* __restrict__ b_k,
    const float* __restrict__ w_v, const float* __restrict__ b_v,
    const float* __restrict__ w_qp, const float* __restrict__ b_qp,
    const float* __restrict__ w_kp, const float* __restrict__ b_kp,
    const float* __restrict__ w_vp, const float* __restrict__ b_vp,
    const float* __restrict__ w_bias, const float* __restrict__ b_bias,
    const float* __restrict__ gamma,
    const float* __restrict__ remb, const float* __restrict__ w_pair,
    const float* __restrict__ w_out,
    unsigned* __restrict__ qnP, unsigned* __restrict__ knT4,
    unsigned* __restrict__ qpP, unsigned* __restrict__ kpT4,
    unsigned* __restrict__ valT2, unsigned* __restrict__ kpT2,
    unsigned* __restrict__ woPk, unsigned* __restrict__ wp2,
    unsigned* __restrict__ remb2,
    float* __restrict__ jinfo, float* __restrict__ iinfo)
{
    const int i0 = blockIdx.x * 2;
    const int tid = threadIdx.x;

    __shared__ float xL[2][DIM];
    __shared__ float qraw[2][128];
    __shared__ float kraw[2][128];
    __shared__ float stat[2][16];
    __shared__ float qpL[2][P3_N];
    __shared__ float kpbL[2][P3_N];
    __shared__ float wbS[384];

    // ---- weight packing strips (blocks 0..15), independent of block data ----
    if (blockIdx.x < 16) {
        for (int t = blockIdx.x*512 + tid; t < 33656; t += 8192) {
            if (t < 28672) {            // woPk: t = t2*256 + col
                const int t2 = t >> 8, colx = t & 255;
                woPk[t] = packh2(w_out[(size_t)(2*t2)*DIM + colx],
                                 w_out[(size_t)(2*t2 + 1)*DIM + colx]);
            } else if (t < 31808) {     // wp2: f2*56 + c
                const int v = t - 28672, f2 = v / 56, cx = v % 56;
                wp2[v] = packh2(w_pair[(2*f2)*PAIR_CN + cx],
                                w_pair[(2*f2 + 1)*PAIR_CN + cx]);
            } else {                    // remb2: r2*56 + c
                const int v = t - 31808, r2 = v / 56, cx = v % 56;
                remb2[v] = packh2(remb[(2*r2)*PAIR_CN + cx],
                                  remb[(2*r2 + 1)*PAIR_CN + cx]);
            }
        }
    }

    {
        const int r = tid >> 8, d = tid & 255;
        xL[r][d] = local[(size_t)(i0 + r) * DIM + d];
    }
    if (tid < 384) wbS[tid] = w_bias[tid];
    __syncthreads();

    char* valT2B = (char*)valT2;
    char* kpT2B  = (char*)kpT2;
    const size_t jp = (size_t)(i0 >> 1);

    if (tid < 336) {
        const int colg = tid >> 1, dh = tid & 1;
        const int col = colg * 4;
        const float* w; int width, c, seg;
        if      (col < 128) { w = w_q;  c = col;       width = 128; seg = 0; }
        else if (col < 256) { w = w_k;  c = col - 128; width = 128; seg = 1; }
        else if (col < 384) { w = w_v;  c = col - 256; width = 128; seg = 2; }
        else if (col < 480) { w = w_qp; c = col - 384; width = 96;  seg = 3; }
        else if (col < 576) { w = w_kp; c = col - 480; width = 96;  seg = 4; }
        else                { w = w_vp; c = col - 576; width = 96;  seg = 5; }

        float acc[2][4] = {{0.f,0.f,0.f,0.f},{0.f,0.f,0.f,0.f}};
#pragma unroll 4
        for (int dd = 0; dd < 128; ++dd) {
            const int d = dh*128 + dd;
            float4 wv = *(const float4*)(w + (size_t)d * width + c);
#pragma unroll
            for (int r = 0; r < 2; ++r) {
                float x = xL[r][d];
                acc[r][0] += x * wv.x; acc[r][1] += x * wv.y;
                acc[r][2] += x * wv.z; acc[r][3] += x * wv.w;
            }
        }
#pragma unroll
        for (int r = 0; r < 2; ++r)
#pragma unroll
            for (int e = 0; e < 4; ++e)
                acc[r][e] += __shfl_xor(acc[r][e], 1);

        if (dh == 0) {
            const float cax0 = pos[i0*15+3],     cay0 = pos[i0*15+4],     caz0 = pos[i0*15+5];
            const float cax1 = pos[(i0+1)*15+3], cay1 = pos[(i0+1)*15+4], caz1 = pos[(i0+1)*15+5];
            float fr0[4], fr1[4];
            const bool isKp = (seg == 4), isQp = (seg == 3);
#pragma unroll
            for (int e = 0; e < 4; ++e) {
                const int cc = c + e;
                const float v0 = acc[0][e], v1 = acc[1][e];
                if (seg == 0) {
                    qraw[0][cc] = v0 + b_q[cc];
                    qraw[1][cc] = v1 + b_q[cc];
                } else if (seg == 1) {
                    kraw[0][cc] = v0 + b_k[cc];
                    kraw[1][cc] = v1 + b_k[cc];
                } else if (seg == 2) {
                    const int h = cc >> 5, sc = cc & 31;
                    const int row = h*PAIR_CN + sc;
                    *(unsigned*)(valT2B + jp*896 + row*4) =
                        packh2(v0 + b_v[cc], v1 + b_v[cc]);
                } else if (seg == 3) {
                    const int x = cc % 3;
                    const float cav0 = (x==0)?cax0:((x==1)?cay0:caz0);
                    const float cav1 = (x==0)?cax1:((x==1)?cay1:caz1);
                    const float r0 = v0 + b_qp[cc] + cav0;
                    const float r1 = v1 + b_qp[cc] + cav1;
                    fr0[e] = r0; fr1[e] = r1;
                    qpL[0][cc] = r0; qpL[1][cc] = r1;
                } else if (seg == 4) {
                    const int x = cc % 3;
                    const float cav0 = (x==0)?cax0:((x==1)?cay0:caz0);
                    const float cav1 = (x==0)?cax1:((x==1)?cay1:caz1);
                    const float r0 = v0 + b_kp[cc] + cav0;
                    const float r1 = v1 + b_kp[cc] + cav1;
                    fr0[e] = r0; fr1[e] = r1;
                    *(unsigned*)(kpT2B + jp*384 + cc*4) = packh2(r0, r1);
                    kpbL[0][cc] = (float)(_Float16)r0;
                    kpbL[1][cc] = (float)(_Float16)r1;
                } else {
                    const int h = cc / 24, rr = cc % 24, x = cc % 3;
                    const float cav0 = (x==0)?cax0:((x==1)?cay0:caz0);
                    const float cav1 = (x==0)?cax1:((x==1)?cay1:caz1);
                    const int row = h*PAIR_CN + 32 + rr;
                    *(unsigned*)(valT2B + jp*896 + row*4) =
                        packh2(v0 + b_vp[cc] + cav0, v1 + b_vp[cc] + cav1);
                }
            }
            if (isQp) {
                const int f2 = c >> 1;
                qpP[(size_t)i0*48 + f2]         = packh2(fr0[0], fr0[1]);
                qpP[(size_t)i0*48 + f2 + 1]     = packh2(fr0[2], fr0[3]);
                qpP[(size_t)(i0+1)*48 + f2]     = packh2(fr1[0], fr1[1]);
                qpP[(size_t)(i0+1)*48 + f2 + 1] = packh2(fr1[2], fr1[3]);
            }
            if (isKp) {
                const int f2 = c >> 1;   // even
                // kpT4[fq][j][e]: u32 index = ((fq*512)+j)*4 + (f2&3)
                const int fq = f2 >> 2;
                kpT4[((size_t)fq*N_NODES + i0    )*4 + (f2 & 3)]       = packh2(fr0[0], fr0[1]);
                kpT4[((size_t)fq*N_NODES + i0    )*4 + ((f2 + 1) & 3)] = packh2(fr0[2], fr0[3]);
                kpT4[((size_t)fq*N_NODES + i0 + 1)*4 + (f2 & 3)]       = packh2(fr1[0], fr1[1]);
                kpT4[((size_t)fq*N_NODES + i0 + 1)*4 + ((f2 + 1) & 3)] = packh2(fr1[2], fr1[3]);
            }
        }
    }
    __syncthreads();

    if (tid < 16) {
        const int r = tid >> 3, t = tid & 7;
        const float* src = (t < 4) ? qraw[r] : kraw[r];
        const int h = t & 3, base = (t < 4) ? 0 : 8;
        float mu = 0.f;
        for (int c = 0; c < 32; ++c) mu += src[h*32 + c];
        mu *= (1.f/32.f);
        float var = 0.f;
        for (int c = 0; c < 32; ++c) { float d = src[h*32 + c] - mu; var += d*d; }
        var *= (1.f/32.f);
        stat[r][base + h*2 + 0] = mu;
        stat[r][base + h*2 + 1] = var;
    }
    __syncthreads();

    {
        const int r = tid >> 8, u = tid & 255;
        const int i = i0 + r;
        if (u < 128) {
            const int h = u >> 5, sidx = u & 31;
            const float mu = stat[r][h*2], var = stat[r][h*2+1];
            float v = (qraw[r][u] - mu) * rsqrtf(var + 1e-5f) * qls[sidx] + qlo[sidx];
            v *= 0.17677669529663687f;  // * sqrt(1/S)
            const float vo = __shfl_xor(v, 1);
            if (!(u & 1)) qnP[(size_t)i*64 + (u >> 1)] = packh2(v, vo);
        } else {
            const int u2 = u - 128, h = u2 >> 5, sidx = u2 & 31;
            const float mu = stat[r][8 + h*2], var = stat[r][9 + h*2];
            float v = (kraw[r][u2] - mu) * rsqrtf(var + 1e-5f) * kls[sidx] + klo[sidx];
            const float vo = __shfl_xor(v, 1);
            if (!(u2 & 1))
                knT4[(((size_t)(u2 >> 3))*N_NODES + i)*4 + ((u2 >> 1) & 3)] = packh2(v, vo);
        }
    }

    // ---- separable terms, 64 threads = 2 r x 4 h x 8 ks ----
    if (tid < 64) {
        const int r = tid >> 5, h = (tid >> 3) & 3, ks = tid & 7;
        float uacc = 0.f, tacc = 0.f;
#pragma unroll
        for (int f = ks; f < P3_N; f += 8) {
            float wb = wbS[f*4 + h];
            uacc += qpL[r][f] * wb;
            tacc += kpbL[r][f] * wb;
        }
        float nq = 0.f, nk = 0.f;
#pragma unroll
        for (int f = h*24 + ks*3; f < h*24 + ks*3 + 3; ++f) {
            nq += qpL[r][f]*qpL[r][f];
            nk += kpbL[r][f]*kpbL[r][f];
        }
        uacc += __shfl_xor(uacc,1); uacc += __shfl_xor(uacc,2); uacc += __shfl_xor(uacc,4);
        tacc += __shfl_xor(tacc,1); tacc += __shfl_xor(tacc,2); tacc += __shfl_xor(tacc,4);
        nq   += __shfl_xor(nq,1);   nq   += __shfl_xor(nq,2);   nq   += __shfl_xor(nq,4);
        nk   += __shfl_xor(nk,1);   nk   += __shfl_xor(nk,2);   nk   += __shfl_xor(nk,4);
        if (ks == 0) {
            const int n = i0 + r;
            const float ps = log1pf(expf(gamma[h])) * (1.0f/12.0f);
            iinfo[n*4 + h] = -ps*nq + uacc + b_bias[h];
            jinfo[n*8 + h] = -ps*nk - tacc;
            if (h == 0) {
                jinfo[n*8 + 4] = 10.f * pos[n*15 + 3];
                jinfo[n*8 + 5] = 10.f * pos[n*15 + 4];
                jinfo[n*8 + 6] = 10.f * pos[n*15 + 5];
                jinfo[n*8 + 7] = 0.f;
            }
        }
    }
}

// ---------------------------------------------------------------------------
// Phase 2: one block per query row. 512 threads, grid 512.
// uint4 loads throughout; packed f16 epilogue.
// ---------------------------------------------------------------------------
__global__ __launch_bounds__(512, 4) void attn_kernel(
    const unsigned* __restrict__ qnP, const unsigned* __restrict__ knT4,
    const unsigned* __restrict__ qpP, const unsigned* __restrict__ kpT4,
    const unsigned* __restrict__ valT2, const unsigned* __restrict__ kpT2,
    const unsigned* __restrict__ woPk, const unsigned* __restrict__ wp2,
    const unsigned* __restrict__ remb2,
    const float* __restrict__ jinfo, const float* __restrict__ iinfo,
    const int* __restrict__ resi, const int* __restrict__ chain,
    const int* __restrict__ batch, const void* __restrict__ maskp,
    const float* __restrict__ w_bias, const float* __restrict__ gamma,
    float* __restrict__ out)
{
    const int i    = blockIdx.x;
    const int tid  = threadIdx.x;
    const int lane = tid & 63;
    const int wv   = tid >> 6;

    __shared__ unsigned qpkL[64];          // packed q pairs
    __shared__ unsigned qspkL[48];         // packed 2ps*qp pairs
    __shared__ unsigned wbPk[H_HEADS][8];
    __shared__ unsigned rbfP[N_NODES][9];
    __shared__ unsigned attnH[H_HEADS][260];
    __shared__ float    mxW[8][H_HEADS], smW[8][H_HEADS];
    __shared__ float    asL[H_HEADS];
    __shared__ float    qpiL[P3_N];
    __shared__ float    partR[4][56][4];
    __shared__ float    partG[8][P3_N][4];
    __shared__ float    GLfR[H_HEADS][16];
    __shared__ unsigned GLf2[H_HEADS][56];
    __shared__ unsigned abktP[H_HEADS][33];
    __shared__ float    resL[HPC];
    __shared__ unsigned resH[FD_N];
    __shared__ float    abkt2[2][H_HEADS][66];
    __shared__ unsigned char rdL[N_NODES], pmL[N_NODES];

    // ---- init ----
    if (tid < 64) {
        qpkL[tid] = qnP[(size_t)i*64 + tid];
    } else if (tid < 112) {
        const int f2 = tid - 64, h = f2 / 12;
        const float ps2 = 2.f * log1pf(expf(gamma[h])) * (1.0f/12.0f);
        const unsigned u = qpP[(size_t)i*48 + f2];
        qspkL[f2] = packh2(ps2*h2lof(u), ps2*h2hif(u));
    } else if (tid < 160) {
        const int f2 = tid - 112;
        const unsigned u = qpP[(size_t)i*48 + f2];
        qpiL[2*f2]   = h2lof(u);
        qpiL[2*f2+1] = h2hif(u);
    } else if (tid < 192) {
        const int v = tid - 160, h = v >> 3, e = v & 7;
        wbPk[h][e] = packh2(w_bias[(P3_N + 2*e)*H_HEADS + h],
                            w_bias[(P3_N + 2*e + 1)*H_HEADS + h]);
    }
    for (int t = tid; t < 2*H_HEADS*66; t += 512) ((float*)abkt2)[t] = 0.f;

    const int  r_i = resi[i], ch_i = chain[i], ba_i = batch[i];
    const bool m_i = mask_true(maskp, i);
    const float dix = jinfo[(size_t)i*8+4], diy = jinfo[(size_t)i*8+5], diz = jinfo[(size_t)i*8+6];

    const float inv3  = 0.57735026918962576f;
    const float rstep = 0.72727272727272727f;   // 1/1.375

    // ---- per-thread j prework ----
    const int j = tid;
    const float4 vq4 = *(const float4*)(jinfo + (size_t)j*8);
    const float4 dj4 = *(const float4*)(jinfo + (size_t)j*8 + 4);
    const float4 ci4 = *(const float4*)(iinfo + (size_t)i*4);
    const float vqa[4] = {vq4.x, vq4.y, vq4.z, vq4.w};
    const float cia[4] = {ci4.x, ci4.y, ci4.z, ci4.w};
    const float dd0 = dix - dj4.x, dd1 = diy - dj4.y, dd2 = diz - dj4.z;
    const float dist = sqrtf(dd0*dd0 + dd1*dd1 + dd2*dd2 + 1e-6f);
    unsigned rr[8];
#pragma unroll
    for (int p = 0; p < 8; ++p) {
        const float u0 = (dist - (1.375f*(float)(2*p)   + 0.6875f)) * rstep;
        const float u1 = (dist - (1.375f*(float)(2*p+1) + 0.6875f)) * rstep;
        rr[p] = packh2(__expf(-u0*u0), __expf(-u1*u1));
        rbfP[j][p] = rr[p];
    }
    const int  rj = resi[j], cj = chain[j], bj = batch[j];
    const bool pm = m_i && mask_true(maskp, j) && (ba_i == bj);
    rdL[j] = (unsigned char)((ch_i != cj) ? 65 : (min(max(r_i - rj, -32), 32) + 32));
    pmL[j] = pm ? 1 : 0;
    __syncthreads();

    // ================= Pass A: uint4 streaming dots =================
    float lv[4];
    {
        const uint4* kcol = (const uint4*)knT4 + j;
        const uint4* pcol = (const uint4*)kpT4 + j;
        const uint4* qk4  = (const uint4*)qpkL;
        const uint4* qs4  = (const uint4*)qspkL;
#pragma unroll
        for (int h = 0; h < 4; ++h) {
            float acc = 0.f;
#pragma unroll
            for (int g = 0; g < 4; ++g) {
                const uint4 kk = kcol[(size_t)(h*4 + g)*N_NODES];
                const uint4 qq = qk4[h*4 + g];
                acc = dot2u(kk.x, qq.x, acc);
                acc = dot2u(kk.y, qq.y, acc);
                acc = dot2u(kk.z, qq.z, acc);
                acc = dot2u(kk.w, qq.w, acc);
            }
#pragma unroll
            for (int g = 0; g < 3; ++g) {
                const uint4 kk = pcol[(size_t)(h*3 + g)*N_NODES];
                const uint4 qq = qs4[h*3 + g];
                acc = dot2u(kk.x, qq.x, acc);
                acc = dot2u(kk.y, qq.y, acc);
                acc = dot2u(kk.z, qq.z, acc);
                acc = dot2u(kk.w, qq.w, acc);
            }
            const uint4 w0 = *(const uint4*)&wbPk[h][0];
            const uint4 w1 = *(const uint4*)&wbPk[h][4];
            acc = dot2u(rr[0], w0.x, acc);
            acc = dot2u(rr[1], w0.y, acc);
            acc = dot2u(rr[2], w0.z, acc);
            acc = dot2u(rr[3], w0.w, acc);
            acc = dot2u(rr[4], w1.x, acc);
            acc = dot2u(rr[5], w1.y, acc);
            acc = dot2u(rr[6], w1.z, acc);
            acc = dot2u(rr[7], w1.w, acc);
            lv[h] = pm ? (acc + cia[h] + vqa[h]) * inv3 : -1e9f;
        }
    }

    // ================= Softmax: 2 reduce rounds =================
    {
        float mx[4] = {lv[0], lv[1], lv[2], lv[3]};
#pragma unroll
        for (int off = 1; off < 64; off <<= 1) {
#pragma unroll
            for (int h = 0; h < 4; ++h) mx[h] = fmaxf(mx[h], __shfl_xor(mx[h], off));
        }
        if (lane == 0) *(float4*)&mxW[wv][0] = make_float4(mx[0], mx[1], mx[2], mx[3]);
        __syncthreads();
        float mxg[4] = {-1e30f, -1e30f, -1e30f, -1e30f};
#pragma unroll
        for (int w = 0; w < 8; ++w) {
            const float4 m = *(const float4*)&mxW[w][0];
            mxg[0] = fmaxf(mxg[0], m.x); mxg[1] = fmaxf(mxg[1], m.y);
            mxg[2] = fmaxf(mxg[2], m.z); mxg[3] = fmaxf(mxg[3], m.w);
        }
        float e[4], sm[4];
#pragma unroll
        for (int h = 0; h < 4; ++h) {
            e[h] = pm ? __expf(lv[h] - mxg[h]) : 0.f;
            sm[h] = e[h];
        }
#pragma unroll
        for (int off = 1; off < 64; off <<= 1) {
#pragma unroll
            for (int h = 0; h < 4; ++h) sm[h] += __shfl_xor(sm[h], off);
        }
        if (lane == 0) *(float4*)&smW[wv][0] = make_float4(sm[0], sm[1], sm[2], sm[3]);
        __syncthreads();
        float smt[4] = {0.f, 0.f, 0.f, 0.f};
#pragma unroll
        for (int w = 0; w < 8; ++w) {
            const float4 m = *(const float4*)&smW[w][0];
            smt[0] += m.x; smt[1] += m.y; smt[2] += m.z; smt[3] += m.w;
        }
        const int half = j >> 8;
        float p[4];
#pragma unroll
        for (int h = 0; h < 4; ++h) {
            const float rden = 1.f / fmaxf(smt[h], 1e-37f);
            p[h] = e[h] * rden;
            atomicAdd(&abkt2[half][h][rdL[j]], p[h]);
        }
        if (tid == 0) {
#pragma unroll
            for (int h = 0; h < 4; ++h)
                asL[h] = smt[h] / fmaxf(smt[h], 1e-37f);
        }
#pragma unroll
        for (int h = 0; h < 4; ++h) {
            const float po = __shfl_xor(p[h], 1);
            if (!(j & 1)) attnH[h][j >> 1] = packh2(p[h], po);
        }
    }
    __syncthreads();

    // ================= Pass B: uint4 loads, partials to LDS ==============
    if (tid < 224) {
        // R: s-quad g = tid%56, jp-quarter q = tid/56
        const int g = tid % 56, q = tid / 56;
        const int h = g / 14;
        const char* colp = (const char*)valT2 + g*16;
        float a0 = 0.f, a1 = 0.f, a2 = 0.f, a3 = 0.f;
#pragma unroll 8
        for (int jpq = q*64; jpq < q*64 + 64; ++jpq) {
            const uint4 u = *(const uint4*)(colp + (size_t)jpq*896);
            const unsigned pw = attnH[h][jpq];
            a0 = dot2u(u.x, pw, a0);
            a1 = dot2u(u.y, pw, a1);
            a2 = dot2u(u.z, pw, a2);
            a3 = dot2u(u.w, pw, a3);
        }
        partR[q][g][0] = a0; partR[q][g][1] = a1;
        partR[q][g][2] = a2; partR[q][g][3] = a3;
    } else if (tid < 416) {
        // Gk: f-quad g = v%24, jp-eighth e = v/24
        const int v = tid - 224, g = v % 24, e = v / 24;
        const char* colp = (const char*)kpT2 + g*16;
        float a[16];
#pragma unroll
        for (int k = 0; k < 16; ++k) a[k] = 0.f;
#pragma unroll 4
        for (int jpq = e*32; jpq < e*32 + 32; ++jpq) {
            const uint4 u = *(const uint4*)(colp + (size_t)jpq*384);
#pragma unroll
            for (int h = 0; h < 4; ++h) {
                const unsigned pw = attnH[h][jpq];
                a[0*4 + h] = dot2u(u.x, pw, a[0*4 + h]);
                a[1*4 + h] = dot2u(u.y, pw, a[1*4 + h]);
                a[2*4 + h] = dot2u(u.z, pw, a[2*4 + h]);
                a[3*4 + h] = dot2u(u.w, pw, a[3*4 + h]);
            }
        }
#pragma unroll
        for (int fi = 0; fi < 4; ++fi)
#pragma unroll
            for (int h = 0; h < 4; ++h)
                partG[e][g*4 + fi][h] = a[fi*4 + h];
    } else if (tid < 480) {
        // rbf-G: b = idx>>2, quarter q = idx&3
        const int idx = tid - 416, b = idx >> 2, q = idx & 3;
        const int w = b >> 1;
        const bool hi = (b & 1);
        float a[4] = {0.f, 0.f, 0.f, 0.f};
#pragma unroll 4
        for (int jpp = q*64; jpp < q*64 + 64; ++jpp) {
            const unsigned r0 = rbfP[2*jpp][w];
            const unsigned r1 = rbfP[2*jpp + 1][w];
            const unsigned ee = hi ? ((r0 >> 16) | (r1 & 0xffff0000u))
                                   : ((r0 & 0xffffu) | (r1 << 16));
            a[0] = dot2u(ee, attnH[0][jpp], a[0]);
            a[1] = dot2u(ee, attnH[1][jpp], a[1]);
            a[2] = dot2u(ee, attnH[2][jpp], a[2]);
            a[3] = dot2u(ee, attnH[3][jpp], a[3]);
        }
#pragma unroll
        for (int h = 0; h < 4; ++h) {
            a[h] += __shfl_xor(a[h], 1);
            a[h] += __shfl_xor(a[h], 2);
            if (q == 0) GLfR[h][b] = a[h];
        }
    }
    __syncthreads();

    // ================= Combine: resL, GLf2, abktP ====================
    for (int t = tid; t < 224; t += 512) {
        const int g = t >> 2, e = t & 3;
        resL[t] = partR[0][g][e] + partR[1][g][e] + partR[2][g][e] + partR[3][g][e];
    }
    for (int t = tid; t < 224; t += 512) {   // t = h*56 + f2
        const int h = t / 56, f2 = t % 56;
        if (f2 < 48) {
            float s0 = 0.f, s1 = 0.f;
#pragma unroll
            for (int e = 0; e < 8; ++e) {
                s0 += partG[e][2*f2][h];
                s1 += partG[e][2*f2 + 1][h];
            }
            GLf2[h][f2] = packh2(qpiL[2*f2]*asL[h] - s0, qpiL[2*f2 + 1]*asL[h] - s1);
        } else {
            GLf2[h][f2] = packh2(GLfR[h][(f2 - 48)*2], GLfR[h][(f2 - 48)*2 + 1]);
        }
    }
    for (int t = tid; t < 132; t += 512) {   // t = h*33 + r2
        const int h = t / 33, r2 = t % 33;
        abktP[h][r2] = packh2(abkt2[0][h][2*r2]   + abkt2[1][h][2*r2],
                              abkt2[0][h][2*r2+1] + abkt2[1][h][2*r2+1]);
    }
    __syncthreads();

    // ================= Epilogue (packed dot2) ====================
    if (tid < HPC) {
        const int h = tid / PAIR_CN, c = tid - h*PAIR_CN;
        float r = resL[tid];
#pragma unroll 8
        for (int r2 = 0; r2 < 33; ++r2)
            r = dot2u(remb2[r2*56 + c], abktP[h][r2], r);
#pragma unroll 8
        for (int f2 = 0; f2 < 56; ++f2)
            r = dot2u(wp2[f2*56 + c], GLf2[h][f2], r);
        resL[tid] = r;
    }
    __syncthreads();

    if (tid < FD_N) resH[tid] = packh2(resL[2*tid], resL[2*tid + 1]);
    __syncthreads();

    // ================= out = resH . woPk (t-split 2-way) ====================
    {
        const int col = tid >> 1, ph = tid & 1;
        float o = 0.f;
#pragma unroll 7
        for (int t2 = ph*56; t2 < ph*56 + 56; ++t2)
            o = dot2u(woPk[t2*256 + col], resH[t2], o);
        o += __shfl_xor(o, 1);
        if (ph == 0) out[(size_t)i*DIM + col] = o;
    }
}

// ---------------------------------------------------------------------------
extern "C" void kernel_launch(void* const* d_in, const int* in_sizes, int n_in,
                              void* d_out, int out_size, void* d_ws, size_t ws_size,
                              hipStream_t stream) {
    (void)in_sizes; (void)n_in; (void)out_size; (void)ws_size;
    const float* local = (const float*)d_in[0];
    const float* pos   = (const float*)d_in[1];
    const int*   resi  = (const int*)d_in[2];
    const int*   chain = (const int*)d_in[3];
    const int*   batch = (const int*)d_in[4];
    const void*  maskp = d_in[5];
    const float* qls   = (const float*)d_in[6];
    const float* qlo   = (const float*)d_in[7];
    const float* kls   = (const float*)d_in[8];
    const float* klo   = (const float*)d_in[9];
    const float* w_q   = (const float*)d_in[10];
    const float* b_q   = (const float*)d_in[11];
    const float* w_k   = (const float*)d_in[12];
    const float* b_k   = (const float*)d_in[13];
    const float* w_v   = (const float*)d_in[14];
    const float* b_v   = (const float*)d_in[15];
    const float* w_qp  = (const float*)d_in[16];
    const float* b_qp  = (const float*)d_in[17];
    const float* w_kp  = (const float*)d_in[18];
    const float* b_kp  = (const float*)d_in[19];
    const float* w_vp  = (const float*)d_in[20];
    const float* b_vp  = (const float*)d_in[21];
    const float* remb  = (const float*)d_in[22];
    const float* w_pair= (const float*)d_in[23];
    const float* w_bias= (const float*)d_in[24];
    const float* b_bias= (const float*)d_in[25];
    const float* gamma = (const float*)d_in[26];
    const float* w_out = (const float*)d_in[27];

    char* ws = (char*)d_ws;
    unsigned* qnP   = (unsigned*)(ws);            // 131072 B [512][64]
    unsigned* qpP   = (unsigned*)(ws + 131072);   //  98304 B [512][48]
    unsigned* knT4  = (unsigned*)(ws + 229376);   // 131072 B [16][512][4]
    unsigned* kpT4  = (unsigned*)(ws + 360448);   //  98304 B [12][512][4]
    unsigned* valT2 = (unsigned*)(ws + 458752);   // 229376 B [256][224]
    unsigned* kpT2  = (unsigned*)(ws + 688128);   //  98304 B [256][96]
    float*    jinf  = (float*)(ws + 786432);      //  16384 B
    float*    iinf  = (float*)(ws + 802816);      //   8192 B
    unsigned* woPk  = (unsigned*)(ws + 811008);   // 114688 B [112][256]
    unsigned* wp2   = (unsigned*)(ws + 925696);   //  12544 B [56][56]
    unsigned* remb2 = (unsigned*)(ws + 938240);   //   7392 B [33][56]

    proj_kernel<<<N_NODES / 2, 512, 0, stream>>>(
        local, pos, qls, qlo, kls, klo,
        w_q, b_q, w_k, b_k, w_v, b_v,
        w_qp, b_qp, w_kp, b_kp, w_vp, b_vp,
        w_bias, b_bias, gamma,
        remb, w_pair, w_out,
        qnP, knT4, qpP, kpT4, valT2, kpT2,
        woPk, wp2, remb2, jinf, iinf);

    attn_kernel<<<N_NODES, 512, 0, stream>>>(
        qnP, knT4, qpP, kpT4, valT2, kpT2,
        woPk, wp2, remb2, jinf, iinf,
        resi, chain, batch, maskp,
        w_bias, gamma,
        (float*)d_out);
}

// Round 14
// 56.812 us; speedup vs baseline: 1.9967x; 1.0105x over previous
//
#include <hip/hip_runtime.h>
#include <hip/hip_bf16.h>
#include <cstddef>

// Problem constants (N, D, S, H, QP, VP) = (512, 256, 32, 4, 8, 8)
#define N_NODES 512
#define DIM     256
#define H_HEADS 4
#define PAIR_CN 56    // S + 3*VP
#define P3_N    96    // H*QP*3
#define FD_N    112   // P3 + 16
#define HPC     224   // H * PAIR_C

typedef _Float16 h2v  __attribute__((ext_vector_type(2)));
typedef _Float16 f16x8 __attribute__((ext_vector_type(8)));
typedef float    f32x4 __attribute__((ext_vector_type(4)));

__device__ __forceinline__ bool mask_true(const void* m, int idx) {
    if (((const unsigned char*)m)[idx] != 0) return true;
    return ((const int*)m)[idx] != 0;
}
__device__ __forceinline__ unsigned packh2(float a, float b) {
    _Float16 ha = (_Float16)a, hb = (_Float16)b;
    unsigned short ua, ub;
    __builtin_memcpy(&ua, &ha, 2); __builtin_memcpy(&ub, &hb, 2);
    return (unsigned)ua | ((unsigned)ub << 16);
}
__device__ __forceinline__ float h2lof(unsigned u) {
    unsigned short t = (unsigned short)(u & 0xffff);
    _Float16 h; __builtin_memcpy(&h, &t, 2); return (float)h;
}
__device__ __forceinline__ float h2hif(unsigned u) {
    unsigned short t = (unsigned short)(u >> 16);
    _Float16 h; __builtin_memcpy(&h, &t, 2); return (float)h;
}
__device__ __forceinline__ float dot2u(unsigned a, unsigned b, float c) {
#if __has_builtin(__builtin_amdgcn_fdot2)
    h2v ha, hb;
    __builtin_memcpy(&ha, &a, 4);
    __builtin_memcpy(&hb, &b, 4);
    return __builtin_amdgcn_fdot2(ha, hb, c, false);
#else
    return c + h2lof(a)*h2lof(b) + h2hif(a)*h2hif(b);
#endif
}
__device__ __forceinline__ f32x4 mfma16(uint4 a, uint4 b, f32x4 c) {
    f16x8 af, bf;
    __builtin_memcpy(&af, &a, 16);
    __builtin_memcpy(&bf, &b, 16);
    return __builtin_amdgcn_mfma_f32_16x16x32_f16(af, bf, c, 0, 0, 0);
}

// ---------------------------------------------------------------------------
// Phase 1: projections + LayerNorm + separable terms + weight packing.
//   qnP   [512][64]          q pairs (pre-scaled)
//   qpP   [512][48]          qp pairs
//   knT4  [16 dq][512 j][4]  kn (Pass A)
//   kpT4  [12 fq][512 j][4]  kp (Pass A)
//   BF    [20 nt][16 kt][64 lane][4 e2]  B-fragments of [val|kp] (Pass B MFMA)
//   woPk/wp2/remb2           packed epilogue weights
// ---------------------------------------------------------------------------
__global__ __launch_bounds__(512) void proj_kernel(
    const float* __restrict__ local, const float* __restrict__ pos,
    const float* __restrict__ qls, const float* __restrict__ qlo,
    const float* __restrict__ kls, const float* __restrict__ klo,
    const float* __restrict__ w_q, const float* __restrict__ b_q,
    const float* __restrict__ w_k, const float* __restrict__ b_k,
    const float* __restrict__ w_v, const float* __restrict__ b_v,
    const float* __restrict__ w_qp, const float* __restrict__ b_qp,
    const float* __restrict__ w_kp, const float* __restrict__ b_kp,
    const float* __restrict__ w_vp, const float* __restrict__ b_vp,
    const float* __restrict__ w_bias, const float* __restrict__ b_bias,
    const float* __restrict__ gamma,
    const float* __restrict__ remb, const float* __restrict__ w_pair,
    const float* __restrict__ w_out,
    unsigned* __restrict__ qnP, unsigned* __restrict__ knT4,
    unsigned* __restrict__ qpP, unsigned* __restrict__ kpT4,
    unsigned* __restrict__ BF,
    unsigned* __restrict__ woPk, unsigned* __restrict__ wp2,
    unsigned* __restrict__ remb2,
    float* __restrict__ jinfo, float* __restrict__ iinfo)
{
    const int i0 = blockIdx.x * 2;
    const int tid = threadIdx.x;

    __shared__ float xL[2][DIM];
    __shared__ float qraw[2][128];
    __shared__ float kraw[2][128];
    __shared__ float stat[2][16];
    __shared__ float qpL[2][P3_N];
    __shared__ float kpbL[2][P3_N];
    __shared__ float wbS[384];

    // ---- weight packing strips (blocks 0..15) ----
    if (blockIdx.x < 16) {
        for (int t = blockIdx.x*512 + tid; t < 33656; t += 8192) {
            if (t < 28672) {
                const int t2 = t >> 8, colx = t & 255;
                woPk[t] = packh2(w_out[(size_t)(2*t2)*DIM + colx],
                                 w_out[(size_t)(2*t2 + 1)*DIM + colx]);
            } else if (t < 31808) {
                const int v = t - 28672, f2 = v / 56, cx = v % 56;
                wp2[v] = packh2(w_pair[(2*f2)*PAIR_CN + cx],
                                w_pair[(2*f2 + 1)*PAIR_CN + cx]);
            } else {
                const int v = t - 31808, r2 = v / 56, cx = v % 56;
                remb2[v] = packh2(remb[(2*r2)*PAIR_CN + cx],
                                  remb[(2*r2 + 1)*PAIR_CN + cx]);
            }
        }
    }

    {
        const int r = tid >> 8, d = tid & 255;
        xL[r][d] = local[(size_t)(i0 + r) * DIM + d];
    }
    if (tid < 384) wbS[tid] = w_bias[tid];
    __syncthreads();

    // BF fragment constant for this node pair: kt = i0>>5, g = (i0>>3)&3, e2 = (i0>>1)&3
    const int cstBF = ((i0 >> 5) << 8) + (((i0 >> 3) & 3) << 6) + ((i0 >> 1) & 3);

    if (tid < 336) {
        const int colg = tid >> 1, dh = tid & 1;
        const int col = colg * 4;
        const float* w; int width, c, seg;
        if      (col < 128) { w = w_q;  c = col;       width = 128; seg = 0; }
        else if (col < 256) { w = w_k;  c = col - 128; width = 128; seg = 1; }
        else if (col < 384) { w = w_v;  c = col - 256; width = 128; seg = 2; }
        else if (col < 480) { w = w_qp; c = col - 384; width = 96;  seg = 3; }
        else if (col < 576) { w = w_kp; c = col - 480; width = 96;  seg = 4; }
        else                { w = w_vp; c = col - 576; width = 96;  seg = 5; }

        float acc[2][4] = {{0.f,0.f,0.f,0.f},{0.f,0.f,0.f,0.f}};
#pragma unroll 4
        for (int dd = 0; dd < 128; ++dd) {
            const int d = dh*128 + dd;
            float4 wv = *(const float4*)(w + (size_t)d * width + c);
#pragma unroll
            for (int r = 0; r < 2; ++r) {
                float x = xL[r][d];
                acc[r][0] += x * wv.x; acc[r][1] += x * wv.y;
                acc[r][2] += x * wv.z; acc[r][3] += x * wv.w;
            }
        }
#pragma unroll
        for (int r = 0; r < 2; ++r)
#pragma unroll
            for (int e = 0; e < 4; ++e)
                acc[r][e] += __shfl_xor(acc[r][e], 1);

        if (dh == 0) {
            const float cax0 = pos[i0*15+3],     cay0 = pos[i0*15+4],     caz0 = pos[i0*15+5];
            const float cax1 = pos[(i0+1)*15+3], cay1 = pos[(i0+1)*15+4], caz1 = pos[(i0+1)*15+5];
            float fr0[4], fr1[4];
            const bool isKp = (seg == 4), isQp = (seg == 3);
#pragma unroll
            for (int e = 0; e < 4; ++e) {
                const int cc = c + e;
                const float v0 = acc[0][e], v1 = acc[1][e];
                if (seg == 0) {
                    qraw[0][cc] = v0 + b_q[cc];
                    qraw[1][cc] = v1 + b_q[cc];
                } else if (seg == 1) {
                    kraw[0][cc] = v0 + b_k[cc];
                    kraw[1][cc] = v1 + b_k[cc];
                } else if (seg == 2) {
                    const int h = cc >> 5, sc = cc & 31;
                    const int colF = h*PAIR_CN + sc;
                    BF[(colF >> 4)*4096 + (colF & 15)*4 + cstBF] =
                        packh2(v0 + b_v[cc], v1 + b_v[cc]);
                } else if (seg == 3) {
                    const int x = cc % 3;
                    const float cav0 = (x==0)?cax0:((x==1)?cay0:caz0);
                    const float cav1 = (x==0)?cax1:((x==1)?cay1:caz1);
                    const float r0 = v0 + b_qp[cc] + cav0;
                    const float r1 = v1 + b_qp[cc] + cav1;
                    fr0[e] = r0; fr1[e] = r1;
                    qpL[0][cc] = r0; qpL[1][cc] = r1;
                } else if (seg == 4) {
                    const int x = cc % 3;
                    const float cav0 = (x==0)?cax0:((x==1)?cay0:caz0);
                    const float cav1 = (x==0)?cax1:((x==1)?cay1:caz1);
                    const float r0 = v0 + b_kp[cc] + cav0;
                    const float r1 = v1 + b_kp[cc] + cav1;
                    fr0[e] = r0; fr1[e] = r1;
                    const int colF = 224 + cc;
                    BF[(colF >> 4)*4096 + (colF & 15)*4 + cstBF] = packh2(r0, r1);
                    kpbL[0][cc] = (float)(_Float16)r0;
                    kpbL[1][cc] = (float)(_Float16)r1;
                } else {
                    const int h = cc / 24, rr = cc % 24, x = cc % 3;
                    const float cav0 = (x==0)?cax0:((x==1)?cay0:caz0);
                    const float cav1 = (x==0)?cax1:((x==1)?cay1:caz1);
                    const int colF = h*PAIR_CN + 32 + rr;
                    BF[(colF >> 4)*4096 + (colF & 15)*4 + cstBF] =
                        packh2(v0 + b_vp[cc] + cav0, v1 + b_vp[cc] + cav1);
                }
            }
            if (isQp) {
                const int f2 = c >> 1;
                qpP[(size_t)i0*48 + f2]         = packh2(fr0[0], fr0[1]);
                qpP[(size_t)i0*48 + f2 + 1]     = packh2(fr0[2], fr0[3]);
                qpP[(size_t)(i0+1)*48 + f2]     = packh2(fr1[0], fr1[1]);
                qpP[(size_t)(i0+1)*48 + f2 + 1] = packh2(fr1[2], fr1[3]);
            }
            if (isKp) {
                const int f2 = c >> 1;
                const int fq = f2 >> 2;
                kpT4[((size_t)fq*N_NODES + i0    )*4 + (f2 & 3)]       = packh2(fr0[0], fr0[1]);
                kpT4[((size_t)fq*N_NODES + i0    )*4 + ((f2 + 1) & 3)] = packh2(fr0[2], fr0[3]);
                kpT4[((size_t)fq*N_NODES + i0 + 1)*4 + (f2 & 3)]       = packh2(fr1[0], fr1[1]);
                kpT4[((size_t)fq*N_NODES + i0 + 1)*4 + ((f2 + 1) & 3)] = packh2(fr1[2], fr1[3]);
            }
        }
    }
    __syncthreads();

    if (tid < 16) {
        const int r = tid >> 3, t = tid & 7;
        const float* src = (t < 4) ? qraw[r] : kraw[r];
        const int h = t & 3, base = (t < 4) ? 0 : 8;
        float mu = 0.f;
        for (int c = 0; c < 32; ++c) mu += src[h*32 + c];
        mu *= (1.f/32.f);
        float var = 0.f;
        for (int c = 0; c < 32; ++c) { float d = src[h*32 + c] - mu; var += d*d; }
        var *= (1.f/32.f);
        stat[r][base + h*2 + 0] = mu;
        stat[r][base + h*2 + 1] = var;
    }
    __syncthreads();

    {
        const int r = tid >> 8, u = tid & 255;
        const int i = i0 + r;
        if (u < 128) {
            const int h = u >> 5, sidx = u & 31;
            const float mu = stat[r][h*2], var = stat[r][h*2+1];
            float v = (qraw[r][u] - mu) * rsqrtf(var + 1e-5f) * qls[sidx] + qlo[sidx];
            v *= 0.17677669529663687f;  // * sqrt(1/S)
            const float vo = __shfl_xor(v, 1);
            if (!(u & 1)) qnP[(size_t)i*64 + (u >> 1)] = packh2(v, vo);
        } else {
            const int u2 = u - 128, h = u2 >> 5, sidx = u2 & 31;
            const float mu = stat[r][8 + h*2], var = stat[r][9 + h*2];
            float v = (kraw[r][u2] - mu) * rsqrtf(var + 1e-5f) * kls[sidx] + klo[sidx];
            const float vo = __shfl_xor(v, 1);
            if (!(u2 & 1))
                knT4[(((size_t)(u2 >> 3))*N_NODES + i)*4 + ((u2 >> 1) & 3)] = packh2(v, vo);
        }
    }

    // ---- separable terms, 64 threads = 2 r x 4 h x 8 ks ----
    if (tid < 64) {
        const int r = tid >> 5, h = (tid >> 3) & 3, ks = tid & 7;
        float uacc = 0.f, tacc = 0.f;
#pragma unroll
        for (int f = ks; f < P3_N; f += 8) {
            float wb = wbS[f*4 + h];
            uacc += qpL[r][f] * wb;
            tacc += kpbL[r][f] * wb;
        }
        float nq = 0.f, nk = 0.f;
#pragma unroll
        for (int f = h*24 + ks*3; f < h*24 + ks*3 + 3; ++f) {
            nq += qpL[r][f]*qpL[r][f];
            nk += kpbL[r][f]*kpbL[r][f];
        }
        uacc += __shfl_xor(uacc,1); uacc += __shfl_xor(uacc,2); uacc += __shfl_xor(uacc,4);
        tacc += __shfl_xor(tacc,1); tacc += __shfl_xor(tacc,2); tacc += __shfl_xor(tacc,4);
        nq   += __shfl_xor(nq,1);   nq   += __shfl_xor(nq,2);   nq   += __shfl_xor(nq,4);
        nk   += __shfl_xor(nk,1);   nk   += __shfl_xor(nk,2);   nk   += __shfl_xor(nk,4);
        if (ks == 0) {
            const int n = i0 + r;
            const float ps = log1pf(expf(gamma[h])) * (1.0f/12.0f);
            iinfo[n*4 + h] = -ps*nq + uacc + b_bias[h];
            jinfo[n*8 + h] = -ps*nk - tacc;
            if (h == 0) {
                jinfo[n*8 + 4] = 10.f * pos[n*15 + 3];
                jinfo[n*8 + 5] = 10.f * pos[n*15 + 4];
                jinfo[n*8 + 6] = 10.f * pos[n*15 + 5];
                jinfo[n*8 + 7] = 0.f;
            }
        }
    }
}

// ---------------------------------------------------------------------------
// Phase 2: one block per query row. 512 threads, grid 512.
// Pass A: thread=j uint4 dot2. Pass B: MFMA P x [val|kp] (waves 0-6) + rbf wave.
// ---------------------------------------------------------------------------
__global__ __launch_bounds__(512, 4) void attn_kernel(
    const unsigned* __restrict__ qnP, const unsigned* __restrict__ knT4,
    const unsigned* __restrict__ qpP, const unsigned* __restrict__ kpT4,
    const unsigned* __restrict__ BF,
    const unsigned* __restrict__ woPk, const unsigned* __restrict__ wp2,
    const unsigned* __restrict__ remb2,
    const float* __restrict__ jinfo, const float* __restrict__ iinfo,
    const int* __restrict__ resi, const int* __restrict__ chain,
    const int* __restrict__ batch, const void* __restrict__ maskp,
    const float* __restrict__ w_bias, const float* __restrict__ gamma,
    float* __restrict__ out)
{
    const int i    = blockIdx.x;
    const int tid  = threadIdx.x;
    const int lane = tid & 63;
    const int wv   = tid >> 6;

    __shared__ unsigned qpkL[64];
    __shared__ unsigned qspkL[48];
    __shared__ unsigned wbPk[H_HEADS][8];
    __shared__ __align__(16) unsigned rbfP[N_NODES][9];
    __shared__ __align__(16) unsigned attnH[H_HEADS][260];
    __shared__ float    mxW[8][H_HEADS], smW[8][H_HEADS];
    __shared__ float    asL[H_HEADS];
    __shared__ float    qpiL[P3_N];
    __shared__ float    GLfF[H_HEADS][P3_N];
    __shared__ float    GLfR[H_HEADS][16];
    __shared__ unsigned GLf2[H_HEADS][56];
    __shared__ unsigned abktP[H_HEADS][33];
    __shared__ float    resL[HPC];
    __shared__ unsigned resH[FD_N];
    __shared__ float    abkt2[2][H_HEADS][66];
    __shared__ unsigned char rdL[N_NODES], pmL[N_NODES];

    // ---- init ----
    if (tid < 64) {
        qpkL[tid] = qnP[(size_t)i*64 + tid];
    } else if (tid < 112) {
        const int f2 = tid - 64, h = f2 / 12;
        const float ps2 = 2.f * log1pf(expf(gamma[h])) * (1.0f/12.0f);
        const unsigned u = qpP[(size_t)i*48 + f2];
        qspkL[f2] = packh2(ps2*h2lof(u), ps2*h2hif(u));
    } else if (tid < 160) {
        const int f2 = tid - 112;
        const unsigned u = qpP[(size_t)i*48 + f2];
        qpiL[2*f2]   = h2lof(u);
        qpiL[2*f2+1] = h2hif(u);
    } else if (tid < 192) {
        const int v = tid - 160, h = v >> 3, e = v & 7;
        wbPk[h][e] = packh2(w_bias[(P3_N + 2*e)*H_HEADS + h],
                            w_bias[(P3_N + 2*e + 1)*H_HEADS + h]);
    }
    for (int t = tid; t < 2*H_HEADS*66; t += 512) ((float*)abkt2)[t] = 0.f;

    const int  r_i = resi[i], ch_i = chain[i], ba_i = batch[i];
    const bool m_i = mask_true(maskp, i);
    const float dix = jinfo[(size_t)i*8+4], diy = jinfo[(size_t)i*8+5], diz = jinfo[(size_t)i*8+6];

    const float inv3  = 0.57735026918962576f;
    const float rstep = 0.72727272727272727f;   // 1/1.375

    // ---- per-thread j prework ----
    const int j = tid;
    const float4 vq4 = *(const float4*)(jinfo + (size_t)j*8);
    const float4 dj4 = *(const float4*)(jinfo + (size_t)j*8 + 4);
    const float4 ci4 = *(const float4*)(iinfo + (size_t)i*4);
    const float vqa[4] = {vq4.x, vq4.y, vq4.z, vq4.w};
    const float cia[4] = {ci4.x, ci4.y, ci4.z, ci4.w};
    const float dd0 = dix - dj4.x, dd1 = diy - dj4.y, dd2 = diz - dj4.z;
    const float dist = sqrtf(dd0*dd0 + dd1*dd1 + dd2*dd2 + 1e-6f);
    unsigned rr[8];
#pragma unroll
    for (int p = 0; p < 8; ++p) {
        const float u0 = (dist - (1.375f*(float)(2*p)   + 0.6875f)) * rstep;
        const float u1 = (dist - (1.375f*(float)(2*p+1) + 0.6875f)) * rstep;
        rr[p] = packh2(__expf(-u0*u0), __expf(-u1*u1));
        rbfP[j][p] = rr[p];
    }
    const int  rj = resi[j], cj = chain[j], bj = batch[j];
    const bool pm = m_i && mask_true(maskp, j) && (ba_i == bj);
    rdL[j] = (unsigned char)((ch_i != cj) ? 65 : (min(max(r_i - rj, -32), 32) + 32));
    pmL[j] = pm ? 1 : 0;
    __syncthreads();

    // ================= Pass A: uint4 streaming dots =================
    float lv[4];
    {
        const uint4* kcol = (const uint4*)knT4 + j;
        const uint4* pcol = (const uint4*)kpT4 + j;
        const uint4* qk4  = (const uint4*)qpkL;
        const uint4* qs4  = (const uint4*)qspkL;
#pragma unroll
        for (int h = 0; h < 4; ++h) {
            float acc = 0.f;
#pragma unroll
            for (int g = 0; g < 4; ++g) {
                const uint4 kk = kcol[(size_t)(h*4 + g)*N_NODES];
                const uint4 qq = qk4[h*4 + g];
                acc = dot2u(kk.x, qq.x, acc);
                acc = dot2u(kk.y, qq.y, acc);
                acc = dot2u(kk.z, qq.z, acc);
                acc = dot2u(kk.w, qq.w, acc);
            }
#pragma unroll
            for (int g = 0; g < 3; ++g) {
                const uint4 kk = pcol[(size_t)(h*3 + g)*N_NODES];
                const uint4 qq = qs4[h*3 + g];
                acc = dot2u(kk.x, qq.x, acc);
                acc = dot2u(kk.y, qq.y, acc);
                acc = dot2u(kk.z, qq.z, acc);
                acc = dot2u(kk.w, qq.w, acc);
            }
            const uint4 w0 = *(const uint4*)&wbPk[h][0];
            const uint4 w1 = *(const uint4*)&wbPk[h][4];
            acc = dot2u(rr[0], w0.x, acc);
            acc = dot2u(rr[1], w0.y, acc);
            acc = dot2u(rr[2], w0.z, acc);
            acc = dot2u(rr[3], w0.w, acc);
            acc = dot2u(rr[4], w1.x, acc);
            acc = dot2u(rr[5], w1.y, acc);
            acc = dot2u(rr[6], w1.z, acc);
            acc = dot2u(rr[7], w1.w, acc);
            lv[h] = pm ? (acc + cia[h] + vqa[h]) * inv3 : -1e9f;
        }
    }

    // ================= Softmax: 2 reduce rounds =================
    {
        float mx[4] = {lv[0], lv[1], lv[2], lv[3]};
#pragma unroll
        for (int off = 1; off < 64; off <<= 1) {
#pragma unroll
            for (int h = 0; h < 4; ++h) mx[h] = fmaxf(mx[h], __shfl_xor(mx[h], off));
        }
        if (lane == 0) *(float4*)&mxW[wv][0] = make_float4(mx[0], mx[1], mx[2], mx[3]);
        __syncthreads();
        float mxg[4] = {-1e30f, -1e30f, -1e30f, -1e30f};
#pragma unroll
        for (int w = 0; w < 8; ++w) {
            const float4 m = *(const float4*)&mxW[w][0];
            mxg[0] = fmaxf(mxg[0], m.x); mxg[1] = fmaxf(mxg[1], m.y);
            mxg[2] = fmaxf(mxg[2], m.z); mxg[3] = fmaxf(mxg[3], m.w);
        }
        float e[4], sm[4];
#pragma unroll
        for (int h = 0; h < 4; ++h) {
            e[h] = pm ? __expf(lv[h] - mxg[h]) : 0.f;
            sm[h] = e[h];
        }
#pragma unroll
        for (int off = 1; off < 64; off <<= 1) {
#pragma unroll
            for (int h = 0; h < 4; ++h) sm[h] += __shfl_xor(sm[h], off);
        }
        if (lane == 0) *(float4*)&smW[wv][0] = make_float4(sm[0], sm[1], sm[2], sm[3]);
        __syncthreads();
        float smt[4] = {0.f, 0.f, 0.f, 0.f};
#pragma unroll
        for (int w = 0; w < 8; ++w) {
            const float4 m = *(const float4*)&smW[w][0];
            smt[0] += m.x; smt[1] += m.y; smt[2] += m.z; smt[3] += m.w;
        }
        const int half = j >> 8;
        float p[4];
#pragma unroll
        for (int h = 0; h < 4; ++h) {
            const float rden = 1.f / fmaxf(smt[h], 1e-37f);
            p[h] = e[h] * rden;
            atomicAdd(&abkt2[half][h][rdL[j]], p[h]);
        }
        if (tid == 0) {
#pragma unroll
            for (int h = 0; h < 4; ++h)
                asL[h] = smt[h] / fmaxf(smt[h], 1e-37f);
        }
#pragma unroll
        for (int h = 0; h < 4; ++h) {
            const float po = __shfl_xor(p[h], 1);
            if (!(j & 1)) attnH[h][j >> 1] = packh2(p[h], po);
        }
    }
    __syncthreads();

    // ================= Pass B: MFMA P x [val|kp] =================
    if (wv < 7) {
        const int row = lane & 15;
        const int ntA = wv, ntB = wv + 7, ntC = wv + 14;
        const bool hasC = (ntC < 20);
        f32x4 accA = {0.f,0.f,0.f,0.f};
        f32x4 accB = {0.f,0.f,0.f,0.f};
        f32x4 accC = {0.f,0.f,0.f,0.f};
        const uint4* bfp = (const uint4*)BF;
#pragma unroll 4
        for (int kt = 0; kt < 16; ++kt) {
            uint4 au = make_uint4(0u, 0u, 0u, 0u);
            if (row < 4) au = *(const uint4*)&attnH[row][kt*16 + (lane >> 4)*4];
            const uint4 bA = bfp[(ntA*16 + kt)*64 + lane];
            const uint4 bB = bfp[(ntB*16 + kt)*64 + lane];
            accA = mfma16(au, bA, accA);
            accB = mfma16(au, bB, accB);
            if (hasC) {
                const uint4 bC = bfp[(ntC*16 + kt)*64 + lane];
                accC = mfma16(au, bC, accC);
            }
        }
        if (lane < 16) {
            {
                const int s = ntA*16 + lane, h = s / PAIR_CN;
                resL[s] = (h==0) ? accA[0] : ((h==1) ? accA[1] : ((h==2) ? accA[2] : accA[3]));
            }
            {
                const int s = ntB*16 + lane, h = s / PAIR_CN;
                resL[s] = (h==0) ? accB[0] : ((h==1) ? accB[1] : ((h==2) ? accB[2] : accB[3]));
            }
            if (hasC) {
                const int f = (ntC - 14)*16 + lane;
                GLfF[0][f] = accC[0];
                GLfF[1][f] = accC[1];
                GLfF[2][f] = accC[2];
                GLfF[3][f] = accC[3];
            }
        }
    } else {
        // rbf-G: wave 7, 16 bins x 4 quarters
        const int idx = tid - 448, b = idx >> 2, q = idx & 3;
        const int w = b >> 1;
        const bool hi = (b & 1);
        float a[4] = {0.f, 0.f, 0.f, 0.f};
#pragma unroll 4
        for (int jpp = q*64; jpp < q*64 + 64; ++jpp) {
            const unsigned r0 = rbfP[2*jpp][w];
            const unsigned r1 = rbfP[2*jpp + 1][w];
            const unsigned ee = hi ? ((r0 >> 16) | (r1 & 0xffff0000u))
                                   : ((r0 & 0xffffu) | (r1 << 16));
            a[0] = dot2u(ee, attnH[0][jpp], a[0]);
            a[1] = dot2u(ee, attnH[1][jpp], a[1]);
            a[2] = dot2u(ee, attnH[2][jpp], a[2]);
            a[3] = dot2u(ee, attnH[3][jpp], a[3]);
        }
#pragma unroll
        for (int h = 0; h < 4; ++h) {
            a[h] += __shfl_xor(a[h], 1);
            a[h] += __shfl_xor(a[h], 2);
            if (q == 0) GLfR[h][b] = a[h];
        }
    }
    __syncthreads();

    // ================= Combine: GLf2 pack, abktP pack ====================
    for (int t = tid; t < 224; t += 512) {   // t = h*56 + f2
        const int h = t / 56, f2 = t % 56;
        if (f2 < 48) {
            GLf2[h][f2] = packh2(qpiL[2*f2]*asL[h]     - GLfF[h][2*f2],
                                 qpiL[2*f2 + 1]*asL[h] - GLfF[h][2*f2 + 1]);
        } else {
            GLf2[h][f2] = packh2(GLfR[h][(f2 - 48)*2], GLfR[h][(f2 - 48)*2 + 1]);
        }
    }
    for (int t = tid; t < 132; t += 512) {   // t = h*33 + r2
        const int h = t / 33, r2 = t % 33;
        abktP[h][r2] = packh2(abkt2[0][h][2*r2]   + abkt2[1][h][2*r2],
                              abkt2[0][h][2*r2+1] + abkt2[1][h][2*r2+1]);
    }
    __syncthreads();

    // ================= Epilogue (packed dot2) ====================
    if (tid < HPC) {
        const int h = tid / PAIR_CN, c = tid - h*PAIR_CN;
        float r = resL[tid];
#pragma unroll 8
        for (int r2 = 0; r2 < 33; ++r2)
            r = dot2u(remb2[r2*56 + c], abktP[h][r2], r);
#pragma unroll 8
        for (int f2 = 0; f2 < 56; ++f2)
            r = dot2u(wp2[f2*56 + c], GLf2[h][f2], r);
        resL[tid] = r;
    }
    __syncthreads();

    if (tid < FD_N) resH[tid] = packh2(resL[2*tid], resL[2*tid + 1]);
    __syncthreads();

    // ================= out = resH . woPk (t-split 2-way) ====================
    {
        const int col = tid >> 1, ph = tid & 1;
        float o = 0.f;
#pragma unroll 7
        for (int t2 = ph*56; t2 < ph*56 + 56; ++t2)
            o = dot2u(woPk[t2*256 + col], resH[t2], o);
        o += __shfl_xor(o, 1);
        if (ph == 0) out[(size_t)i*DIM + col] = o;
    }
}

// ---------------------------------------------------------------------------
extern "C" void kernel_launch(void* const* d_in, const int* in_sizes, int n_in,
                              void* d_out, int out_size, void* d_ws, size_t ws_size,
                              hipStream_t stream) {
    (void)in_sizes; (void)n_in; (void)out_size; (void)ws_size;
    const float* local = (const float*)d_in[0];
    const float* pos   = (const float*)d_in[1];
    const int*   resi  = (const int*)d_in[2];
    const int*   chain = (const int*)d_in[3];
    const int*   batch = (const int*)d_in[4];
    const void*  maskp = d_in[5];
    const float* qls   = (const float*)d_in[6];
    const float* qlo   = (const float*)d_in[7];
    const float* kls   = (const float*)d_in[8];
    const float* klo   = (const float*)d_in[9];
    const float* w_q   = (const float*)d_in[10];
    const float* b_q   = (const float*)d_in[11];
    const float* w_k   = (const float*)d_in[12];
    const float* b_k   = (const float*)d_in[13];
    const float* w_v   = (const float*)d_in[14];
    const float* b_v   = (const float*)d_in[15];
    const float* w_qp  = (const float*)d_in[16];
    const float* b_qp  = (const float*)d_in[17];
    const float* w_kp  = (const float*)d_in[18];
    const float* b_kp  = (const float*)d_in[19];
    const float* w_vp  = (const float*)d_in[20];
    const float* b_vp  = (const float*)d_in[21];
    const float* remb  = (const float*)d_in[22];
    const float* w_pair= (const float*)d_in[23];
    const float* w_bias= (const float*)d_in[24];
    const float* b_bias= (const float*)d_in[25];
    const float* gamma = (const float*)d_in[26];
    const float* w_out = (const float*)d_in[27];

    char* ws = (char*)d_ws;
    unsigned* qnP   = (unsigned*)(ws);            // 131072 B [512][64]
    unsigned* qpP   = (unsigned*)(ws + 131072);   //  98304 B [512][48]
    unsigned* knT4  = (unsigned*)(ws + 229376);   // 131072 B [16][512][4]
    unsigned* kpT4  = (unsigned*)(ws + 360448);   //  98304 B [12][512][4]
    unsigned* BF    = (unsigned*)(ws + 458752);   // 327680 B [20][16][64][4]
    float*    jinf  = (float*)(ws + 786432);      //  16384 B
    float*    iinf  = (float*)(ws + 802816);      //   8192 B
    unsigned* woPk  = (unsigned*)(ws + 811008);   // 114688 B [112][256]
    unsigned* wp2   = (unsigned*)(ws + 925696);   //  12544 B [56][56]
    unsigned* remb2 = (unsigned*)(ws + 938240);   //   7392 B [33][56]

    proj_kernel<<<N_NODES / 2, 512, 0, stream>>>(
        local, pos, qls, qlo, kls, klo,
        w_q, b_q, w_k, b_k, w_v, b_v,
        w_qp, b_qp, w_kp, b_kp, w_vp, b_vp,
        w_bias, b_bias, gamma,
        remb, w_pair, w_out,
        qnP, knT4, qpP, kpT4, BF,
        woPk, wp2, remb2, jinf, iinf);

    attn_kernel<<<N_NODES, 512, 0, stream>>>(
        qnP, knT4, qpP, kpT4, BF,
        woPk, wp2, remb2, jinf, iinf,
        resi, chain, batch, maskp,
        w_bias, gamma,
        (float*)d_out);
}

// Round 15
// 53.958 us; speedup vs baseline: 2.1023x; 1.0529x over previous
//
#include <hip/hip_runtime.h>
#include <hip/hip_bf16.h>
#include <cstddef>

// Problem constants (N, D, S, H, QP, VP) = (512, 256, 32, 4, 8, 8)
#define N_NODES 512
#define DIM     256
#define H_HEADS 4
#define PAIR_CN 56    // S + 3*VP
#define P3_N    96    // H*QP*3
#define FD_N    112   // P3 + 16
#define HPC     224   // H * PAIR_C

typedef _Float16 h2v  __attribute__((ext_vector_type(2)));
typedef _Float16 f16x8 __attribute__((ext_vector_type(8)));
typedef float    f32x4 __attribute__((ext_vector_type(4)));

__device__ __forceinline__ bool mask_true(const void* m, int idx) {
    if (((const unsigned char*)m)[idx] != 0) return true;
    return ((const int*)m)[idx] != 0;
}
__device__ __forceinline__ unsigned packh2(float a, float b) {
    _Float16 ha = (_Float16)a, hb = (_Float16)b;
    unsigned short ua, ub;
    __builtin_memcpy(&ua, &ha, 2); __builtin_memcpy(&ub, &hb, 2);
    return (unsigned)ua | ((unsigned)ub << 16);
}
__device__ __forceinline__ float h2lof(unsigned u) {
    unsigned short t = (unsigned short)(u & 0xffff);
    _Float16 h; __builtin_memcpy(&h, &t, 2); return (float)h;
}
__device__ __forceinline__ float h2hif(unsigned u) {
    unsigned short t = (unsigned short)(u >> 16);
    _Float16 h; __builtin_memcpy(&h, &t, 2); return (float)h;
}
__device__ __forceinline__ float dot2u(unsigned a, unsigned b, float c) {
#if __has_builtin(__builtin_amdgcn_fdot2)
    h2v ha, hb;
    __builtin_memcpy(&ha, &a, 4);
    __builtin_memcpy(&hb, &b, 4);
    return __builtin_amdgcn_fdot2(ha, hb, c, false);
#else
    return c + h2lof(a)*h2lof(b) + h2hif(a)*h2hif(b);
#endif
}
__device__ __forceinline__ f32x4 mfma16(uint4 a, uint4 b, f32x4 c) {
    f16x8 af, bf;
    __builtin_memcpy(&af, &a, 16);
    __builtin_memcpy(&bf, &b, 16);
    return __builtin_amdgcn_mfma_f32_16x16x32_f16(af, bf, c, 0, 0, 0);
}

// ---------------------------------------------------------------------------
// Phase 1: projections + LayerNorm + separable terms + weight packing.
// (unchanged from round 14)
// ---------------------------------------------------------------------------
__global__ __launch_bounds__(512) void proj_kernel(
    const float* __restrict__ local, const float* __restrict__ pos,
    const float* __restrict__ qls, const float* __restrict__ qlo,
    const float* __restrict__ kls, const float* __restrict__ klo,
    const float* __restrict__ w_q, const float* __restrict__ b_q,
    const float* __restrict__ w_k, const float* __restrict__ b_k,
    const float* __restrict__ w_v, const float* __restrict__ b_v,
    const float* __restrict__ w_qp, const float* __restrict__ b_qp,
    const float* __restrict__ w_kp, const float* __restrict__ b_kp,
    const float* __restrict__ w_vp, const float* __restrict__ b_vp,
    const float* __restrict__ w_bias, const float* __restrict__ b_bias,
    const float* __restrict__ gamma,
    const float* __restrict__ remb, const float* __restrict__ w_pair,
    const float* __restrict__ w_out,
    unsigned* __restrict__ qnP, unsigned* __restrict__ knT4,
    unsigned* __restrict__ qpP, unsigned* __restrict__ kpT4,
    unsigned* __restrict__ BF,
    unsigned* __restrict__ woPk, unsigned* __restrict__ wp2,
    unsigned* __restrict__ remb2,
    float* __restrict__ jinfo, float* __restrict__ iinfo)
{
    const int i0 = blockIdx.x * 2;
    const int tid = threadIdx.x;

    __shared__ float xL[2][DIM];
    __shared__ float qraw[2][128];
    __shared__ float kraw[2][128];
    __shared__ float stat[2][16];
    __shared__ float qpL[2][P3_N];
    __shared__ float kpbL[2][P3_N];
    __shared__ float wbS[384];

    if (blockIdx.x < 16) {
        for (int t = blockIdx.x*512 + tid; t < 33656; t += 8192) {
            if (t < 28672) {
                const int t2 = t >> 8, colx = t & 255;
                woPk[t] = packh2(w_out[(size_t)(2*t2)*DIM + colx],
                                 w_out[(size_t)(2*t2 + 1)*DIM + colx]);
            } else if (t < 31808) {
                const int v = t - 28672, f2 = v / 56, cx = v % 56;
                wp2[v] = packh2(w_pair[(2*f2)*PAIR_CN + cx],
                                w_pair[(2*f2 + 1)*PAIR_CN + cx]);
            } else {
                const int v = t - 31808, r2 = v / 56, cx = v % 56;
                remb2[v] = packh2(remb[(2*r2)*PAIR_CN + cx],
                                  remb[(2*r2 + 1)*PAIR_CN + cx]);
            }
        }
    }

    {
        const int r = tid >> 8, d = tid & 255;
        xL[r][d] = local[(size_t)(i0 + r) * DIM + d];
    }
    if (tid < 384) wbS[tid] = w_bias[tid];
    __syncthreads();

    const int cstBF = ((i0 >> 5) << 8) + (((i0 >> 3) & 3) << 6) + ((i0 >> 1) & 3);

    if (tid < 336) {
        const int colg = tid >> 1, dh = tid & 1;
        const int col = colg * 4;
        const float* w; int width, c, seg;
        if      (col < 128) { w = w_q;  c = col;       width = 128; seg = 0; }
        else if (col < 256) { w = w_k;  c = col - 128; width = 128; seg = 1; }
        else if (col < 384) { w = w_v;  c = col - 256; width = 128; seg = 2; }
        else if (col < 480) { w = w_qp; c = col - 384; width = 96;  seg = 3; }
        else if (col < 576) { w = w_kp; c = col - 480; width = 96;  seg = 4; }
        else                { w = w_vp; c = col - 576; width = 96;  seg = 5; }

        float acc[2][4] = {{0.f,0.f,0.f,0.f},{0.f,0.f,0.f,0.f}};
#pragma unroll 4
        for (int dd = 0; dd < 128; ++dd) {
            const int d = dh*128 + dd;
            float4 wv = *(const float4*)(w + (size_t)d * width + c);
#pragma unroll
            for (int r = 0; r < 2; ++r) {
                float x = xL[r][d];
                acc[r][0] += x * wv.x; acc[r][1] += x * wv.y;
                acc[r][2] += x * wv.z; acc[r][3] += x * wv.w;
            }
        }
#pragma unroll
        for (int r = 0; r < 2; ++r)
#pragma unroll
            for (int e = 0; e < 4; ++e)
                acc[r][e] += __shfl_xor(acc[r][e], 1);

        if (dh == 0) {
            const float cax0 = pos[i0*15+3],     cay0 = pos[i0*15+4],     caz0 = pos[i0*15+5];
            const float cax1 = pos[(i0+1)*15+3], cay1 = pos[(i0+1)*15+4], caz1 = pos[(i0+1)*15+5];
            float fr0[4], fr1[4];
            const bool isKp = (seg == 4), isQp = (seg == 3);
#pragma unroll
            for (int e = 0; e < 4; ++e) {
                const int cc = c + e;
                const float v0 = acc[0][e], v1 = acc[1][e];
                if (seg == 0) {
                    qraw[0][cc] = v0 + b_q[cc];
                    qraw[1][cc] = v1 + b_q[cc];
                } else if (seg == 1) {
                    kraw[0][cc] = v0 + b_k[cc];
                    kraw[1][cc] = v1 + b_k[cc];
                } else if (seg == 2) {
                    const int h = cc >> 5, sc = cc & 31;
                    const int colF = h*PAIR_CN + sc;
                    BF[(colF >> 4)*4096 + (colF & 15)*4 + cstBF] =
                        packh2(v0 + b_v[cc], v1 + b_v[cc]);
                } else if (seg == 3) {
                    const int x = cc % 3;
                    const float cav0 = (x==0)?cax0:((x==1)?cay0:caz0);
                    const float cav1 = (x==0)?cax1:((x==1)?cay1:caz1);
                    const float r0 = v0 + b_qp[cc] + cav0;
                    const float r1 = v1 + b_qp[cc] + cav1;
                    fr0[e] = r0; fr1[e] = r1;
                    qpL[0][cc] = r0; qpL[1][cc] = r1;
                } else if (seg == 4) {
                    const int x = cc % 3;
                    const float cav0 = (x==0)?cax0:((x==1)?cay0:caz0);
                    const float cav1 = (x==0)?cax1:((x==1)?cay1:caz1);
                    const float r0 = v0 + b_kp[cc] + cav0;
                    const float r1 = v1 + b_kp[cc] + cav1;
                    fr0[e] = r0; fr1[e] = r1;
                    const int colF = 224 + cc;
                    BF[(colF >> 4)*4096 + (colF & 15)*4 + cstBF] = packh2(r0, r1);
                    kpbL[0][cc] = (float)(_Float16)r0;
                    kpbL[1][cc] = (float)(_Float16)r1;
                } else {
                    const int h = cc / 24, rr = cc % 24, x = cc % 3;
                    const float cav0 = (x==0)?cax0:((x==1)?cay0:caz0);
                    const float cav1 = (x==0)?cax1:((x==1)?cay1:caz1);
                    const int colF = h*PAIR_CN + 32 + rr;
                    BF[(colF >> 4)*4096 + (colF & 15)*4 + cstBF] =
                        packh2(v0 + b_vp[cc] + cav0, v1 + b_vp[cc] + cav1);
                }
            }
            if (isQp) {
                const int f2 = c >> 1;
                qpP[(size_t)i0*48 + f2]         = packh2(fr0[0], fr0[1]);
                qpP[(size_t)i0*48 + f2 + 1]     = packh2(fr0[2], fr0[3]);
                qpP[(size_t)(i0+1)*48 + f2]     = packh2(fr1[0], fr1[1]);
                qpP[(size_t)(i0+1)*48 + f2 + 1] = packh2(fr1[2], fr1[3]);
            }
            if (isKp) {
                const int f2 = c >> 1;
                const int fq = f2 >> 2;
                kpT4[((size_t)fq*N_NODES + i0    )*4 + (f2 & 3)]       = packh2(fr0[0], fr0[1]);
                kpT4[((size_t)fq*N_NODES + i0    )*4 + ((f2 + 1) & 3)] = packh2(fr0[2], fr0[3]);
                kpT4[((size_t)fq*N_NODES + i0 + 1)*4 + (f2 & 3)]       = packh2(fr1[0], fr1[1]);
                kpT4[((size_t)fq*N_NODES + i0 + 1)*4 + ((f2 + 1) & 3)] = packh2(fr1[2], fr1[3]);
            }
        }
    }
    __syncthreads();

    if (tid < 16) {
        const int r = tid >> 3, t = tid & 7;
        const float* src = (t < 4) ? qraw[r] : kraw[r];
        const int h = t & 3, base = (t < 4) ? 0 : 8;
        float mu = 0.f;
        for (int c = 0; c < 32; ++c) mu += src[h*32 + c];
        mu *= (1.f/32.f);
        float var = 0.f;
        for (int c = 0; c < 32; ++c) { float d = src[h*32 + c] - mu; var += d*d; }
        var *= (1.f/32.f);
        stat[r][base + h*2 + 0] = mu;
        stat[r][base + h*2 + 1] = var;
    }
    __syncthreads();

    {
        const int r = tid >> 8, u = tid & 255;
        const int i = i0 + r;
        if (u < 128) {
            const int h = u >> 5, sidx = u & 31;
            const float mu = stat[r][h*2], var = stat[r][h*2+1];
            float v = (qraw[r][u] - mu) * rsqrtf(var + 1e-5f) * qls[sidx] + qlo[sidx];
            v *= 0.17677669529663687f;  // * sqrt(1/S)
            const float vo = __shfl_xor(v, 1);
            if (!(u & 1)) qnP[(size_t)i*64 + (u >> 1)] = packh2(v, vo);
        } else {
            const int u2 = u - 128, h = u2 >> 5, sidx = u2 & 31;
            const float mu = stat[r][8 + h*2], var = stat[r][9 + h*2];
            float v = (kraw[r][u2] - mu) * rsqrtf(var + 1e-5f) * kls[sidx] + klo[sidx];
            const float vo = __shfl_xor(v, 1);
            if (!(u2 & 1))
                knT4[(((size_t)(u2 >> 3))*N_NODES + i)*4 + ((u2 >> 1) & 3)] = packh2(v, vo);
        }
    }

    if (tid < 64) {
        const int r = tid >> 5, h = (tid >> 3) & 3, ks = tid & 7;
        float uacc = 0.f, tacc = 0.f;
#pragma unroll
        for (int f = ks; f < P3_N; f += 8) {
            float wb = wbS[f*4 + h];
            uacc += qpL[r][f] * wb;
            tacc += kpbL[r][f] * wb;
        }
        float nq = 0.f, nk = 0.f;
#pragma unroll
        for (int f = h*24 + ks*3; f < h*24 + ks*3 + 3; ++f) {
            nq += qpL[r][f]*qpL[r][f];
            nk += kpbL[r][f]*kpbL[r][f];
        }
        uacc += __shfl_xor(uacc,1); uacc += __shfl_xor(uacc,2); uacc += __shfl_xor(uacc,4);
        tacc += __shfl_xor(tacc,1); tacc += __shfl_xor(tacc,2); tacc += __shfl_xor(tacc,4);
        nq   += __shfl_xor(nq,1);   nq   += __shfl_xor(nq,2);   nq   += __shfl_xor(nq,4);
        nk   += __shfl_xor(nk,1);   nk   += __shfl_xor(nk,2);   nk   += __shfl_xor(nk,4);
        if (ks == 0) {
            const int n = i0 + r;
            const float ps = log1pf(expf(gamma[h])) * (1.0f/12.0f);
            iinfo[n*4 + h] = -ps*nq + uacc + b_bias[h];
            jinfo[n*8 + h] = -ps*nk - tacc;
            if (h == 0) {
                jinfo[n*8 + 4] = 10.f * pos[n*15 + 3];
                jinfo[n*8 + 5] = 10.f * pos[n*15 + 4];
                jinfo[n*8 + 6] = 10.f * pos[n*15 + 5];
                jinfo[n*8 + 7] = 0.f;
            }
        }
    }
}

// ---------------------------------------------------------------------------
// Phase 2: one block per query row. 512 threads, grid 512.
// Pass A: 2 explicit 14-load batches. Pass B: MFMA + rbf wave.
// Wave-private softmax buckets; chunked epilogue loads.
// ---------------------------------------------------------------------------
__global__ __launch_bounds__(512, 4) void attn_kernel(
    const unsigned* __restrict__ qnP, const unsigned* __restrict__ knT4,
    const unsigned* __restrict__ qpP, const unsigned* __restrict__ kpT4,
    const unsigned* __restrict__ BF,
    const unsigned* __restrict__ woPk, const unsigned* __restrict__ wp2,
    const unsigned* __restrict__ remb2,
    const float* __restrict__ jinfo, const float* __restrict__ iinfo,
    const int* __restrict__ resi, const int* __restrict__ chain,
    const int* __restrict__ batch, const void* __restrict__ maskp,
    const float* __restrict__ w_bias, const float* __restrict__ gamma,
    float* __restrict__ out)
{
    const int i    = blockIdx.x;
    const int tid  = threadIdx.x;
    const int lane = tid & 63;
    const int wv   = tid >> 6;

    __shared__ unsigned qpkL[64];
    __shared__ unsigned qspkL[48];
    __shared__ unsigned wbPk[H_HEADS][8];
    __shared__ __align__(16) unsigned rbfP[N_NODES][9];
    __shared__ __align__(16) unsigned attnH[H_HEADS][260];
    __shared__ float    mxW[8][H_HEADS], smW[8][H_HEADS];
    __shared__ float    asL[H_HEADS];
    __shared__ float    qpiL[P3_N];
    __shared__ float    GLfF[H_HEADS][P3_N];
    __shared__ float    GLfR[H_HEADS][16];
    __shared__ unsigned GLf2[H_HEADS][56];
    __shared__ unsigned abktP[H_HEADS][33];
    __shared__ float    resL[HPC];
    __shared__ unsigned resH[FD_N];
    __shared__ float    abktW[8][H_HEADS][66];   // wave-private buckets
    __shared__ unsigned char rdL[N_NODES], pmL[N_NODES];

    // ---- init ----
    if (tid < 64) {
        qpkL[tid] = qnP[(size_t)i*64 + tid];
    } else if (tid < 112) {
        const int f2 = tid - 64, h = f2 / 12;
        const float ps2 = 2.f * log1pf(expf(gamma[h])) * (1.0f/12.0f);
        const unsigned u = qpP[(size_t)i*48 + f2];
        qspkL[f2] = packh2(ps2*h2lof(u), ps2*h2hif(u));
    } else if (tid < 160) {
        const int f2 = tid - 112;
        const unsigned u = qpP[(size_t)i*48 + f2];
        qpiL[2*f2]   = h2lof(u);
        qpiL[2*f2+1] = h2hif(u);
    } else if (tid < 192) {
        const int v = tid - 160, h = v >> 3, e = v & 7;
        wbPk[h][e] = packh2(w_bias[(P3_N + 2*e)*H_HEADS + h],
                            w_bias[(P3_N + 2*e + 1)*H_HEADS + h]);
    }
    for (int t = tid; t < 8*H_HEADS*66; t += 512) ((float*)abktW)[t] = 0.f;

    const int  r_i = resi[i], ch_i = chain[i], ba_i = batch[i];
    const bool m_i = mask_true(maskp, i);
    const float dix = jinfo[(size_t)i*8+4], diy = jinfo[(size_t)i*8+5], diz = jinfo[(size_t)i*8+6];

    const float inv3  = 0.57735026918962576f;
    const float rstep = 0.72727272727272727f;   // 1/1.375

    // ---- per-thread j prework ----
    const int j = tid;
    const float4 vq4 = *(const float4*)(jinfo + (size_t)j*8);
    const float4 dj4 = *(const float4*)(jinfo + (size_t)j*8 + 4);
    const float4 ci4 = *(const float4*)(iinfo + (size_t)i*4);
    const float vqa[4] = {vq4.x, vq4.y, vq4.z, vq4.w};
    const float cia[4] = {ci4.x, ci4.y, ci4.z, ci4.w};
    const float dd0 = dix - dj4.x, dd1 = diy - dj4.y, dd2 = diz - dj4.z;
    const float dist = sqrtf(dd0*dd0 + dd1*dd1 + dd2*dd2 + 1e-6f);
    unsigned rr[8];
#pragma unroll
    for (int p = 0; p < 8; ++p) {
        const float u0 = (dist - (1.375f*(float)(2*p)   + 0.6875f)) * rstep;
        const float u1 = (dist - (1.375f*(float)(2*p+1) + 0.6875f)) * rstep;
        rr[p] = packh2(__expf(-u0*u0), __expf(-u1*u1));
        rbfP[j][p] = rr[p];
    }
    const int  rj = resi[j], cj = chain[j], bj = batch[j];
    const bool pm = m_i && mask_true(maskp, j) && (ba_i == bj);
    const int  rdv = (ch_i != cj) ? 65 : (min(max(r_i - rj, -32), 32) + 32);
    rdL[j] = (unsigned char)rdv;
    pmL[j] = pm ? 1 : 0;
    __syncthreads();

    // ================= Pass A: 2 explicit load batches =================
    float lv[4];
    {
        const uint4* kcol = (const uint4*)knT4 + j;
        const uint4* pcol = (const uint4*)kpT4 + j;
        const uint4* qk4  = (const uint4*)qpkL;
        const uint4* qs4  = (const uint4*)qspkL;
#pragma unroll
        for (int hp = 0; hp < 2; ++hp) {
            const int h0 = hp*2, h1 = hp*2 + 1;
            // ---- load window: 8 kn + 6 kp uint4 ----
            const uint4 ka0 = kcol[(size_t)(h0*4 + 0)*N_NODES];
            const uint4 ka1 = kcol[(size_t)(h0*4 + 1)*N_NODES];
            const uint4 ka2 = kcol[(size_t)(h0*4 + 2)*N_NODES];
            const uint4 ka3 = kcol[(size_t)(h0*4 + 3)*N_NODES];
            const uint4 kb0 = kcol[(size_t)(h1*4 + 0)*N_NODES];
            const uint4 kb1 = kcol[(size_t)(h1*4 + 1)*N_NODES];
            const uint4 kb2 = kcol[(size_t)(h1*4 + 2)*N_NODES];
            const uint4 kb3 = kcol[(size_t)(h1*4 + 3)*N_NODES];
            const uint4 pa0 = pcol[(size_t)(h0*3 + 0)*N_NODES];
            const uint4 pa1 = pcol[(size_t)(h0*3 + 1)*N_NODES];
            const uint4 pa2 = pcol[(size_t)(h0*3 + 2)*N_NODES];
            const uint4 pb0 = pcol[(size_t)(h1*3 + 0)*N_NODES];
            const uint4 pb1 = pcol[(size_t)(h1*3 + 1)*N_NODES];
            const uint4 pb2 = pcol[(size_t)(h1*3 + 2)*N_NODES];
            // ---- compute h0 ----
            float a0 = 0.f;
            {
                const uint4 q0 = qk4[h0*4 + 0], q1 = qk4[h0*4 + 1];
                const uint4 q2 = qk4[h0*4 + 2], q3 = qk4[h0*4 + 3];
                a0 = dot2u(ka0.x, q0.x, a0); a0 = dot2u(ka0.y, q0.y, a0);
                a0 = dot2u(ka0.z, q0.z, a0); a0 = dot2u(ka0.w, q0.w, a0);
                a0 = dot2u(ka1.x, q1.x, a0); a0 = dot2u(ka1.y, q1.y, a0);
                a0 = dot2u(ka1.z, q1.z, a0); a0 = dot2u(ka1.w, q1.w, a0);
                a0 = dot2u(ka2.x, q2.x, a0); a0 = dot2u(ka2.y, q2.y, a0);
                a0 = dot2u(ka2.z, q2.z, a0); a0 = dot2u(ka2.w, q2.w, a0);
                a0 = dot2u(ka3.x, q3.x, a0); a0 = dot2u(ka3.y, q3.y, a0);
                a0 = dot2u(ka3.z, q3.z, a0); a0 = dot2u(ka3.w, q3.w, a0);
                const uint4 s0 = qs4[h0*3 + 0], s1 = qs4[h0*3 + 1], s2 = qs4[h0*3 + 2];
                a0 = dot2u(pa0.x, s0.x, a0); a0 = dot2u(pa0.y, s0.y, a0);
                a0 = dot2u(pa0.z, s0.z, a0); a0 = dot2u(pa0.w, s0.w, a0);
                a0 = dot2u(pa1.x, s1.x, a0); a0 = dot2u(pa1.y, s1.y, a0);
                a0 = dot2u(pa1.z, s1.z, a0); a0 = dot2u(pa1.w, s1.w, a0);
                a0 = dot2u(pa2.x, s2.x, a0); a0 = dot2u(pa2.y, s2.y, a0);
                a0 = dot2u(pa2.z, s2.z, a0); a0 = dot2u(pa2.w, s2.w, a0);
                const uint4 w0 = *(const uint4*)&wbPk[h0][0];
                const uint4 w1 = *(const uint4*)&wbPk[h0][4];
                a0 = dot2u(rr[0], w0.x, a0); a0 = dot2u(rr[1], w0.y, a0);
                a0 = dot2u(rr[2], w0.z, a0); a0 = dot2u(rr[3], w0.w, a0);
                a0 = dot2u(rr[4], w1.x, a0); a0 = dot2u(rr[5], w1.y, a0);
                a0 = dot2u(rr[6], w1.z, a0); a0 = dot2u(rr[7], w1.w, a0);
            }
            lv[h0] = pm ? (a0 + cia[h0] + vqa[h0]) * inv3 : -1e9f;
            // ---- compute h1 ----
            float a1 = 0.f;
            {
                const uint4 q0 = qk4[h1*4 + 0], q1 = qk4[h1*4 + 1];
                const uint4 q2 = qk4[h1*4 + 2], q3 = qk4[h1*4 + 3];
                a1 = dot2u(kb0.x, q0.x, a1); a1 = dot2u(kb0.y, q0.y, a1);
                a1 = dot2u(kb0.z, q0.z, a1); a1 = dot2u(kb0.w, q0.w, a1);
                a1 = dot2u(kb1.x, q1.x, a1); a1 = dot2u(kb1.y, q1.y, a1);
                a1 = dot2u(kb1.z, q1.z, a1); a1 = dot2u(kb1.w, q1.w, a1);
                a1 = dot2u(kb2.x, q2.x, a1); a1 = dot2u(kb2.y, q2.y, a1);
                a1 = dot2u(kb2.z, q2.z, a1); a1 = dot2u(kb2.w, q2.w, a1);
                a1 = dot2u(kb3.x, q3.x, a1); a1 = dot2u(kb3.y, q3.y, a1);
                a1 = dot2u(kb3.z, q3.z, a1); a1 = dot2u(kb3.w, q3.w, a1);
                const uint4 s0 = qs4[h1*3 + 0], s1 = qs4[h1*3 + 1], s2 = qs4[h1*3 + 2];
                a1 = dot2u(pb0.x, s0.x, a1); a1 = dot2u(pb0.y, s0.y, a1);
                a1 = dot2u(pb0.z, s0.z, a1); a1 = dot2u(pb0.w, s0.w, a1);
                a1 = dot2u(pb1.x, s1.x, a1); a1 = dot2u(pb1.y, s1.y, a1);
                a1 = dot2u(pb1.z, s1.z, a1); a1 = dot2u(pb1.w, s1.w, a1);
                a1 = dot2u(pb2.x, s2.x, a1); a1 = dot2u(pb2.y, s2.y, a1);
                a1 = dot2u(pb2.z, s2.z, a1); a1 = dot2u(pb2.w, s2.w, a1);
                const uint4 w0 = *(const uint4*)&wbPk[h1][0];
                const uint4 w1 = *(const uint4*)&wbPk[h1][4];
                a1 = dot2u(rr[0], w0.x, a1); a1 = dot2u(rr[1], w0.y, a1);
                a1 = dot2u(rr[2], w0.z, a1); a1 = dot2u(rr[3], w0.w, a1);
                a1 = dot2u(rr[4], w1.x, a1); a1 = dot2u(rr[5], w1.y, a1);
                a1 = dot2u(rr[6], w1.z, a1); a1 = dot2u(rr[7], w1.w, a1);
            }
            lv[h1] = pm ? (a1 + cia[h1] + vqa[h1]) * inv3 : -1e9f;
        }
    }

    // ================= Softmax: 2 reduce rounds =================
    {
        float mx[4] = {lv[0], lv[1], lv[2], lv[3]};
#pragma unroll
        for (int off = 1; off < 64; off <<= 1) {
#pragma unroll
            for (int h = 0; h < 4; ++h) mx[h] = fmaxf(mx[h], __shfl_xor(mx[h], off));
        }
        if (lane == 0) *(float4*)&mxW[wv][0] = make_float4(mx[0], mx[1], mx[2], mx[3]);
        __syncthreads();
        float mxg[4] = {-1e30f, -1e30f, -1e30f, -1e30f};
#pragma unroll
        for (int w = 0; w < 8; ++w) {
            const float4 m = *(const float4*)&mxW[w][0];
            mxg[0] = fmaxf(mxg[0], m.x); mxg[1] = fmaxf(mxg[1], m.y);
            mxg[2] = fmaxf(mxg[2], m.z); mxg[3] = fmaxf(mxg[3], m.w);
        }
        float e[4], sm[4];
#pragma unroll
        for (int h = 0; h < 4; ++h) {
            e[h] = pm ? __expf(lv[h] - mxg[h]) : 0.f;
            sm[h] = e[h];
        }
#pragma unroll
        for (int off = 1; off < 64; off <<= 1) {
#pragma unroll
            for (int h = 0; h < 4; ++h) sm[h] += __shfl_xor(sm[h], off);
        }
        if (lane == 0) *(float4*)&smW[wv][0] = make_float4(sm[0], sm[1], sm[2], sm[3]);
        __syncthreads();
        float smt[4] = {0.f, 0.f, 0.f, 0.f};
#pragma unroll
        for (int w = 0; w < 8; ++w) {
            const float4 m = *(const float4*)&smW[w][0];
            smt[0] += m.x; smt[1] += m.y; smt[2] += m.z; smt[3] += m.w;
        }
        float p[4];
#pragma unroll
        for (int h = 0; h < 4; ++h) {
            const float rden = 1.f / fmaxf(smt[h], 1e-37f);
            p[h] = e[h] * rden;
            atomicAdd(&abktW[wv][h][rdv], p[h]);
        }
        if (tid == 0) {
#pragma unroll
            for (int h = 0; h < 4; ++h)
                asL[h] = smt[h] / fmaxf(smt[h], 1e-37f);
        }
#pragma unroll
        for (int h = 0; h < 4; ++h) {
            const float po = __shfl_xor(p[h], 1);
            if (!(j & 1)) attnH[h][j >> 1] = packh2(p[h], po);
        }
    }
    __syncthreads();

    // ================= Pass B: MFMA P x [val|kp] =================
    if (wv < 7) {
        const int row = lane & 15;
        const int ntA = wv, ntB = wv + 7, ntC = wv + 14;
        const bool hasC = (ntC < 20);
        f32x4 accA = {0.f,0.f,0.f,0.f};
        f32x4 accB = {0.f,0.f,0.f,0.f};
        f32x4 accC = {0.f,0.f,0.f,0.f};
        const uint4* bfp = (const uint4*)BF;
#pragma unroll 4
        for (int kt = 0; kt < 16; ++kt) {
            uint4 au = make_uint4(0u, 0u, 0u, 0u);
            if (row < 4) au = *(const uint4*)&attnH[row][kt*16 + (lane >> 4)*4];
            const uint4 bA = bfp[(ntA*16 + kt)*64 + lane];
            const uint4 bB = bfp[(ntB*16 + kt)*64 + lane];
            accA = mfma16(au, bA, accA);
            accB = mfma16(au, bB, accB);
            if (hasC) {
                const uint4 bC = bfp[(ntC*16 + kt)*64 + lane];
                accC = mfma16(au, bC, accC);
            }
        }
        if (lane < 16) {
            {
                const int s = ntA*16 + lane, h = s / PAIR_CN;
                resL[s] = (h==0) ? accA[0] : ((h==1) ? accA[1] : ((h==2) ? accA[2] : accA[3]));
            }
            {
                const int s = ntB*16 + lane, h = s / PAIR_CN;
                resL[s] = (h==0) ? accB[0] : ((h==1) ? accB[1] : ((h==2) ? accB[2] : accB[3]));
            }
            if (hasC) {
                const int f = (ntC - 14)*16 + lane;
                GLfF[0][f] = accC[0];
                GLfF[1][f] = accC[1];
                GLfF[2][f] = accC[2];
                GLfF[3][f] = accC[3];
            }
        }
    } else {
        const int idx = tid - 448, b = idx >> 2, q = idx & 3;
        const int w = b >> 1;
        const bool hi = (b & 1);
        float a[4] = {0.f, 0.f, 0.f, 0.f};
#pragma unroll 4
        for (int jpp = q*64; jpp < q*64 + 64; ++jpp) {
            const unsigned r0 = rbfP[2*jpp][w];
            const unsigned r1 = rbfP[2*jpp + 1][w];
            const unsigned ee = hi ? ((r0 >> 16) | (r1 & 0xffff0000u))
                                   : ((r0 & 0xffffu) | (r1 << 16));
            a[0] = dot2u(ee, attnH[0][jpp], a[0]);
            a[1] = dot2u(ee, attnH[1][jpp], a[1]);
            a[2] = dot2u(ee, attnH[2][jpp], a[2]);
            a[3] = dot2u(ee, attnH[3][jpp], a[3]);
        }
#pragma unroll
        for (int h = 0; h < 4; ++h) {
            a[h] += __shfl_xor(a[h], 1);
            a[h] += __shfl_xor(a[h], 2);
            if (q == 0) GLfR[h][b] = a[h];
        }
    }
    __syncthreads();

    // ================= Combine: GLf2 pack, bucket pack ====================
    for (int t = tid; t < 224; t += 512) {   // t = h*56 + f2
        const int h = t / 56, f2 = t % 56;
        if (f2 < 48) {
            GLf2[h][f2] = packh2(qpiL[2*f2]*asL[h]     - GLfF[h][2*f2],
                                 qpiL[2*f2 + 1]*asL[h] - GLfF[h][2*f2 + 1]);
        } else {
            GLf2[h][f2] = packh2(GLfR[h][(f2 - 48)*2], GLfR[h][(f2 - 48)*2 + 1]);
        }
    }
    for (int t = tid; t < 132; t += 512) {   // t = h*33 + r2
        const int h = t / 33, r2 = t % 33;
        float s0 = 0.f, s1 = 0.f;
#pragma unroll
        for (int w = 0; w < 8; ++w) {
            s0 += abktW[w][h][2*r2];
            s1 += abktW[w][h][2*r2 + 1];
        }
        abktP[h][r2] = packh2(s0, s1);
    }
    __syncthreads();

    // ================= Epilogue (chunked packed dot2) ====================
    if (tid < HPC) {
        const int h = tid / PAIR_CN, c = tid - h*PAIR_CN;
        float r = resL[tid];
        {
            unsigned buf[16];
#pragma unroll
            for (int t = 0; t < 16; ++t) buf[t] = remb2[t*56 + c];
#pragma unroll
            for (int t = 0; t < 16; ++t) r = dot2u(buf[t], abktP[h][t], r);
#pragma unroll
            for (int t = 0; t < 16; ++t) buf[t] = remb2[(16 + t)*56 + c];
#pragma unroll
            for (int t = 0; t < 16; ++t) r = dot2u(buf[t], abktP[h][16 + t], r);
            r = dot2u(remb2[32*56 + c], abktP[h][32], r);
        }
        {
            unsigned buf[14];
#pragma unroll
            for (int qq = 0; qq < 4; ++qq) {
#pragma unroll
                for (int t = 0; t < 14; ++t) buf[t] = wp2[(qq*14 + t)*56 + c];
#pragma unroll
                for (int t = 0; t < 14; ++t) r = dot2u(buf[t], GLf2[h][qq*14 + t], r);
            }
        }
        resL[tid] = r;
    }
    __syncthreads();

    if (tid < FD_N) resH[tid] = packh2(resL[2*tid], resL[2*tid + 1]);
    __syncthreads();

    // ================= out = resH . woPk (t-split 2-way, chunked) ==========
    {
        const int col = tid >> 1, ph = tid & 1;
        float o = 0.f;
        unsigned buf[14];
#pragma unroll
        for (int qq = 0; qq < 4; ++qq) {
            const int base = ph*56 + qq*14;
#pragma unroll
            for (int t = 0; t < 14; ++t) buf[t] = woPk[(base + t)*256 + col];
#pragma unroll
            for (int t = 0; t < 14; ++t) o = dot2u(buf[t], resH[base + t], o);
        }
        o += __shfl_xor(o, 1);
        if (ph == 0) out[(size_t)i*DIM + col] = o;
    }
}

// ---------------------------------------------------------------------------
extern "C" void kernel_launch(void* const* d_in, const int* in_sizes, int n_in,
                              void* d_out, int out_size, void* d_ws, size_t ws_size,
                              hipStream_t stream) {
    (void)in_sizes; (void)n_in; (void)out_size; (void)ws_size;
    const float* local = (const float*)d_in[0];
    const float* pos   = (const float*)d_in[1];
    const int*   resi  = (const int*)d_in[2];
    const int*   chain = (const int*)d_in[3];
    const int*   batch = (const int*)d_in[4];
    const void*  maskp = d_in[5];
    const float* qls   = (const float*)d_in[6];
    const float* qlo   = (const float*)d_in[7];
    const float* kls   = (const float*)d_in[8];
    const float* klo   = (const float*)d_in[9];
    const float* w_q   = (const float*)d_in[10];
    const float* b_q   = (const float*)d_in[11];
    const float* w_k   = (const float*)d_in[12];
    const float* b_k   = (const float*)d_in[13];
    const float* w_v   = (const float*)d_in[14];
    const float* b_v   = (const float*)d_in[15];
    const float* w_qp  = (const float*)d_in[16];
    const float* b_qp  = (const float*)d_in[17];
    const float* w_kp  = (const float*)d_in[18];
    const float* b_kp  = (const float*)d_in[19];
    const float* w_vp  = (const float*)d_in[20];
    const float* b_vp  = (const float*)d_in[21];
    const float* remb  = (const float*)d_in[22];
    const float* w_pair= (const float*)d_in[23];
    const float* w_bias= (const float*)d_in[24];
    const float* b_bias= (const float*)d_in[25];
    const float* gamma = (const float*)d_in[26];
    const float* w_out = (const float*)d_in[27];

    char* ws = (char*)d_ws;
    unsigned* qnP   = (unsigned*)(ws);            // 131072 B [512][64]
    unsigned* qpP   = (unsigned*)(ws + 131072);   //  98304 B [512][48]
    unsigned* knT4  = (unsigned*)(ws + 229376);   // 131072 B [16][512][4]
    unsigned* kpT4  = (unsigned*)(ws + 360448);   //  98304 B [12][512][4]
    unsigned* BF    = (unsigned*)(ws + 458752);   // 327680 B [20][16][64][4]
    float*    jinf  = (float*)(ws + 786432);      //  16384 B
    float*    iinf  = (float*)(ws + 802816);      //   8192 B
    unsigned* woPk  = (unsigned*)(ws + 811008);   // 114688 B [112][256]
    unsigned* wp2   = (unsigned*)(ws + 925696);   //  12544 B [56][56]
    unsigned* remb2 = (unsigned*)(ws + 938240);   //   7392 B [33][56]

    proj_kernel<<<N_NODES / 2, 512, 0, stream>>>(
        local, pos, qls, qlo, kls, klo,
        w_q, b_q, w_k, b_k, w_v, b_v,
        w_qp, b_qp, w_kp, b_kp, w_vp, b_vp,
        w_bias, b_bias, gamma,
        remb, w_pair, w_out,
        qnP, knT4, qpP, kpT4, BF,
        woPk, wp2, remb2, jinf, iinf);

    attn_kernel<<<N_NODES, 512, 0, stream>>>(
        qnP, knT4, qpP, kpT4, BF,
        woPk, wp2, remb2, jinf, iinf,
        resi, chain, batch, maskp,
        w_bias, gamma,
        (float*)d_out);
}

// Round 16
// 53.816 us; speedup vs baseline: 2.1079x; 1.0026x over previous
//
#include <hip/hip_runtime.h>
#include <hip/hip_bf16.h>
#include <cstddef>

// Problem constants (N, D, S, H, QP, VP) = (512, 256, 32, 4, 8, 8)
#define N_NODES 512
#define DIM     256
#define H_HEADS 4
#define PAIR_CN 56    // S + 3*VP
#define P3_N    96    // H*QP*3
#define FD_N    112   // P3 + 16
#define HPC     224   // H * PAIR_C

typedef _Float16 h2v  __attribute__((ext_vector_type(2)));
typedef _Float16 f16x8 __attribute__((ext_vector_type(8)));
typedef float    f32x4 __attribute__((ext_vector_type(4)));

__device__ __forceinline__ bool mask_true(const void* m, int idx) {
    if (((const unsigned char*)m)[idx] != 0) return true;
    return ((const int*)m)[idx] != 0;
}
__device__ __forceinline__ unsigned packh2(float a, float b) {
    _Float16 ha = (_Float16)a, hb = (_Float16)b;
    unsigned short ua, ub;
    __builtin_memcpy(&ua, &ha, 2); __builtin_memcpy(&ub, &hb, 2);
    return (unsigned)ua | ((unsigned)ub << 16);
}
__device__ __forceinline__ float h2lof(unsigned u) {
    unsigned short t = (unsigned short)(u & 0xffff);
    _Float16 h; __builtin_memcpy(&h, &t, 2); return (float)h;
}
__device__ __forceinline__ float h2hif(unsigned u) {
    unsigned short t = (unsigned short)(u >> 16);
    _Float16 h; __builtin_memcpy(&h, &t, 2); return (float)h;
}
__device__ __forceinline__ float dot2u(unsigned a, unsigned b, float c) {
#if __has_builtin(__builtin_amdgcn_fdot2)
    h2v ha, hb;
    __builtin_memcpy(&ha, &a, 4);
    __builtin_memcpy(&hb, &b, 4);
    return __builtin_amdgcn_fdot2(ha, hb, c, false);
#else
    return c + h2lof(a)*h2lof(b) + h2hif(a)*h2hif(b);
#endif
}
__device__ __forceinline__ f32x4 mfma16(uint4 a, uint4 b, f32x4 c) {
    f16x8 af, bf;
    __builtin_memcpy(&af, &a, 16);
    __builtin_memcpy(&bf, &b, 16);
    return __builtin_amdgcn_mfma_f32_16x16x32_f16(af, bf, c, 0, 0, 0);
}

// ---------------------------------------------------------------------------
// Phase 1: projections + LayerNorm + separable terms + weight packing.
// GEMM K-loop restructured into 16 batches of 8 explicit float4 loads.
// ---------------------------------------------------------------------------
__global__ __launch_bounds__(512) void proj_kernel(
    const float* __restrict__ local, const float* __restrict__ pos,
    const float* __restrict__ qls, const float* __restrict__ qlo,
    const float* __restrict__ kls, const float* __restrict__ klo,
    const float* __restrict__ w_q, const float* __restrict__ b_q,
    const float* __restrict__ w_k, const float* __restrict__ b_k,
    const float* __restrict__ w_v, const float* __restrict__ b_v,
    const float* __restrict__ w_qp, const float* __restrict__ b_qp,
    const float* __restrict__ w_kp, const float* __restrict__ b_kp,
    const float* __restrict__ w_vp, const float* __restrict__ b_vp,
    const float* __restrict__ w_bias, const float* __restrict__ b_bias,
    const float* __restrict__ gamma,
    const float* __restrict__ remb, const float* __restrict__ w_pair,
    const float* __restrict__ w_out,
    unsigned* __restrict__ qnP, unsigned* __restrict__ knT4,
    unsigned* __restrict__ qpP, unsigned* __restrict__ kpT4,
    unsigned* __restrict__ BF,
    unsigned* __restrict__ woPk, unsigned* __restrict__ wp2,
    unsigned* __restrict__ remb2,
    float* __restrict__ jinfo, float* __restrict__ iinfo)
{
    const int i0 = blockIdx.x * 2;
    const int tid = threadIdx.x;

    __shared__ float xL[2][DIM];
    __shared__ float qraw[2][128];
    __shared__ float kraw[2][128];
    __shared__ float stat[2][16];
    __shared__ float qpL[2][P3_N];
    __shared__ float kpbL[2][P3_N];
    __shared__ float wbS[384];

    if (blockIdx.x < 16) {
        for (int t = blockIdx.x*512 + tid; t < 33656; t += 8192) {
            if (t < 28672) {
                const int t2 = t >> 8, colx = t & 255;
                woPk[t] = packh2(w_out[(size_t)(2*t2)*DIM + colx],
                                 w_out[(size_t)(2*t2 + 1)*DIM + colx]);
            } else if (t < 31808) {
                const int v = t - 28672, f2 = v / 56, cx = v % 56;
                wp2[v] = packh2(w_pair[(2*f2)*PAIR_CN + cx],
                                w_pair[(2*f2 + 1)*PAIR_CN + cx]);
            } else {
                const int v = t - 31808, r2 = v / 56, cx = v % 56;
                remb2[v] = packh2(remb[(2*r2)*PAIR_CN + cx],
                                  remb[(2*r2 + 1)*PAIR_CN + cx]);
            }
        }
    }

    {
        const int r = tid >> 8, d = tid & 255;
        xL[r][d] = local[(size_t)(i0 + r) * DIM + d];
    }
    if (tid < 384) wbS[tid] = w_bias[tid];
    __syncthreads();

    const int cstBF = ((i0 >> 5) << 8) + (((i0 >> 3) & 3) << 6) + ((i0 >> 1) & 3);

    if (tid < 336) {
        const int colg = tid >> 1, dh = tid & 1;
        const int col = colg * 4;
        const float* w; int width, c, seg;
        if      (col < 128) { w = w_q;  c = col;       width = 128; seg = 0; }
        else if (col < 256) { w = w_k;  c = col - 128; width = 128; seg = 1; }
        else if (col < 384) { w = w_v;  c = col - 256; width = 128; seg = 2; }
        else if (col < 480) { w = w_qp; c = col - 384; width = 96;  seg = 3; }
        else if (col < 576) { w = w_kp; c = col - 480; width = 96;  seg = 4; }
        else                { w = w_vp; c = col - 576; width = 96;  seg = 5; }

        float acc[2][4] = {{0.f,0.f,0.f,0.f},{0.f,0.f,0.f,0.f}};
        const float* wc = w + c;
        const int dbase = dh * 128;
#pragma unroll 1
        for (int bb = 0; bb < 16; ++bb) {
            const int d0 = dbase + bb*8;
            // ---- explicit 8-load window ----
            const float4 wv0 = *(const float4*)(wc + (size_t)(d0 + 0)*width);
            const float4 wv1 = *(const float4*)(wc + (size_t)(d0 + 1)*width);
            const float4 wv2 = *(const float4*)(wc + (size_t)(d0 + 2)*width);
            const float4 wv3 = *(const float4*)(wc + (size_t)(d0 + 3)*width);
            const float4 wv4 = *(const float4*)(wc + (size_t)(d0 + 4)*width);
            const float4 wv5 = *(const float4*)(wc + (size_t)(d0 + 5)*width);
            const float4 wv6 = *(const float4*)(wc + (size_t)(d0 + 6)*width);
            const float4 wv7 = *(const float4*)(wc + (size_t)(d0 + 7)*width);
#pragma unroll
            for (int r = 0; r < 2; ++r) {
                const float x0 = xL[r][d0 + 0], x1 = xL[r][d0 + 1];
                const float x2 = xL[r][d0 + 2], x3 = xL[r][d0 + 3];
                const float x4 = xL[r][d0 + 4], x5 = xL[r][d0 + 5];
                const float x6 = xL[r][d0 + 6], x7 = xL[r][d0 + 7];
                acc[r][0] += x0*wv0.x + x1*wv1.x + x2*wv2.x + x3*wv3.x
                           + x4*wv4.x + x5*wv5.x + x6*wv6.x + x7*wv7.x;
                acc[r][1] += x0*wv0.y + x1*wv1.y + x2*wv2.y + x3*wv3.y
                           + x4*wv4.y + x5*wv5.y + x6*wv6.y + x7*wv7.y;
                acc[r][2] += x0*wv0.z + x1*wv1.z + x2*wv2.z + x3*wv3.z
                           + x4*wv4.z + x5*wv5.z + x6*wv6.z + x7*wv7.z;
                acc[r][3] += x0*wv0.w + x1*wv1.w + x2*wv2.w + x3*wv3.w
                           + x4*wv4.w + x5*wv5.w + x6*wv6.w + x7*wv7.w;
            }
        }
#pragma unroll
        for (int r = 0; r < 2; ++r)
#pragma unroll
            for (int e = 0; e < 4; ++e)
                acc[r][e] += __shfl_xor(acc[r][e], 1);

        if (dh == 0) {
            const float cax0 = pos[i0*15+3],     cay0 = pos[i0*15+4],     caz0 = pos[i0*15+5];
            const float cax1 = pos[(i0+1)*15+3], cay1 = pos[(i0+1)*15+4], caz1 = pos[(i0+1)*15+5];
            float fr0[4], fr1[4];
            const bool isKp = (seg == 4), isQp = (seg == 3);
#pragma unroll
            for (int e = 0; e < 4; ++e) {
                const int cc = c + e;
                const float v0 = acc[0][e], v1 = acc[1][e];
                if (seg == 0) {
                    qraw[0][cc] = v0 + b_q[cc];
                    qraw[1][cc] = v1 + b_q[cc];
                } else if (seg == 1) {
                    kraw[0][cc] = v0 + b_k[cc];
                    kraw[1][cc] = v1 + b_k[cc];
                } else if (seg == 2) {
                    const int h = cc >> 5, sc = cc & 31;
                    const int colF = h*PAIR_CN + sc;
                    BF[(colF >> 4)*4096 + (colF & 15)*4 + cstBF] =
                        packh2(v0 + b_v[cc], v1 + b_v[cc]);
                } else if (seg == 3) {
                    const int x = cc % 3;
                    const float cav0 = (x==0)?cax0:((x==1)?cay0:caz0);
                    const float cav1 = (x==0)?cax1:((x==1)?cay1:caz1);
                    const float r0 = v0 + b_qp[cc] + cav0;
                    const float r1 = v1 + b_qp[cc] + cav1;
                    fr0[e] = r0; fr1[e] = r1;
                    qpL[0][cc] = r0; qpL[1][cc] = r1;
                } else if (seg == 4) {
                    const int x = cc % 3;
                    const float cav0 = (x==0)?cax0:((x==1)?cay0:caz0);
                    const float cav1 = (x==0)?cax1:((x==1)?cay1:caz1);
                    const float r0 = v0 + b_kp[cc] + cav0;
                    const float r1 = v1 + b_kp[cc] + cav1;
                    fr0[e] = r0; fr1[e] = r1;
                    const int colF = 224 + cc;
                    BF[(colF >> 4)*4096 + (colF & 15)*4 + cstBF] = packh2(r0, r1);
                    kpbL[0][cc] = (float)(_Float16)r0;
                    kpbL[1][cc] = (float)(_Float16)r1;
                } else {
                    const int h = cc / 24, rr = cc % 24, x = cc % 3;
                    const float cav0 = (x==0)?cax0:((x==1)?cay0:caz0);
                    const float cav1 = (x==0)?cax1:((x==1)?cay1:caz1);
                    const int colF = h*PAIR_CN + 32 + rr;
                    BF[(colF >> 4)*4096 + (colF & 15)*4 + cstBF] =
                        packh2(v0 + b_vp[cc] + cav0, v1 + b_vp[cc] + cav1);
                }
            }
            if (isQp) {
                const int f2 = c >> 1;
                qpP[(size_t)i0*48 + f2]         = packh2(fr0[0], fr0[1]);
                qpP[(size_t)i0*48 + f2 + 1]     = packh2(fr0[2], fr0[3]);
                qpP[(size_t)(i0+1)*48 + f2]     = packh2(fr1[0], fr1[1]);
                qpP[(size_t)(i0+1)*48 + f2 + 1] = packh2(fr1[2], fr1[3]);
            }
            if (isKp) {
                const int f2 = c >> 1;
                const int fq = f2 >> 2;
                kpT4[((size_t)fq*N_NODES + i0    )*4 + (f2 & 3)]       = packh2(fr0[0], fr0[1]);
                kpT4[((size_t)fq*N_NODES + i0    )*4 + ((f2 + 1) & 3)] = packh2(fr0[2], fr0[3]);
                kpT4[((size_t)fq*N_NODES + i0 + 1)*4 + (f2 & 3)]       = packh2(fr1[0], fr1[1]);
                kpT4[((size_t)fq*N_NODES + i0 + 1)*4 + ((f2 + 1) & 3)] = packh2(fr1[2], fr1[3]);
            }
        }
    }
    __syncthreads();

    if (tid < 16) {
        const int r = tid >> 3, t = tid & 7;
        const float* src = (t < 4) ? qraw[r] : kraw[r];
        const int h = t & 3, base = (t < 4) ? 0 : 8;
        float mu = 0.f;
        for (int c = 0; c < 32; ++c) mu += src[h*32 + c];
        mu *= (1.f/32.f);
        float var = 0.f;
        for (int c = 0; c < 32; ++c) { float d = src[h*32 + c] - mu; var += d*d; }
        var *= (1.f/32.f);
        stat[r][base + h*2 + 0] = mu;
        stat[r][base + h*2 + 1] = var;
    }
    __syncthreads();

    {
        const int r = tid >> 8, u = tid & 255;
        const int i = i0 + r;
        if (u < 128) {
            const int h = u >> 5, sidx = u & 31;
            const float mu = stat[r][h*2], var = stat[r][h*2+1];
            float v = (qraw[r][u] - mu) * rsqrtf(var + 1e-5f) * qls[sidx] + qlo[sidx];
            v *= 0.17677669529663687f;  // * sqrt(1/S)
            const float vo = __shfl_xor(v, 1);
            if (!(u & 1)) qnP[(size_t)i*64 + (u >> 1)] = packh2(v, vo);
        } else {
            const int u2 = u - 128, h = u2 >> 5, sidx = u2 & 31;
            const float mu = stat[r][8 + h*2], var = stat[r][9 + h*2];
            float v = (kraw[r][u2] - mu) * rsqrtf(var + 1e-5f) * kls[sidx] + klo[sidx];
            const float vo = __shfl_xor(v, 1);
            if (!(u2 & 1))
                knT4[(((size_t)(u2 >> 3))*N_NODES + i)*4 + ((u2 >> 1) & 3)] = packh2(v, vo);
        }
    }

    if (tid < 64) {
        const int r = tid >> 5, h = (tid >> 3) & 3, ks = tid & 7;
        float uacc = 0.f, tacc = 0.f;
#pragma unroll
        for (int f = ks; f < P3_N; f += 8) {
            float wb = wbS[f*4 + h];
            uacc += qpL[r][f] * wb;
            tacc += kpbL[r][f] * wb;
        }
        float nq = 0.f, nk = 0.f;
#pragma unroll
        for (int f = h*24 + ks*3; f < h*24 + ks*3 + 3; ++f) {
            nq += qpL[r][f]*qpL[r][f];
            nk += kpbL[r][f]*kpbL[r][f];
        }
        uacc += __shfl_xor(uacc,1); uacc += __shfl_xor(uacc,2); uacc += __shfl_xor(uacc,4);
        tacc += __shfl_xor(tacc,1); tacc += __shfl_xor(tacc,2); tacc += __shfl_xor(tacc,4);
        nq   += __shfl_xor(nq,1);   nq   += __shfl_xor(nq,2);   nq   += __shfl_xor(nq,4);
        nk   += __shfl_xor(nk,1);   nk   += __shfl_xor(nk,2);   nk   += __shfl_xor(nk,4);
        if (ks == 0) {
            const int n = i0 + r;
            const float ps = log1pf(expf(gamma[h])) * (1.0f/12.0f);
            iinfo[n*4 + h] = -ps*nq + uacc + b_bias[h];
            jinfo[n*8 + h] = -ps*nk - tacc;
            if (h == 0) {
                jinfo[n*8 + 4] = 10.f * pos[n*15 + 3];
                jinfo[n*8 + 5] = 10.f * pos[n*15 + 4];
                jinfo[n*8 + 6] = 10.f * pos[n*15 + 5];
                jinfo[n*8 + 7] = 0.f;
            }
        }
    }
}

// ---------------------------------------------------------------------------
// Phase 2: one block per query row. 512 threads, grid 512.
// (unchanged from round 15)
// ---------------------------------------------------------------------------
__global__ __launch_bounds__(512, 4) void attn_kernel(
    const unsigned* __restrict__ qnP, const unsigned* __restrict__ knT4,
    const unsigned* __restrict__ qpP, const unsigned* __restrict__ kpT4,
    const unsigned* __restrict__ BF,
    const unsigned* __restrict__ woPk, const unsigned* __restrict__ wp2,
    const unsigned* __restrict__ remb2,
    const float* __restrict__ jinfo, const float* __restrict__ iinfo,
    const int* __restrict__ resi, const int* __restrict__ chain,
    const int* __restrict__ batch, const void* __restrict__ maskp,
    const float* __restrict__ w_bias, const float* __restrict__ gamma,
    float* __restrict__ out)
{
    const int i    = blockIdx.x;
    const int tid  = threadIdx.x;
    const int lane = tid & 63;
    const int wv   = tid >> 6;

    __shared__ unsigned qpkL[64];
    __shared__ unsigned qspkL[48];
    __shared__ unsigned wbPk[H_HEADS][8];
    __shared__ __align__(16) unsigned rbfP[N_NODES][9];
    __shared__ __align__(16) unsigned attnH[H_HEADS][260];
    __shared__ float    mxW[8][H_HEADS], smW[8][H_HEADS];
    __shared__ float    asL[H_HEADS];
    __shared__ float    qpiL[P3_N];
    __shared__ float    GLfF[H_HEADS][P3_N];
    __shared__ float    GLfR[H_HEADS][16];
    __shared__ unsigned GLf2[H_HEADS][56];
    __shared__ unsigned abktP[H_HEADS][33];
    __shared__ float    resL[HPC];
    __shared__ unsigned resH[FD_N];
    __shared__ float    abktW[8][H_HEADS][66];
    __shared__ unsigned char rdL[N_NODES], pmL[N_NODES];

    if (tid < 64) {
        qpkL[tid] = qnP[(size_t)i*64 + tid];
    } else if (tid < 112) {
        const int f2 = tid - 64, h = f2 / 12;
        const float ps2 = 2.f * log1pf(expf(gamma[h])) * (1.0f/12.0f);
        const unsigned u = qpP[(size_t)i*48 + f2];
        qspkL[f2] = packh2(ps2*h2lof(u), ps2*h2hif(u));
    } else if (tid < 160) {
        const int f2 = tid - 112;
        const unsigned u = qpP[(size_t)i*48 + f2];
        qpiL[2*f2]   = h2lof(u);
        qpiL[2*f2+1] = h2hif(u);
    } else if (tid < 192) {
        const int v = tid - 160, h = v >> 3, e = v & 7;
        wbPk[h][e] = packh2(w_bias[(P3_N + 2*e)*H_HEADS + h],
                            w_bias[(P3_N + 2*e + 1)*H_HEADS + h]);
    }
    for (int t = tid; t < 8*H_HEADS*66; t += 512) ((float*)abktW)[t] = 0.f;

    const int  r_i = resi[i], ch_i = chain[i], ba_i = batch[i];
    const bool m_i = mask_true(maskp, i);
    const float dix = jinfo[(size_t)i*8+4], diy = jinfo[(size_t)i*8+5], diz = jinfo[(size_t)i*8+6];

    const float inv3  = 0.57735026918962576f;
    const float rstep = 0.72727272727272727f;   // 1/1.375

    const int j = tid;
    const float4 vq4 = *(const float4*)(jinfo + (size_t)j*8);
    const float4 dj4 = *(const float4*)(jinfo + (size_t)j*8 + 4);
    const float4 ci4 = *(const float4*)(iinfo + (size_t)i*4);
    const float vqa[4] = {vq4.x, vq4.y, vq4.z, vq4.w};
    const float cia[4] = {ci4.x, ci4.y, ci4.z, ci4.w};
    const float dd0 = dix - dj4.x, dd1 = diy - dj4.y, dd2 = diz - dj4.z;
    const float dist = sqrtf(dd0*dd0 + dd1*dd1 + dd2*dd2 + 1e-6f);
    unsigned rr[8];
#pragma unroll
    for (int p = 0; p < 8; ++p) {
        const float u0 = (dist - (1.375f*(float)(2*p)   + 0.6875f)) * rstep;
        const float u1 = (dist - (1.375f*(float)(2*p+1) + 0.6875f)) * rstep;
        rr[p] = packh2(__expf(-u0*u0), __expf(-u1*u1));
        rbfP[j][p] = rr[p];
    }
    const int  rj = resi[j], cj = chain[j], bj = batch[j];
    const bool pm = m_i && mask_true(maskp, j) && (ba_i == bj);
    const int  rdv = (ch_i != cj) ? 65 : (min(max(r_i - rj, -32), 32) + 32);
    rdL[j] = (unsigned char)rdv;
    pmL[j] = pm ? 1 : 0;
    __syncthreads();

    // ================= Pass A: 2 explicit load batches =================
    float lv[4];
    {
        const uint4* kcol = (const uint4*)knT4 + j;
        const uint4* pcol = (const uint4*)kpT4 + j;
        const uint4* qk4  = (const uint4*)qpkL;
        const uint4* qs4  = (const uint4*)qspkL;
#pragma unroll
        for (int hp = 0; hp < 2; ++hp) {
            const int h0 = hp*2, h1 = hp*2 + 1;
            const uint4 ka0 = kcol[(size_t)(h0*4 + 0)*N_NODES];
            const uint4 ka1 = kcol[(size_t)(h0*4 + 1)*N_NODES];
            const uint4 ka2 = kcol[(size_t)(h0*4 + 2)*N_NODES];
            const uint4 ka3 = kcol[(size_t)(h0*4 + 3)*N_NODES];
            const uint4 kb0 = kcol[(size_t)(h1*4 + 0)*N_NODES];
            const uint4 kb1 = kcol[(size_t)(h1*4 + 1)*N_NODES];
            const uint4 kb2 = kcol[(size_t)(h1*4 + 2)*N_NODES];
            const uint4 kb3 = kcol[(size_t)(h1*4 + 3)*N_NODES];
            const uint4 pa0 = pcol[(size_t)(h0*3 + 0)*N_NODES];
            const uint4 pa1 = pcol[(size_t)(h0*3 + 1)*N_NODES];
            const uint4 pa2 = pcol[(size_t)(h0*3 + 2)*N_NODES];
            const uint4 pb0 = pcol[(size_t)(h1*3 + 0)*N_NODES];
            const uint4 pb1 = pcol[(size_t)(h1*3 + 1)*N_NODES];
            const uint4 pb2 = pcol[(size_t)(h1*3 + 2)*N_NODES];
            float a0 = 0.f;
            {
                const uint4 q0 = qk4[h0*4 + 0], q1 = qk4[h0*4 + 1];
                const uint4 q2 = qk4[h0*4 + 2], q3 = qk4[h0*4 + 3];
                a0 = dot2u(ka0.x, q0.x, a0); a0 = dot2u(ka0.y, q0.y, a0);
                a0 = dot2u(ka0.z, q0.z, a0); a0 = dot2u(ka0.w, q0.w, a0);
                a0 = dot2u(ka1.x, q1.x, a0); a0 = dot2u(ka1.y, q1.y, a0);
                a0 = dot2u(ka1.z, q1.z, a0); a0 = dot2u(ka1.w, q1.w, a0);
                a0 = dot2u(ka2.x, q2.x, a0); a0 = dot2u(ka2.y, q2.y, a0);
                a0 = dot2u(ka2.z, q2.z, a0); a0 = dot2u(ka2.w, q2.w, a0);
                a0 = dot2u(ka3.x, q3.x, a0); a0 = dot2u(ka3.y, q3.y, a0);
                a0 = dot2u(ka3.z, q3.z, a0); a0 = dot2u(ka3.w, q3.w, a0);
                const uint4 s0 = qs4[h0*3 + 0], s1 = qs4[h0*3 + 1], s2 = qs4[h0*3 + 2];
                a0 = dot2u(pa0.x, s0.x, a0); a0 = dot2u(pa0.y, s0.y, a0);
                a0 = dot2u(pa0.z, s0.z, a0); a0 = dot2u(pa0.w, s0.w, a0);
                a0 = dot2u(pa1.x, s1.x, a0); a0 = dot2u(pa1.y, s1.y, a0);
                a0 = dot2u(pa1.z, s1.z, a0); a0 = dot2u(pa1.w, s1.w, a0);
                a0 = dot2u(pa2.x, s2.x, a0); a0 = dot2u(pa2.y, s2.y, a0);
                a0 = dot2u(pa2.z, s2.z, a0); a0 = dot2u(pa2.w, s2.w, a0);
                const uint4 w0 = *(const uint4*)&wbPk[h0][0];
                const uint4 w1 = *(const uint4*)&wbPk[h0][4];
                a0 = dot2u(rr[0], w0.x, a0); a0 = dot2u(rr[1], w0.y, a0);
                a0 = dot2u(rr[2], w0.z, a0); a0 = dot2u(rr[3], w0.w, a0);
                a0 = dot2u(rr[4], w1.x, a0); a0 = dot2u(rr[5], w1.y, a0);
                a0 = dot2u(rr[6], w1.z, a0); a0 = dot2u(rr[7], w1.w, a0);
            }
            lv[h0] = pm ? (a0 + cia[h0] + vqa[h0]) * inv3 : -1e9f;
            float a1 = 0.f;
            {
                const uint4 q0 = qk4[h1*4 + 0], q1 = qk4[h1*4 + 1];
                const uint4 q2 = qk4[h1*4 + 2], q3 = qk4[h1*4 + 3];
                a1 = dot2u(kb0.x, q0.x, a1); a1 = dot2u(kb0.y, q0.y, a1);
                a1 = dot2u(kb0.z, q0.z, a1); a1 = dot2u(kb0.w, q0.w, a1);
                a1 = dot2u(kb1.x, q1.x, a1); a1 = dot2u(kb1.y, q1.y, a1);
                a1 = dot2u(kb1.z, q1.z, a1); a1 = dot2u(kb1.w, q1.w, a1);
                a1 = dot2u(kb2.x, q2.x, a1); a1 = dot2u(kb2.y, q2.y, a1);
                a1 = dot2u(kb2.z, q2.z, a1); a1 = dot2u(kb2.w, q2.w, a1);
                a1 = dot2u(kb3.x, q3.x, a1); a1 = dot2u(kb3.y, q3.y, a1);
                a1 = dot2u(kb3.z, q3.z, a1); a1 = dot2u(kb3.w, q3.w, a1);
                const uint4 s0 = qs4[h1*3 + 0], s1 = qs4[h1*3 + 1], s2 = qs4[h1*3 + 2];
                a1 = dot2u(pb0.x, s0.x, a1); a1 = dot2u(pb0.y, s0.y, a1);
                a1 = dot2u(pb0.z, s0.z, a1); a1 = dot2u(pb0.w, s0.w, a1);
                a1 = dot2u(pb1.x, s1.x, a1); a1 = dot2u(pb1.y, s1.y, a1);
                a1 = dot2u(pb1.z, s1.z, a1); a1 = dot2u(pb1.w, s1.w, a1);
                a1 = dot2u(pb2.x, s2.x, a1); a1 = dot2u(pb2.y, s2.y, a1);
                a1 = dot2u(pb2.z, s2.z, a1); a1 = dot2u(pb2.w, s2.w, a1);
                const uint4 w0 = *(const uint4*)&wbPk[h1][0];
                const uint4 w1 = *(const uint4*)&wbPk[h1][4];
                a1 = dot2u(rr[0], w0.x, a1); a1 = dot2u(rr[1], w0.y, a1);
                a1 = dot2u(rr[2], w0.z, a1); a1 = dot2u(rr[3], w0.w, a1);
                a1 = dot2u(rr[4], w1.x, a1); a1 = dot2u(rr[5], w1.y, a1);
                a1 = dot2u(rr[6], w1.z, a1); a1 = dot2u(rr[7], w1.w, a1);
            }
            lv[h1] = pm ? (a1 + cia[h1] + vqa[h1]) * inv3 : -1e9f;
        }
    }

    // ================= Softmax: 2 reduce rounds =================
    {
        float mx[4] = {lv[0], lv[1], lv[2], lv[3]};
#pragma unroll
        for (int off = 1; off < 64; off <<= 1) {
#pragma unroll
            for (int h = 0; h < 4; ++h) mx[h] = fmaxf(mx[h], __shfl_xor(mx[h], off));
        }
        if (lane == 0) *(float4*)&mxW[wv][0] = make_float4(mx[0], mx[1], mx[2], mx[3]);
        __syncthreads();
        float mxg[4] = {-1e30f, -1e30f, -1e30f, -1e30f};
#pragma unroll
        for (int w = 0; w < 8; ++w) {
            const float4 m = *(const float4*)&mxW[w][0];
            mxg[0] = fmaxf(mxg[0], m.x); mxg[1] = fmaxf(mxg[1], m.y);
            mxg[2] = fmaxf(mxg[2], m.z); mxg[3] = fmaxf(mxg[3], m.w);
        }
        float e[4], sm[4];
#pragma unroll
        for (int h = 0; h < 4; ++h) {
            e[h] = pm ? __expf(lv[h] - mxg[h]) : 0.f;
            sm[h] = e[h];
        }
#pragma unroll
        for (int off = 1; off < 64; off <<= 1) {
#pragma unroll
            for (int h = 0; h < 4; ++h) sm[h] += __shfl_xor(sm[h], off);
        }
        if (lane == 0) *(float4*)&smW[wv][0] = make_float4(sm[0], sm[1], sm[2], sm[3]);
        __syncthreads();
        float smt[4] = {0.f, 0.f, 0.f, 0.f};
#pragma unroll
        for (int w = 0; w < 8; ++w) {
            const float4 m = *(const float4*)&smW[w][0];
            smt[0] += m.x; smt[1] += m.y; smt[2] += m.z; smt[3] += m.w;
        }
        float p[4];
#pragma unroll
        for (int h = 0; h < 4; ++h) {
            const float rden = 1.f / fmaxf(smt[h], 1e-37f);
            p[h] = e[h] * rden;
            atomicAdd(&abktW[wv][h][rdv], p[h]);
        }
        if (tid == 0) {
#pragma unroll
            for (int h = 0; h < 4; ++h)
                asL[h] = smt[h] / fmaxf(smt[h], 1e-37f);
        }
#pragma unroll
        for (int h = 0; h < 4; ++h) {
            const float po = __shfl_xor(p[h], 1);
            if (!(j & 1)) attnH[h][j >> 1] = packh2(p[h], po);
        }
    }
    __syncthreads();

    // ================= Pass B: MFMA P x [val|kp] =================
    if (wv < 7) {
        const int row = lane & 15;
        const int ntA = wv, ntB = wv + 7, ntC = wv + 14;
        const bool hasC = (ntC < 20);
        f32x4 accA = {0.f,0.f,0.f,0.f};
        f32x4 accB = {0.f,0.f,0.f,0.f};
        f32x4 accC = {0.f,0.f,0.f,0.f};
        const uint4* bfp = (const uint4*)BF;
#pragma unroll 4
        for (int kt = 0; kt < 16; ++kt) {
            uint4 au = make_uint4(0u, 0u, 0u, 0u);
            if (row < 4) au = *(const uint4*)&attnH[row][kt*16 + (lane >> 4)*4];
            const uint4 bA = bfp[(ntA*16 + kt)*64 + lane];
            const uint4 bB = bfp[(ntB*16 + kt)*64 + lane];
            accA = mfma16(au, bA, accA);
            accB = mfma16(au, bB, accB);
            if (hasC) {
                const uint4 bC = bfp[(ntC*16 + kt)*64 + lane];
                accC = mfma16(au, bC, accC);
            }
        }
        if (lane < 16) {
            {
                const int s = ntA*16 + lane, h = s / PAIR_CN;
                resL[s] = (h==0) ? accA[0] : ((h==1) ? accA[1] : ((h==2) ? accA[2] : accA[3]));
            }
            {
                const int s = ntB*16 + lane, h = s / PAIR_CN;
                resL[s] = (h==0) ? accB[0] : ((h==1) ? accB[1] : ((h==2) ? accB[2] : accB[3]));
            }
            if (hasC) {
                const int f = (ntC - 14)*16 + lane;
                GLfF[0][f] = accC[0];
                GLfF[1][f] = accC[1];
                GLfF[2][f] = accC[2];
                GLfF[3][f] = accC[3];
            }
        }
    } else {
        const int idx = tid - 448, b = idx >> 2, q = idx & 3;
        const int w = b >> 1;
        const bool hi = (b & 1);
        float a[4] = {0.f, 0.f, 0.f, 0.f};
#pragma unroll 4
        for (int jpp = q*64; jpp < q*64 + 64; ++jpp) {
            const unsigned r0 = rbfP[2*jpp][w];
            const unsigned r1 = rbfP[2*jpp + 1][w];
            const unsigned ee = hi ? ((r0 >> 16) | (r1 & 0xffff0000u))
                                   : ((r0 & 0xffffu) | (r1 << 16));
            a[0] = dot2u(ee, attnH[0][jpp], a[0]);
            a[1] = dot2u(ee, attnH[1][jpp], a[1]);
            a[2] = dot2u(ee, attnH[2][jpp], a[2]);
            a[3] = dot2u(ee, attnH[3][jpp], a[3]);
        }
#pragma unroll
        for (int h = 0; h < 4; ++h) {
            a[h] += __shfl_xor(a[h], 1);
            a[h] += __shfl_xor(a[h], 2);
            if (q == 0) GLfR[h][b] = a[h];
        }
    }
    __syncthreads();

    // ================= Combine: GLf2 pack, bucket pack ====================
    for (int t = tid; t < 224; t += 512) {
        const int h = t / 56, f2 = t % 56;
        if (f2 < 48) {
            GLf2[h][f2] = packh2(qpiL[2*f2]*asL[h]     - GLfF[h][2*f2],
                                 qpiL[2*f2 + 1]*asL[h] - GLfF[h][2*f2 + 1]);
        } else {
            GLf2[h][f2] = packh2(GLfR[h][(f2 - 48)*2], GLfR[h][(f2 - 48)*2 + 1]);
        }
    }
    for (int t = tid; t < 132; t += 512) {
        const int h = t / 33, r2 = t % 33;
        float s0 = 0.f, s1 = 0.f;
#pragma unroll
        for (int w = 0; w < 8; ++w) {
            s0 += abktW[w][h][2*r2];
            s1 += abktW[w][h][2*r2 + 1];
        }
        abktP[h][r2] = packh2(s0, s1);
    }
    __syncthreads();

    // ================= Epilogue (chunked packed dot2) ====================
    if (tid < HPC) {
        const int h = tid / PAIR_CN, c = tid - h*PAIR_CN;
        float r = resL[tid];
        {
            unsigned buf[16];
#pragma unroll
            for (int t = 0; t < 16; ++t) buf[t] = remb2[t*56 + c];
#pragma unroll
            for (int t = 0; t < 16; ++t) r = dot2u(buf[t], abktP[h][t], r);
#pragma unroll
            for (int t = 0; t < 16; ++t) buf[t] = remb2[(16 + t)*56 + c];
#pragma unroll
            for (int t = 0; t < 16; ++t) r = dot2u(buf[t], abktP[h][16 + t], r);
            r = dot2u(remb2[32*56 + c], abktP[h][32], r);
        }
        {
            unsigned buf[14];
#pragma unroll
            for (int qq = 0; qq < 4; ++qq) {
#pragma unroll
                for (int t = 0; t < 14; ++t) buf[t] = wp2[(qq*14 + t)*56 + c];
#pragma unroll
                for (int t = 0; t < 14; ++t) r = dot2u(buf[t], GLf2[h][qq*14 + t], r);
            }
        }
        resL[tid] = r;
    }
    __syncthreads();

    if (tid < FD_N) resH[tid] = packh2(resL[2*tid], resL[2*tid + 1]);
    __syncthreads();

    {
        const int col = tid >> 1, ph = tid & 1;
        float o = 0.f;
        unsigned buf[14];
#pragma unroll
        for (int qq = 0; qq < 4; ++qq) {
            const int base = ph*56 + qq*14;
#pragma unroll
            for (int t = 0; t < 14; ++t) buf[t] = woPk[(base + t)*256 + col];
#pragma unroll
            for (int t = 0; t < 14; ++t) o = dot2u(buf[t], resH[base + t], o);
        }
        o += __shfl_xor(o, 1);
        if (ph == 0) out[(size_t)i*DIM + col] = o;
    }
}

// ---------------------------------------------------------------------------
extern "C" void kernel_launch(void* const* d_in, const int* in_sizes, int n_in,
                              void* d_out, int out_size, void* d_ws, size_t ws_size,
                              hipStream_t stream) {
    (void)in_sizes; (void)n_in; (void)out_size; (void)ws_size;
    const float* local = (const float*)d_in[0];
    const float* pos   = (const float*)d_in[1];
    const int*   resi  = (const int*)d_in[2];
    const int*   chain = (const int*)d_in[3];
    const int*   batch = (const int*)d_in[4];
    const void*  maskp = d_in[5];
    const float* qls   = (const float*)d_in[6];
    const float* qlo   = (const float*)d_in[7];
    const float* kls   = (const float*)d_in[8];
    const float* klo   = (const float*)d_in[9];
    const float* w_q   = (const float*)d_in[10];
    const float* b_q   = (const float*)d_in[11];
    const float* w_k   = (const float*)d_in[12];
    const float* b_k   = (const float*)d_in[13];
    const float* w_v   = (const float*)d_in[14];
    const float* b_v   = (const float*)d_in[15];
    const float* w_qp  = (const float*)d_in[16];
    const float* b_qp  = (const float*)d_in[17];
    const float* w_kp  = (const float*)d_in[18];
    const float* b_kp  = (const float*)d_in[19];
    const float* w_vp  = (const float*)d_in[20];
    const float* b_vp  = (const float*)d_in[21];
    const float* remb  = (const float*)d_in[22];
    const float* w_pair= (const float*)d_in[23];
    const float* w_bias= (const float*)d_in[24];
    const float* b_bias= (const float*)d_in[25];
    const float* gamma = (const float*)d_in[26];
    const float* w_out = (const float*)d_in[27];

    char* ws = (char*)d_ws;
    unsigned* qnP   = (unsigned*)(ws);            // 131072 B [512][64]
    unsigned* qpP   = (unsigned*)(ws + 131072);   //  98304 B [512][48]
    unsigned* knT4  = (unsigned*)(ws + 229376);   // 131072 B [16][512][4]
    unsigned* kpT4  = (unsigned*)(ws + 360448);   //  98304 B [12][512][4]
    unsigned* BF    = (unsigned*)(ws + 458752);   // 327680 B [20][16][64][4]
    float*    jinf  = (float*)(ws + 786432);      //  16384 B
    float*    iinf  = (float*)(ws + 802816);      //   8192 B
    unsigned* woPk  = (unsigned*)(ws + 811008);   // 114688 B [112][256]
    unsigned* wp2   = (unsigned*)(ws + 925696);   //  12544 B [56][56]
    unsigned* remb2 = (unsigned*)(ws + 938240);   //   7392 B [33][56]

    proj_kernel<<<N_NODES / 2, 512, 0, stream>>>(
        local, pos, qls, qlo, kls, klo,
        w_q, b_q, w_k, b_k, w_v, b_v,
        w_qp, b_qp, w_kp, b_kp, w_vp, b_vp,
        w_bias, b_bias, gamma,
        remb, w_pair, w_out,
        qnP, knT4, qpP, kpT4, BF,
        woPk, wp2, remb2, jinf, iinf);

    attn_kernel<<<N_NODES, 512, 0, stream>>>(
        qnP, knT4, qpP, kpT4, BF,
        woPk, wp2, remb2, jinf, iinf,
        resi, chain, batch, maskp,
        w_bias, gamma,
        (float*)d_out);
}

// Round 17
// 53.443 us; speedup vs baseline: 2.1226x; 1.0070x over previous
//
#include <hip/hip_runtime.h>
#include <hip/hip_bf16.h>
#include <cstddef>

// Problem constants (N, D, S, H, QP, VP) = (512, 256, 32, 4, 8, 8)
#define N_NODES 512
#define DIM     256
#define H_HEADS 4
#define PAIR_CN 56    // S + 3*VP
#define P3_N    96    // H*QP*3
#define FD_N    112   // P3 + 16
#define HPC     224   // H * PAIR_C

typedef _Float16 h2v  __attribute__((ext_vector_type(2)));
typedef _Float16 f16x8 __attribute__((ext_vector_type(8)));
typedef float    f32x4 __attribute__((ext_vector_type(4)));

__device__ __forceinline__ bool mask_true(const void* m, int idx) {
    if (((const unsigned char*)m)[idx] != 0) return true;
    return ((const int*)m)[idx] != 0;
}
__device__ __forceinline__ unsigned packh2(float a, float b) {
    _Float16 ha = (_Float16)a, hb = (_Float16)b;
    unsigned short ua, ub;
    __builtin_memcpy(&ua, &ha, 2); __builtin_memcpy(&ub, &hb, 2);
    return (unsigned)ua | ((unsigned)ub << 16);
}
__device__ __forceinline__ float h2lof(unsigned u) {
    unsigned short t = (unsigned short)(u & 0xffff);
    _Float16 h; __builtin_memcpy(&h, &t, 2); return (float)h;
}
__device__ __forceinline__ float h2hif(unsigned u) {
    unsigned short t = (unsigned short)(u >> 16);
    _Float16 h; __builtin_memcpy(&h, &t, 2); return (float)h;
}
__device__ __forceinline__ float dot2u(unsigned a, unsigned b, float c) {
#if __has_builtin(__builtin_amdgcn_fdot2)
    h2v ha, hb;
    __builtin_memcpy(&ha, &a, 4);
    __builtin_memcpy(&hb, &b, 4);
    return __builtin_amdgcn_fdot2(ha, hb, c, false);
#else
    return c + h2lof(a)*h2lof(b) + h2hif(a)*h2hif(b);
#endif
}
__device__ __forceinline__ f32x4 mfma16(uint4 a, uint4 b, f32x4 c) {
    f16x8 af, bf;
    __builtin_memcpy(&af, &a, 16);
    __builtin_memcpy(&bf, &b, 16);
    return __builtin_amdgcn_mfma_f32_16x16x32_f16(af, bf, c, 0, 0, 0);
}

// ---------------------------------------------------------------------------
// Phase 1: projections + LayerNorm + separable terms + weight packing.
// (unchanged from round 16)
// ---------------------------------------------------------------------------
__global__ __launch_bounds__(512) void proj_kernel(
    const float* __restrict__ local, const float* __restrict__ pos,
    const float* __restrict__ qls, const float* __restrict__ qlo,
    const float* __restrict__ kls, const float* __restrict__ klo,
    const float* __restrict__ w_q, const float* __restrict__ b_q,
    const float* __restrict__ w_k, const float* __restrict__ b_k,
    const float* __restrict__ w_v, const float* __restrict__ b_v,
    const float* __restrict__ w_qp, const float* __restrict__ b_qp,
    const float* __restrict__ w_kp, const float* __restrict__ b_kp,
    const float* __restrict__ w_vp, const float* __restrict__ b_vp,
    const float* __restrict__ w_bias, const float* __restrict__ b_bias,
    const float* __restrict__ gamma,
    const float* __restrict__ remb, const float* __restrict__ w_pair,
    const float* __restrict__ w_out,
    unsigned* __restrict__ qnP, unsigned* __restrict__ knT4,
    unsigned* __restrict__ qpP, unsigned* __restrict__ kpT4,
    unsigned* __restrict__ BF,
    unsigned* __restrict__ woPk, unsigned* __restrict__ wp2,
    unsigned* __restrict__ remb2,
    float* __restrict__ jinfo, float* __restrict__ iinfo)
{
    const int i0 = blockIdx.x * 2;
    const int tid = threadIdx.x;

    __shared__ float xL[2][DIM];
    __shared__ float qraw[2][128];
    __shared__ float kraw[2][128];
    __shared__ float stat[2][16];
    __shared__ float qpL[2][P3_N];
    __shared__ float kpbL[2][P3_N];
    __shared__ float wbS[384];

    if (blockIdx.x < 16) {
        for (int t = blockIdx.x*512 + tid; t < 33656; t += 8192) {
            if (t < 28672) {
                const int t2 = t >> 8, colx = t & 255;
                woPk[t] = packh2(w_out[(size_t)(2*t2)*DIM + colx],
                                 w_out[(size_t)(2*t2 + 1)*DIM + colx]);
            } else if (t < 31808) {
                const int v = t - 28672, f2 = v / 56, cx = v % 56;
                wp2[v] = packh2(w_pair[(2*f2)*PAIR_CN + cx],
                                w_pair[(2*f2 + 1)*PAIR_CN + cx]);
            } else {
                const int v = t - 31808, r2 = v / 56, cx = v % 56;
                remb2[v] = packh2(remb[(2*r2)*PAIR_CN + cx],
                                  remb[(2*r2 + 1)*PAIR_CN + cx]);
            }
        }
    }

    {
        const int r = tid >> 8, d = tid & 255;
        xL[r][d] = local[(size_t)(i0 + r) * DIM + d];
    }
    if (tid < 384) wbS[tid] = w_bias[tid];
    __syncthreads();

    const int cstBF = ((i0 >> 5) << 8) + (((i0 >> 3) & 3) << 6) + ((i0 >> 1) & 3);

    if (tid < 336) {
        const int colg = tid >> 1, dh = tid & 1;
        const int col = colg * 4;
        const float* w; int width, c, seg;
        if      (col < 128) { w = w_q;  c = col;       width = 128; seg = 0; }
        else if (col < 256) { w = w_k;  c = col - 128; width = 128; seg = 1; }
        else if (col < 384) { w = w_v;  c = col - 256; width = 128; seg = 2; }
        else if (col < 480) { w = w_qp; c = col - 384; width = 96;  seg = 3; }
        else if (col < 576) { w = w_kp; c = col - 480; width = 96;  seg = 4; }
        else                { w = w_vp; c = col - 576; width = 96;  seg = 5; }

        float acc[2][4] = {{0.f,0.f,0.f,0.f},{0.f,0.f,0.f,0.f}};
        const float* wc = w + c;
        const int dbase = dh * 128;
#pragma unroll 1
        for (int bb = 0; bb < 16; ++bb) {
            const int d0 = dbase + bb*8;
            const float4 wv0 = *(const float4*)(wc + (size_t)(d0 + 0)*width);
            const float4 wv1 = *(const float4*)(wc + (size_t)(d0 + 1)*width);
            const float4 wv2 = *(const float4*)(wc + (size_t)(d0 + 2)*width);
            const float4 wv3 = *(const float4*)(wc + (size_t)(d0 + 3)*width);
            const float4 wv4 = *(const float4*)(wc + (size_t)(d0 + 4)*width);
            const float4 wv5 = *(const float4*)(wc + (size_t)(d0 + 5)*width);
            const float4 wv6 = *(const float4*)(wc + (size_t)(d0 + 6)*width);
            const float4 wv7 = *(const float4*)(wc + (size_t)(d0 + 7)*width);
#pragma unroll
            for (int r = 0; r < 2; ++r) {
                const float x0 = xL[r][d0 + 0], x1 = xL[r][d0 + 1];
                const float x2 = xL[r][d0 + 2], x3 = xL[r][d0 + 3];
                const float x4 = xL[r][d0 + 4], x5 = xL[r][d0 + 5];
                const float x6 = xL[r][d0 + 6], x7 = xL[r][d0 + 7];
                acc[r][0] += x0*wv0.x + x1*wv1.x + x2*wv2.x + x3*wv3.x
                           + x4*wv4.x + x5*wv5.x + x6*wv6.x + x7*wv7.x;
                acc[r][1] += x0*wv0.y + x1*wv1.y + x2*wv2.y + x3*wv3.y
                           + x4*wv4.y + x5*wv5.y + x6*wv6.y + x7*wv7.y;
                acc[r][2] += x0*wv0.z + x1*wv1.z + x2*wv2.z + x3*wv3.z
                           + x4*wv4.z + x5*wv5.z + x6*wv6.z + x7*wv7.z;
                acc[r][3] += x0*wv0.w + x1*wv1.w + x2*wv2.w + x3*wv3.w
                           + x4*wv4.w + x5*wv5.w + x6*wv6.w + x7*wv7.w;
            }
        }
#pragma unroll
        for (int r = 0; r < 2; ++r)
#pragma unroll
            for (int e = 0; e < 4; ++e)
                acc[r][e] += __shfl_xor(acc[r][e], 1);

        if (dh == 0) {
            const float cax0 = pos[i0*15+3],     cay0 = pos[i0*15+4],     caz0 = pos[i0*15+5];
            const float cax1 = pos[(i0+1)*15+3], cay1 = pos[(i0+1)*15+4], caz1 = pos[(i0+1)*15+5];
            float fr0[4], fr1[4];
            const bool isKp = (seg == 4), isQp = (seg == 3);
#pragma unroll
            for (int e = 0; e < 4; ++e) {
                const int cc = c + e;
                const float v0 = acc[0][e], v1 = acc[1][e];
                if (seg == 0) {
                    qraw[0][cc] = v0 + b_q[cc];
                    qraw[1][cc] = v1 + b_q[cc];
                } else if (seg == 1) {
                    kraw[0][cc] = v0 + b_k[cc];
                    kraw[1][cc] = v1 + b_k[cc];
                } else if (seg == 2) {
                    const int h = cc >> 5, sc = cc & 31;
                    const int colF = h*PAIR_CN + sc;
                    BF[(colF >> 4)*4096 + (colF & 15)*4 + cstBF] =
                        packh2(v0 + b_v[cc], v1 + b_v[cc]);
                } else if (seg == 3) {
                    const int x = cc % 3;
                    const float cav0 = (x==0)?cax0:((x==1)?cay0:caz0);
                    const float cav1 = (x==0)?cax1:((x==1)?cay1:caz1);
                    const float r0 = v0 + b_qp[cc] + cav0;
                    const float r1 = v1 + b_qp[cc] + cav1;
                    fr0[e] = r0; fr1[e] = r1;
                    qpL[0][cc] = r0; qpL[1][cc] = r1;
                } else if (seg == 4) {
                    const int x = cc % 3;
                    const float cav0 = (x==0)?cax0:((x==1)?cay0:caz0);
                    const float cav1 = (x==0)?cax1:((x==1)?cay1:caz1);
                    const float r0 = v0 + b_kp[cc] + cav0;
                    const float r1 = v1 + b_kp[cc] + cav1;
                    fr0[e] = r0; fr1[e] = r1;
                    const int colF = 224 + cc;
                    BF[(colF >> 4)*4096 + (colF & 15)*4 + cstBF] = packh2(r0, r1);
                    kpbL[0][cc] = (float)(_Float16)r0;
                    kpbL[1][cc] = (float)(_Float16)r1;
                } else {
                    const int h = cc / 24, rr = cc % 24, x = cc % 3;
                    const float cav0 = (x==0)?cax0:((x==1)?cay0:caz0);
                    const float cav1 = (x==0)?cax1:((x==1)?cay1:caz1);
                    const int colF = h*PAIR_CN + 32 + rr;
                    BF[(colF >> 4)*4096 + (colF & 15)*4 + cstBF] =
                        packh2(v0 + b_vp[cc] + cav0, v1 + b_vp[cc] + cav1);
                }
            }
            if (isQp) {
                const int f2 = c >> 1;
                qpP[(size_t)i0*48 + f2]         = packh2(fr0[0], fr0[1]);
                qpP[(size_t)i0*48 + f2 + 1]     = packh2(fr0[2], fr0[3]);
                qpP[(size_t)(i0+1)*48 + f2]     = packh2(fr1[0], fr1[1]);
                qpP[(size_t)(i0+1)*48 + f2 + 1] = packh2(fr1[2], fr1[3]);
            }
            if (isKp) {
                const int f2 = c >> 1;
                const int fq = f2 >> 2;
                kpT4[((size_t)fq*N_NODES + i0    )*4 + (f2 & 3)]       = packh2(fr0[0], fr0[1]);
                kpT4[((size_t)fq*N_NODES + i0    )*4 + ((f2 + 1) & 3)] = packh2(fr0[2], fr0[3]);
                kpT4[((size_t)fq*N_NODES + i0 + 1)*4 + (f2 & 3)]       = packh2(fr1[0], fr1[1]);
                kpT4[((size_t)fq*N_NODES + i0 + 1)*4 + ((f2 + 1) & 3)] = packh2(fr1[2], fr1[3]);
            }
        }
    }
    __syncthreads();

    if (tid < 16) {
        const int r = tid >> 3, t = tid & 7;
        const float* src = (t < 4) ? qraw[r] : kraw[r];
        const int h = t & 3, base = (t < 4) ? 0 : 8;
        float mu = 0.f;
        for (int c = 0; c < 32; ++c) mu += src[h*32 + c];
        mu *= (1.f/32.f);
        float var = 0.f;
        for (int c = 0; c < 32; ++c) { float d = src[h*32 + c] - mu; var += d*d; }
        var *= (1.f/32.f);
        stat[r][base + h*2 + 0] = mu;
        stat[r][base + h*2 + 1] = var;
    }
    __syncthreads();

    {
        const int r = tid >> 8, u = tid & 255;
        const int i = i0 + r;
        if (u < 128) {
            const int h = u >> 5, sidx = u & 31;
            const float mu = stat[r][h*2], var = stat[r][h*2+1];
            float v = (qraw[r][u] - mu) * rsqrtf(var + 1e-5f) * qls[sidx] + qlo[sidx];
            v *= 0.17677669529663687f;  // * sqrt(1/S)
            const float vo = __shfl_xor(v, 1);
            if (!(u & 1)) qnP[(size_t)i*64 + (u >> 1)] = packh2(v, vo);
        } else {
            const int u2 = u - 128, h = u2 >> 5, sidx = u2 & 31;
            const float mu = stat[r][8 + h*2], var = stat[r][9 + h*2];
            float v = (kraw[r][u2] - mu) * rsqrtf(var + 1e-5f) * kls[sidx] + klo[sidx];
            const float vo = __shfl_xor(v, 1);
            if (!(u2 & 1))
                knT4[(((size_t)(u2 >> 3))*N_NODES + i)*4 + ((u2 >> 1) & 3)] = packh2(v, vo);
        }
    }

    if (tid < 64) {
        const int r = tid >> 5, h = (tid >> 3) & 3, ks = tid & 7;
        float uacc = 0.f, tacc = 0.f;
#pragma unroll
        for (int f = ks; f < P3_N; f += 8) {
            float wb = wbS[f*4 + h];
            uacc += qpL[r][f] * wb;
            tacc += kpbL[r][f] * wb;
        }
        float nq = 0.f, nk = 0.f;
#pragma unroll
        for (int f = h*24 + ks*3; f < h*24 + ks*3 + 3; ++f) {
            nq += qpL[r][f]*qpL[r][f];
            nk += kpbL[r][f]*kpbL[r][f];
        }
        uacc += __shfl_xor(uacc,1); uacc += __shfl_xor(uacc,2); uacc += __shfl_xor(uacc,4);
        tacc += __shfl_xor(tacc,1); tacc += __shfl_xor(tacc,2); tacc += __shfl_xor(tacc,4);
        nq   += __shfl_xor(nq,1);   nq   += __shfl_xor(nq,2);   nq   += __shfl_xor(nq,4);
        nk   += __shfl_xor(nk,1);   nk   += __shfl_xor(nk,2);   nk   += __shfl_xor(nk,4);
        if (ks == 0) {
            const int n = i0 + r;
            const float ps = log1pf(expf(gamma[h])) * (1.0f/12.0f);
            iinfo[n*4 + h] = -ps*nq + uacc + b_bias[h];
            jinfo[n*8 + h] = -ps*nk - tacc;
            if (h == 0) {
                jinfo[n*8 + 4] = 10.f * pos[n*15 + 3];
                jinfo[n*8 + 5] = 10.f * pos[n*15 + 4];
                jinfo[n*8 + 6] = 10.f * pos[n*15 + 5];
                jinfo[n*8 + 7] = 0.f;
            }
        }
    }
}

// ---------------------------------------------------------------------------
// Phase 2: TWO query rows per block (ib, ib+1). 1024 threads, grid 256.
// Thread = (j, head-pair); all table/weight loads amortized across 2 rows.
// ---------------------------------------------------------------------------
__global__ __launch_bounds__(1024, 4) void attn_kernel(
    const unsigned* __restrict__ qnP, const unsigned* __restrict__ knT4,
    const unsigned* __restrict__ qpP, const unsigned* __restrict__ kpT4,
    const unsigned* __restrict__ BF,
    const unsigned* __restrict__ woPk, const unsigned* __restrict__ wp2,
    const unsigned* __restrict__ remb2,
    const float* __restrict__ jinfo, const float* __restrict__ iinfo,
    const int* __restrict__ resi, const int* __restrict__ chain,
    const int* __restrict__ batch, const void* __restrict__ maskp,
    const float* __restrict__ w_bias, const float* __restrict__ gamma,
    float* __restrict__ out)
{
    const int ib   = blockIdx.x * 2;
    const int tid  = threadIdx.x;
    const int lane = tid & 63;
    const int wv   = tid >> 6;      // 0..15
    const int hp   = tid >> 9;      // 0/1: head pair
    const int j    = tid & 511;

    __shared__ unsigned qpkL[2][64];
    __shared__ unsigned qspkL[2][48];
    __shared__ unsigned wbPk[H_HEADS][8];
    __shared__ __align__(16) unsigned rbfP[2][N_NODES][9];
    __shared__ __align__(16) unsigned attnH2[8][260];       // row = i*4+h
    __shared__ float    mxW[16][4], smW[16][4];
    __shared__ float    asL2[2][H_HEADS];
    __shared__ float    qpiL2[2][P3_N];
    __shared__ float    GLfF2[2][H_HEADS][P3_N];
    __shared__ float    GLfR2[2][H_HEADS][16];
    __shared__ unsigned GLf22[2][H_HEADS][56];
    __shared__ unsigned abktP2[2][H_HEADS][33];
    __shared__ float    resL2[2][HPC];
    __shared__ unsigned resH2[2][FD_N];
    __shared__ float    abktW8[8][2][H_HEADS][66];

    // ---- init ----
    if (tid < 128) {
        const int r = tid >> 6, u = tid & 63;
        qpkL[r][u] = qnP[(size_t)(ib + r)*64 + u];
    } else if (tid < 224) {
        const int v = tid - 128, r = v / 48, f2 = v % 48;
        const int h = f2 / 12;
        const float ps2 = 2.f * log1pf(expf(gamma[h])) * (1.0f/12.0f);
        const unsigned u = qpP[(size_t)(ib + r)*48 + f2];
        qspkL[r][f2] = packh2(ps2*h2lof(u), ps2*h2hif(u));
    } else if (tid < 320) {
        const int v = tid - 224, r = v / 48, f2 = v % 48;
        const unsigned u = qpP[(size_t)(ib + r)*48 + f2];
        qpiL2[r][2*f2]   = h2lof(u);
        qpiL2[r][2*f2+1] = h2hif(u);
    } else if (tid < 352) {
        const int v = tid - 320, h = v >> 3, e = v & 7;
        wbPk[h][e] = packh2(w_bias[(P3_N + 2*e)*H_HEADS + h],
                            w_bias[(P3_N + 2*e + 1)*H_HEADS + h]);
    }
    for (int t = tid; t < 8*2*H_HEADS*66; t += 1024) ((float*)abktW8)[t] = 0.f;

    const int  ri0 = resi[ib], ri1 = resi[ib+1];
    const int  ch0 = chain[ib], ch1 = chain[ib+1];
    const int  ba0 = batch[ib], ba1 = batch[ib+1];
    const bool mi0 = mask_true(maskp, ib), mi1 = mask_true(maskp, ib+1);
    const float dix0 = jinfo[(size_t)ib*8+4], diy0 = jinfo[(size_t)ib*8+5], diz0 = jinfo[(size_t)ib*8+6];
    const float dix1 = jinfo[(size_t)(ib+1)*8+4], diy1 = jinfo[(size_t)(ib+1)*8+5], diz1 = jinfo[(size_t)(ib+1)*8+6];

    const float inv3  = 0.57735026918962576f;
    const float rstep = 0.72727272727272727f;   // 1/1.375

    // ---- per-thread j prework: rbf for row hp; rd/pm for both rows ----
    const float4 vq4 = *(const float4*)(jinfo + (size_t)j*8);
    const float4 dj4 = *(const float4*)(jinfo + (size_t)j*8 + 4);
    const float4 ciA = *(const float4*)(iinfo + (size_t)ib*4);
    const float4 ciB = *(const float4*)(iinfo + (size_t)(ib+1)*4);
    const float vqa[4] = {vq4.x, vq4.y, vq4.z, vq4.w};
    const float cia[2][4] = {{ciA.x, ciA.y, ciA.z, ciA.w},
                             {ciB.x, ciB.y, ciB.z, ciB.w}};
    {
        const float dx = (hp ? dix1 : dix0) - dj4.x;
        const float dy = (hp ? diy1 : diy0) - dj4.y;
        const float dz = (hp ? diz1 : diz0) - dj4.z;
        const float dist = sqrtf(dx*dx + dy*dy + dz*dz + 1e-6f);
#pragma unroll
        for (int p = 0; p < 8; ++p) {
            const float u0 = (dist - (1.375f*(float)(2*p)   + 0.6875f)) * rstep;
            const float u1 = (dist - (1.375f*(float)(2*p+1) + 0.6875f)) * rstep;
            rbfP[hp][j][p] = packh2(__expf(-u0*u0), __expf(-u1*u1));
        }
    }
    const int  rj = resi[j], cj = chain[j], bj = batch[j];
    const bool mj = mask_true(maskp, j);
    bool pmv[2];
    int  rdv[2];
    pmv[0] = mi0 && mj && (ba0 == bj);
    pmv[1] = mi1 && mj && (ba1 == bj);
    rdv[0] = (ch0 != cj) ? 65 : (min(max(ri0 - rj, -32), 32) + 32);
    rdv[1] = (ch1 != cj) ? 65 : (min(max(ri1 - rj, -32), 32) + 32);
    __syncthreads();

    // ================= Pass A: thread=(j,hp), 14 loads -> 4 logits ==========
    float lv[2][2];   // [row][hh], h = hp*2 + hh
    {
        const int h0 = hp*2, h1 = hp*2 + 1;
        const uint4* kcol = (const uint4*)knT4 + j;
        const uint4* pcol = (const uint4*)kpT4 + j;
        const uint4 ka0 = kcol[(size_t)(h0*4 + 0)*N_NODES];
        const uint4 ka1 = kcol[(size_t)(h0*4 + 1)*N_NODES];
        const uint4 ka2 = kcol[(size_t)(h0*4 + 2)*N_NODES];
        const uint4 ka3 = kcol[(size_t)(h0*4 + 3)*N_NODES];
        const uint4 kb0 = kcol[(size_t)(h1*4 + 0)*N_NODES];
        const uint4 kb1 = kcol[(size_t)(h1*4 + 1)*N_NODES];
        const uint4 kb2 = kcol[(size_t)(h1*4 + 2)*N_NODES];
        const uint4 kb3 = kcol[(size_t)(h1*4 + 3)*N_NODES];
        const uint4 pa0 = pcol[(size_t)(h0*3 + 0)*N_NODES];
        const uint4 pa1 = pcol[(size_t)(h0*3 + 1)*N_NODES];
        const uint4 pa2 = pcol[(size_t)(h0*3 + 2)*N_NODES];
        const uint4 pb0 = pcol[(size_t)(h1*3 + 0)*N_NODES];
        const uint4 pb1 = pcol[(size_t)(h1*3 + 1)*N_NODES];
        const uint4 pb2 = pcol[(size_t)(h1*3 + 2)*N_NODES];
        const uint4 rr0a = *(const uint4*)&rbfP[0][j][0];
        const uint4 rr0b = *(const uint4*)&rbfP[0][j][4];
        const uint4 rr1a = *(const uint4*)&rbfP[1][j][0];
        const uint4 rr1b = *(const uint4*)&rbfP[1][j][4];
        const uint4 w0a = *(const uint4*)&wbPk[h0][0];
        const uint4 w0b = *(const uint4*)&wbPk[h0][4];
        const uint4 w1a = *(const uint4*)&wbPk[h1][0];
        const uint4 w1b = *(const uint4*)&wbPk[h1][4];
#pragma unroll
        for (int r = 0; r < 2; ++r) {
            const uint4* qk4 = (const uint4*)&qpkL[r][0];
            const uint4* qs4 = (const uint4*)&qspkL[r][0];
            const uint4 rra = r ? rr1a : rr0a;
            const uint4 rrb = r ? rr1b : rr0b;
            float a0 = 0.f;
            {
                const uint4 q0 = qk4[h0*4 + 0], q1 = qk4[h0*4 + 1];
                const uint4 q2 = qk4[h0*4 + 2], q3 = qk4[h0*4 + 3];
                a0 = dot2u(ka0.x, q0.x, a0); a0 = dot2u(ka0.y, q0.y, a0);
                a0 = dot2u(ka0.z, q0.z, a0); a0 = dot2u(ka0.w, q0.w, a0);
                a0 = dot2u(ka1.x, q1.x, a0); a0 = dot2u(ka1.y, q1.y, a0);
                a0 = dot2u(ka1.z, q1.z, a0); a0 = dot2u(ka1.w, q1.w, a0);
                a0 = dot2u(ka2.x, q2.x, a0); a0 = dot2u(ka2.y, q2.y, a0);
                a0 = dot2u(ka2.z, q2.z, a0); a0 = dot2u(ka2.w, q2.w, a0);
                a0 = dot2u(ka3.x, q3.x, a0); a0 = dot2u(ka3.y, q3.y, a0);
                a0 = dot2u(ka3.z, q3.z, a0); a0 = dot2u(ka3.w, q3.w, a0);
                const uint4 s0 = qs4[h0*3 + 0], s1 = qs4[h0*3 + 1], s2 = qs4[h0*3 + 2];
                a0 = dot2u(pa0.x, s0.x, a0); a0 = dot2u(pa0.y, s0.y, a0);
                a0 = dot2u(pa0.z, s0.z, a0); a0 = dot2u(pa0.w, s0.w, a0);
                a0 = dot2u(pa1.x, s1.x, a0); a0 = dot2u(pa1.y, s1.y, a0);
                a0 = dot2u(pa1.z, s1.z, a0); a0 = dot2u(pa1.w, s1.w, a0);
                a0 = dot2u(pa2.x, s2.x, a0); a0 = dot2u(pa2.y, s2.y, a0);
                a0 = dot2u(pa2.z, s2.z, a0); a0 = dot2u(pa2.w, s2.w, a0);
                a0 = dot2u(rra.x, w0a.x, a0); a0 = dot2u(rra.y, w0a.y, a0);
                a0 = dot2u(rra.z, w0a.z, a0); a0 = dot2u(rra.w, w0a.w, a0);
                a0 = dot2u(rrb.x, w0b.x, a0); a0 = dot2u(rrb.y, w0b.y, a0);
                a0 = dot2u(rrb.z, w0b.z, a0); a0 = dot2u(rrb.w, w0b.w, a0);
            }
            lv[r][0] = pmv[r] ? (a0 + cia[r][h0] + vqa[h0]) * inv3 : -1e9f;
            float a1 = 0.f;
            {
                const uint4 q0 = qk4[h1*4 + 0], q1 = qk4[h1*4 + 1];
                const uint4 q2 = qk4[h1*4 + 2], q3 = qk4[h1*4 + 3];
                a1 = dot2u(kb0.x, q0.x, a1); a1 = dot2u(kb0.y, q0.y, a1);
                a1 = dot2u(kb0.z, q0.z, a1); a1 = dot2u(kb0.w, q0.w, a1);
                a1 = dot2u(kb1.x, q1.x, a1); a1 = dot2u(kb1.y, q1.y, a1);
                a1 = dot2u(kb1.z, q1.z, a1); a1 = dot2u(kb1.w, q1.w, a1);
                a1 = dot2u(kb2.x, q2.x, a1); a1 = dot2u(kb2.y, q2.y, a1);
                a1 = dot2u(kb2.z, q2.z, a1); a1 = dot2u(kb2.w, q2.w, a1);
                a1 = dot2u(kb3.x, q3.x, a1); a1 = dot2u(kb3.y, q3.y, a1);
                a1 = dot2u(kb3.z, q3.z, a1); a1 = dot2u(kb3.w, q3.w, a1);
                const uint4 s0 = qs4[h1*3 + 0], s1 = qs4[h1*3 + 1], s2 = qs4[h1*3 + 2];
                a1 = dot2u(pb0.x, s0.x, a1); a1 = dot2u(pb0.y, s0.y, a1);
                a1 = dot2u(pb0.z, s0.z, a1); a1 = dot2u(pb0.w, s0.w, a1);
                a1 = dot2u(pb1.x, s1.x, a1); a1 = dot2u(pb1.y, s1.y, a1);
                a1 = dot2u(pb1.z, s1.z, a1); a1 = dot2u(pb1.w, s1.w, a1);
                a1 = dot2u(pb2.x, s2.x, a1); a1 = dot2u(pb2.y, s2.y, a1);
                a1 = dot2u(pb2.z, s2.z, a1); a1 = dot2u(pb2.w, s2.w, a1);
                a1 = dot2u(rra.x, w1a.x, a1); a1 = dot2u(rra.y, w1a.y, a1);
                a1 = dot2u(rra.z, w1a.z, a1); a1 = dot2u(rra.w, w1a.w, a1);
                a1 = dot2u(rrb.x, w1b.x, a1); a1 = dot2u(rrb.y, w1b.y, a1);
                a1 = dot2u(rrb.z, w1b.z, a1); a1 = dot2u(rrb.w, w1b.w, a1);
            }
            lv[r][1] = pmv[r] ? (a1 + cia[r][h1] + vqa[h1]) * inv3 : -1e9f;
        }
    }

    // ================= Softmax: intra-wave + 8-wave combine per hp-group ====
    {
        float mx[4] = {lv[0][0], lv[0][1], lv[1][0], lv[1][1]};
#pragma unroll
        for (int off = 1; off < 64; off <<= 1) {
#pragma unroll
            for (int s = 0; s < 4; ++s) mx[s] = fmaxf(mx[s], __shfl_xor(mx[s], off));
        }
        if (lane == 0) *(float4*)&mxW[wv][0] = make_float4(mx[0], mx[1], mx[2], mx[3]);
        __syncthreads();
        float mxg[4] = {-1e30f, -1e30f, -1e30f, -1e30f};
        const int wbase = hp*8;
#pragma unroll
        for (int w = 0; w < 8; ++w) {
            const float4 m = *(const float4*)&mxW[wbase + w][0];
            mxg[0] = fmaxf(mxg[0], m.x); mxg[1] = fmaxf(mxg[1], m.y);
            mxg[2] = fmaxf(mxg[2], m.z); mxg[3] = fmaxf(mxg[3], m.w);
        }
        float e[4], sm[4];
        e[0] = pmv[0] ? __expf(lv[0][0] - mxg[0]) : 0.f;
        e[1] = pmv[0] ? __expf(lv[0][1] - mxg[1]) : 0.f;
        e[2] = pmv[1] ? __expf(lv[1][0] - mxg[2]) : 0.f;
        e[3] = pmv[1] ? __expf(lv[1][1] - mxg[3]) : 0.f;
#pragma unroll
        for (int s = 0; s < 4; ++s) sm[s] = e[s];
#pragma unroll
        for (int off = 1; off < 64; off <<= 1) {
#pragma unroll
            for (int s = 0; s < 4; ++s) sm[s] += __shfl_xor(sm[s], off);
        }
        if (lane == 0) *(float4*)&smW[wv][0] = make_float4(sm[0], sm[1], sm[2], sm[3]);
        __syncthreads();
        float smt[4] = {0.f, 0.f, 0.f, 0.f};
#pragma unroll
        for (int w = 0; w < 8; ++w) {
            const float4 m = *(const float4*)&smW[wbase + w][0];
            smt[0] += m.x; smt[1] += m.y; smt[2] += m.z; smt[3] += m.w;
        }
        float p[4];
#pragma unroll
        for (int s = 0; s < 4; ++s) {
            const float rden = 1.f / fmaxf(smt[s], 1e-37f);
            p[s] = e[s] * rden;
        }
        const int h0 = hp*2;
        atomicAdd(&abktW8[wv & 7][0][h0    ][rdv[0]], p[0]);
        atomicAdd(&abktW8[wv & 7][0][h0 + 1][rdv[0]], p[1]);
        atomicAdd(&abktW8[wv & 7][1][h0    ][rdv[1]], p[2]);
        atomicAdd(&abktW8[wv & 7][1][h0 + 1][rdv[1]], p[3]);
        if (j == 0) {
            asL2[0][h0]     = smt[0] / fmaxf(smt[0], 1e-37f);
            asL2[0][h0 + 1] = smt[1] / fmaxf(smt[1], 1e-37f);
            asL2[1][h0]     = smt[2] / fmaxf(smt[2], 1e-37f);
            asL2[1][h0 + 1] = smt[3] / fmaxf(smt[3], 1e-37f);
        }
#pragma unroll
        for (int s = 0; s < 4; ++s) {
            const float po = __shfl_xor(p[s], 1);
            if (!(j & 1)) {
                const int r = s >> 1, hh = s & 1;
                attnH2[r*4 + h0 + hh][j >> 1] = packh2(p[s], po);
            }
        }
    }
    __syncthreads();

    // ================= Pass B: MFMA P(8 rows) x [val|kp], + rbf waves =======
    if (wv < 14) {
        const int row = lane & 15;
        const int ntA = wv;
        const int ntB = (wv < 6) ? (wv + 14) : -1;
        f32x4 accA = {0.f,0.f,0.f,0.f};
        f32x4 accB = {0.f,0.f,0.f,0.f};
        const uint4* bfp = (const uint4*)BF;
#pragma unroll 4
        for (int kt = 0; kt < 16; ++kt) {
            uint4 au = make_uint4(0u, 0u, 0u, 0u);
            if (row < 8) au = *(const uint4*)&attnH2[row][kt*16 + (lane >> 4)*4];
            const uint4 bA = bfp[(ntA*16 + kt)*64 + lane];
            accA = mfma16(au, bA, accA);
            if (ntB >= 0) {
                const uint4 bB = bfp[(ntB*16 + kt)*64 + lane];
                accB = mfma16(au, bB, accB);
            }
        }
        if (lane < 32) {
            const int r = lane >> 4, c16 = lane & 15;
            {
                const int s = ntA*16 + c16;
                if (s < HPC) {
                    resL2[r][s] = ((const float*)&accA)[s / PAIR_CN];
                } else {
                    const int f = s - HPC;
                    GLfF2[r][0][f] = accA[0];
                    GLfF2[r][1][f] = accA[1];
                    GLfF2[r][2][f] = accA[2];
                    GLfF2[r][3][f] = accA[3];
                }
            }
            if (ntB >= 0) {
                const int s = ntB*16 + c16;
                if (s < HPC) {
                    resL2[r][s] = ((const float*)&accB)[s / PAIR_CN];
                } else {
                    const int f = s - HPC;
                    GLfF2[r][0][f] = accB[0];
                    GLfF2[r][1][f] = accB[1];
                    GLfF2[r][2][f] = accB[2];
                    GLfF2[r][3][f] = accB[3];
                }
            }
        }
    } else {
        // rbf-G: wave 14 -> row 0, wave 15 -> row 1
        const int r = wv - 14;
        const int b = lane >> 2, q = lane & 3;
        const int w = b >> 1;
        const bool hi = (b & 1);
        float a[4] = {0.f, 0.f, 0.f, 0.f};
#pragma unroll 4
        for (int jpp = q*64; jpp < q*64 + 64; ++jpp) {
            const unsigned r0 = rbfP[r][2*jpp][w];
            const unsigned r1 = rbfP[r][2*jpp + 1][w];
            const unsigned ee = hi ? ((r0 >> 16) | (r1 & 0xffff0000u))
                                   : ((r0 & 0xffffu) | (r1 << 16));
            a[0] = dot2u(ee, attnH2[r*4 + 0][jpp], a[0]);
            a[1] = dot2u(ee, attnH2[r*4 + 1][jpp], a[1]);
            a[2] = dot2u(ee, attnH2[r*4 + 2][jpp], a[2]);
            a[3] = dot2u(ee, attnH2[r*4 + 3][jpp], a[3]);
        }
#pragma unroll
        for (int h = 0; h < 4; ++h) {
            a[h] += __shfl_xor(a[h], 1);
            a[h] += __shfl_xor(a[h], 2);
            if (q == 0) GLfR2[r][h][b] = a[h];
        }
    }
    __syncthreads();

    // ================= Combine: GLf2 pack, bucket pack ====================
    for (int t = tid; t < 448; t += 1024) {   // t = r*224 + h*56 + f2
        const int r = t / 224, v = t % 224, h = v / 56, f2 = v % 56;
        if (f2 < 48) {
            GLf22[r][h][f2] = packh2(qpiL2[r][2*f2]*asL2[r][h]     - GLfF2[r][h][2*f2],
                                     qpiL2[r][2*f2 + 1]*asL2[r][h] - GLfF2[r][h][2*f2 + 1]);
        } else {
            GLf22[r][h][f2] = packh2(GLfR2[r][h][(f2 - 48)*2], GLfR2[r][h][(f2 - 48)*2 + 1]);
        }
    }
    for (int t = tid; t < 264; t += 1024) {   // t = r*132 + h*33 + r2
        const int r = t / 132, v = t % 132, h = v / 33, r2 = v % 33;
        float s0 = 0.f, s1 = 0.f;
#pragma unroll
        for (int w = 0; w < 8; ++w) {
            s0 += abktW8[w][r][h][2*r2];
            s1 += abktW8[w][r][h][2*r2 + 1];
        }
        abktP2[r][h][r2] = packh2(s0, s1);
    }
    __syncthreads();

    // ================= Epilogue: weights loaded once, 2 rows ================
    if (tid < HPC) {
        const int h = tid / PAIR_CN, c = tid - h*PAIR_CN;
        float r0 = resL2[0][tid];
        float r1 = resL2[1][tid];
        {
            unsigned buf[16];
#pragma unroll
            for (int t = 0; t < 16; ++t) buf[t] = remb2[t*56 + c];
#pragma unroll
            for (int t = 0; t < 16; ++t) {
                r0 = dot2u(buf[t], abktP2[0][h][t], r0);
                r1 = dot2u(buf[t], abktP2[1][h][t], r1);
            }
#pragma unroll
            for (int t = 0; t < 16; ++t) buf[t] = remb2[(16 + t)*56 + c];
#pragma unroll
            for (int t = 0; t < 16; ++t) {
                r0 = dot2u(buf[t], abktP2[0][h][16 + t], r0);
                r1 = dot2u(buf[t], abktP2[1][h][16 + t], r1);
            }
            const unsigned b32 = remb2[32*56 + c];
            r0 = dot2u(b32, abktP2[0][h][32], r0);
            r1 = dot2u(b32, abktP2[1][h][32], r1);
        }
        {
            unsigned buf[14];
#pragma unroll
            for (int qq = 0; qq < 4; ++qq) {
#pragma unroll
                for (int t = 0; t < 14; ++t) buf[t] = wp2[(qq*14 + t)*56 + c];
#pragma unroll
                for (int t = 0; t < 14; ++t) {
                    r0 = dot2u(buf[t], GLf22[0][h][qq*14 + t], r0);
                    r1 = dot2u(buf[t], GLf22[1][h][qq*14 + t], r1);
                }
            }
        }
        resL2[0][tid] = r0;
        resL2[1][tid] = r1;
    }
    __syncthreads();

    if (tid < 2*FD_N) {
        const int r = tid / FD_N, t2 = tid % FD_N;
        resH2[r][t2] = packh2(resL2[r][2*t2], resL2[r][2*t2 + 1]);
    }
    __syncthreads();

    // ================= out: woPk loaded once, 2 rows =======================
    if (tid < 512) {
        const int col = tid >> 1, ph = tid & 1;
        float o0 = 0.f, o1 = 0.f;
        unsigned buf[14];
#pragma unroll
        for (int qq = 0; qq < 4; ++qq) {
            const int base = ph*56 + qq*14;
#pragma unroll
            for (int t = 0; t < 14; ++t) buf[t] = woPk[(base + t)*256 + col];
#pragma unroll
            for (int t = 0; t < 14; ++t) {
                o0 = dot2u(buf[t], resH2[0][base + t], o0);
                o1 = dot2u(buf[t], resH2[1][base + t], o1);
            }
        }
        o0 += __shfl_xor(o0, 1);
        o1 += __shfl_xor(o1, 1);
        if (ph == 0) {
            out[(size_t)ib*DIM + col]       = o0;
            out[(size_t)(ib + 1)*DIM + col] = o1;
        }
    }
}

// ---------------------------------------------------------------------------
extern "C" void kernel_launch(void* const* d_in, const int* in_sizes, int n_in,
                              void* d_out, int out_size, void* d_ws, size_t ws_size,
                              hipStream_t stream) {
    (void)in_sizes; (void)n_in; (void)out_size; (void)ws_size;
    const float* local = (const float*)d_in[0];
    const float* pos   = (const float*)d_in[1];
    const int*   resi  = (const int*)d_in[2];
    const int*   chain = (const int*)d_in[3];
    const int*   batch = (const int*)d_in[4];
    const void*  maskp = d_in[5];
    const float* qls   = (const float*)d_in[6];
    const float* qlo   = (const float*)d_in[7];
    const float* kls   = (const float*)d_in[8];
    const float* klo   = (const float*)d_in[9];
    const float* w_q   = (const float*)d_in[10];
    const float* b_q   = (const float*)d_in[11];
    const float* w_k   = (const float*)d_in[12];
    const float* b_k   = (const float*)d_in[13];
    const float* w_v   = (const float*)d_in[14];
    const float* b_v   = (const float*)d_in[15];
    const float* w_qp  = (const float*)d_in[16];
    const float* b_qp  = (const float*)d_in[17];
    const float* w_kp  = (const float*)d_in[18];
    const float* b_kp  = (const float*)d_in[19];
    const float* w_vp  = (const float*)d_in[20];
    const float* b_vp  = (const float*)d_in[21];
    const float* remb  = (const float*)d_in[22];
    const float* w_pair= (const float*)d_in[23];
    const float* w_bias= (const float*)d_in[24];
    const float* b_bias= (const float*)d_in[25];
    const float* gamma = (const float*)d_in[26];
    const float* w_out = (const float*)d_in[27];

    char* ws = (char*)d_ws;
    unsigned* qnP   = (unsigned*)(ws);            // 131072 B [512][64]
    unsigned* qpP   = (unsigned*)(ws + 131072);   //  98304 B [512][48]
    unsigned* knT4  = (unsigned*)(ws + 229376);   // 131072 B [16][512][4]
    unsigned* kpT4  = (unsigned*)(ws + 360448);   //  98304 B [12][512][4]
    unsigned* BF    = (unsigned*)(ws + 458752);   // 327680 B [20][16][64][4]
    float*    jinf  = (float*)(ws + 786432);      //  16384 B
    float*    iinf  = (float*)(ws + 802816);      //   8192 B
    unsigned* woPk  = (unsigned*)(ws + 811008);   // 114688 B [112][256]
    unsigned* wp2   = (unsigned*)(ws + 925696);   //  12544 B [56][56]
    unsigned* remb2 = (unsigned*)(ws + 938240);   //   7392 B [33][56]

    proj_kernel<<<N_NODES / 2, 512, 0, stream>>>(
        local, pos, qls, qlo, kls, klo,
        w_q, b_q, w_k, b_k, w_v, b_v,
        w_qp, b_qp, w_kp, b_kp, w_vp, b_vp,
        w_bias, b_bias, gamma,
        remb, w_pair, w_out,
        qnP, knT4, qpP, kpT4, BF,
        woPk, wp2, remb2, jinf, iinf);

    attn_kernel<<<N_NODES / 2, 1024, 0, stream>>>(
        qnP, knT4, qpP, kpT4, BF,
        woPk, wp2, remb2, jinf, iinf,
        resi, chain, batch, maskp,
        w_bias, gamma,
        (float*)d_out);
}